// Round 9
// baseline (266.990 us; speedup 1.0000x reference)
//
#include <hip/hip_runtime.h>
#include <cmath>

#define DIMM 1024
#define NHEADS 16
#define NKV 4
#define HD 64
#define SEQ 1024
#define BSZ 8
#define ROWS (BSZ * SEQ)   // 8192

typedef unsigned short u16;
typedef __attribute__((ext_vector_type(8))) short bf16x8;
typedef __attribute__((ext_vector_type(4))) float f32x4;
typedef __attribute__((ext_vector_type(4))) unsigned short u16x4;

static __device__ __forceinline__ u16 f2bf(float f) {
    union { float f; unsigned u; } v; v.f = f;
    unsigned r = v.u + 0x7FFFu + ((v.u >> 16) & 1u);
    return (u16)(r >> 16);
}

// async global->LDS, 16B per lane; dst must be wave-uniform base (HW adds lane*16)
static __device__ __forceinline__ void gload16(const u16* g, u16* l) {
    __builtin_amdgcn_global_load_lds(
        (const __attribute__((address_space(1))) unsigned int*)g,
        (__attribute__((address_space(3))) unsigned int*)l, 16, 0, 0);
}

// ---------------- weight abs-mean partial reduce ----------------
__global__ __launch_bounds__(256) void k_absmean(const float* __restrict__ w, int n,
                                                 float* __restrict__ partial) {
    float s = 0.f;
    for (int i = blockIdx.x * 256 + threadIdx.x; i < n; i += 64 * 256) s += fabsf(w[i]);
    #pragma unroll
    for (int off = 32; off; off >>= 1) s += __shfl_xor(s, off);
    __shared__ float red[4];
    if ((threadIdx.x & 63) == 0) red[threadIdx.x >> 6] = s;
    __syncthreads();
    if (threadIdx.x == 0) partial[blockIdx.x] = red[0] + red[1] + red[2] + red[3];
}

// ---------------- alpha = max(mean|w|, eps) ----------------
__global__ void k_alpha(const float* __restrict__ partial, float* __restrict__ alpha) {
    int i = threadIdx.x;
    if (i < 4) {
        const int ns[4] = {1048576, 262144, 262144, 1048576};
        float s = 0.f;
        for (int j = 0; j < 64; ++j) s += partial[i * 64 + j];
        alpha[i] = fmaxf(s / (float)ns[i], 1e-8f);
    }
}

// ---------------- ternarize -> bf16 (values {-1,0,1}, exact) ----------------
__global__ __launch_bounds__(256) void k_tern(const float* __restrict__ w,
                                              const float* __restrict__ alpha, int ai,
                                              u16* __restrict__ wt, int n4) {
    float a = alpha[ai];
    for (int i = blockIdx.x * blockDim.x + threadIdx.x; i < n4; i += gridDim.x * blockDim.x) {
        float4 v = *reinterpret_cast<const float4*>(&w[i * 4]);
        u16x4 o;
        o.x = f2bf(rintf(fminf(fmaxf(v.x / a, -1.f), 1.f)));
        o.y = f2bf(rintf(fminf(fmaxf(v.y / a, -1.f), 1.f)));
        o.z = f2bf(rintf(fminf(fmaxf(v.z / a, -1.f), 1.f)));
        o.w = f2bf(rintf(fminf(fmaxf(v.w / a, -1.f), 1.f)));
        *reinterpret_cast<u16x4*>(&wt[i * 4]) = o;
    }
}

// ---------------- per-row activation quantization -> bf16 ints ----------------
__global__ __launch_bounds__(256) void k_quant(const float* __restrict__ X,
                                               u16* __restrict__ Xq, float* __restrict__ g) {
    int row = blockIdx.x;
    const float* xr = X + (size_t)row * DIMM;
    float4 v = *reinterpret_cast<const float4*>(&xr[threadIdx.x * 4]);
    float mv = fmaxf(fmaxf(fabsf(v.x), fabsf(v.y)), fmaxf(fabsf(v.z), fabsf(v.w)));
    #pragma unroll
    for (int off = 32; off; off >>= 1) mv = fmaxf(mv, __shfl_xor(mv, off));
    __shared__ float red[4];
    if ((threadIdx.x & 63) == 0) red[threadIdx.x >> 6] = mv;
    __syncthreads();
    mv = fmaxf(fmaxf(red[0], red[1]), fmaxf(red[2], red[3]));
    float gamma = fmaxf(mv, 1e-8f) / 127.0f;
    u16x4 o;
    o.x = f2bf(rintf(fminf(fmaxf(v.x / gamma, -128.f), 127.f)));
    o.y = f2bf(rintf(fminf(fmaxf(v.y / gamma, -128.f), 127.f)));
    o.z = f2bf(rintf(fminf(fmaxf(v.z / gamma, -128.f), 127.f)));
    o.w = f2bf(rintf(fminf(fmaxf(v.w / gamma, -128.f), 127.f)));
    *reinterpret_cast<u16x4*>(&Xq[(size_t)row * DIMM + threadIdx.x * 4]) = o;
    if (threadIdx.x == 0) g[row] = gamma;
}

// ---------------- QKV GEMM with fused rms_norm+rope epilogue ----------------
__global__ __launch_bounds__(256) void k_gemm_qkv(const u16* __restrict__ A,
                                                  const u16* __restrict__ B,
                                                  const float* __restrict__ gamma,
                                                  const float* __restrict__ alpha_p,
                                                  const float* __restrict__ rc,
                                                  const float* __restrict__ rs,
                                                  const float* __restrict__ gain,
                                                  u16* __restrict__ Qo,
                                                  u16* __restrict__ Ko,
                                                  float* __restrict__ Cv) {
    __shared__ u16 As[128 * 64];
    __shared__ u16 Bs[128 * 64];
    const int K = DIMM;
    int tid = threadIdx.x;
    int w = tid >> 6, lane = tid & 63;
    int lr = lane & 15, lg = lane >> 4;
    int lr7 = lr & 7;
    int wm = w >> 1, wn = w & 1;
    int row0 = blockIdx.y * 128, col0 = blockIdx.x * 128;

    f32x4 acc[4][4];
    #pragma unroll
    for (int mf = 0; mf < 4; ++mf)
        #pragma unroll
        for (int nf = 0; nf < 4; ++nf) acc[mf][nf] = (f32x4){0.f, 0.f, 0.f, 0.f};

    int srow = w * 32 + (lane >> 3);
    int scol = 8 * ((lane & 7) ^ (lane >> 3));
    const u16* Ag = A + (size_t)(row0 + srow) * K + scol;
    const u16* Bg = B + (size_t)(col0 + srow) * K + scol;

    for (int k0 = 0; k0 < K; k0 += 64) {
        #pragma unroll
        for (int i = 0; i < 4; ++i) {
            gload16(Ag + (size_t)i * 8 * K + k0, &As[w * 2048 + i * 512]);
            gload16(Bg + (size_t)i * 8 * K + k0, &Bs[w * 2048 + i * 512]);
        }
        __syncthreads();
        #pragma unroll
        for (int kk = 0; kk < 64; kk += 32) {
            int sl = (kk >> 3);
            bf16x8 af[4], bfr[4];
            #pragma unroll
            for (int mf = 0; mf < 4; ++mf)
                af[mf] = *reinterpret_cast<const bf16x8*>(
                    &As[(wm * 64 + mf * 16 + lr) * 64 + 8 * ((sl + lg) ^ lr7)]);
            #pragma unroll
            for (int nf = 0; nf < 4; ++nf)
                bfr[nf] = *reinterpret_cast<const bf16x8*>(
                    &Bs[(wn * 64 + nf * 16 + lr) * 64 + 8 * ((sl + lg) ^ lr7)]);
            #pragma unroll
            for (int mf = 0; mf < 4; ++mf)
                #pragma unroll
                for (int nf = 0; nf < 4; ++nf)
                    acc[mf][nf] = __builtin_amdgcn_mfma_f32_16x16x32_bf16(af[mf], bfr[nf], acc[mf][nf], 0, 0, 0);
        }
        __syncthreads();
    }

    int c0 = col0 + wn * 64;
    int hh = c0 >> 6;   // 0..15 Q heads, 16..19 K heads, 20..23 V heads
    float alpha = alpha_p[hh < 16 ? 0 : (hh < 20 ? 1 : 2)];
    float ga = (hh < 16) ? gain[hh] * (0.125f * 1.4426950408889634f) : 1.0f;

    #pragma unroll
    for (int mf = 0; mf < 4; ++mf) {
        #pragma unroll
        for (int reg = 0; reg < 4; ++reg) {
            int row = row0 + wm * 64 + mf * 16 + lg * 4 + reg;
            float sc = gamma[row] * alpha;
            float v0 = acc[mf][0][reg] * sc;
            float v1 = acc[mf][1][reg] * sc;
            float v2 = acc[mf][2][reg] * sc;
            float v3 = acc[mf][3][reg] * sc;
            int s = row & 1023, b = row >> 10;
            if (hh < 20) {
                float ss = v0 * v0 + v1 * v1 + v2 * v2 + v3 * v3;
                #pragma unroll
                for (int off = 8; off; off >>= 1) ss += __shfl_xor(ss, off);
                float rn = 1.0f / sqrtf(ss * (1.0f / 64.0f) + 1.1920929e-07f);
                v0 *= rn; v1 *= rn; v2 *= rn; v3 *= rn;
                float cA = rc[s * 32 + lr],      sA = rs[s * 32 + lr];
                float cB = rc[s * 32 + 16 + lr], sB = rs[s * 32 + 16 + lr];
                float y0 = v0 * cA + v2 * sA, y2 = v2 * cA - v0 * sA;
                float y1 = v1 * cB + v3 * sB, y3 = v3 * cB - v1 * sB;
                u16* dst;
                if (hh < 16) {
                    y0 *= ga; y1 *= ga; y2 *= ga; y3 *= ga;
                    dst = Qo + ((size_t)((b * 16 + hh) * 1024 + s)) * 64;
                } else {
                    dst = Ko + ((size_t)((b * 4 + (hh - 16)) * 1024 + s)) * 64;
                }
                dst[lr] = f2bf(y0); dst[16 + lr] = f2bf(y1);
                dst[32 + lr] = f2bf(y2); dst[48 + lr] = f2bf(y3);
            } else {
                float* dst = Cv + (size_t)row * 256 + (hh - 20) * 64;
                dst[lr] = v0; dst[16 + lr] = v1; dst[32 + lr] = v2; dst[48 + lr] = v3;
            }
        }
    }
}

// ---------------- plain GEMM for output projection ----------------
__global__ __launch_bounds__(256) void k_gemm_out(const u16* __restrict__ A,
                                                  const u16* __restrict__ B,
                                                  const float* __restrict__ gamma,
                                                  const float* __restrict__ alpha_p,
                                                  float* __restrict__ C) {
    __shared__ u16 As[128 * 64];
    __shared__ u16 Bs[128 * 64];
    const int K = DIMM;
    int tid = threadIdx.x;
    int w = tid >> 6, lane = tid & 63;
    int lr = lane & 15, lg = lane >> 4;
    int lr7 = lr & 7;
    int wm = w >> 1, wn = w & 1;
    int row0 = blockIdx.y * 128, col0 = blockIdx.x * 128;

    f32x4 acc[4][4];
    #pragma unroll
    for (int mf = 0; mf < 4; ++mf)
        #pragma unroll
        for (int nf = 0; nf < 4; ++nf) acc[mf][nf] = (f32x4){0.f, 0.f, 0.f, 0.f};

    int srow = w * 32 + (lane >> 3);
    int scol = 8 * ((lane & 7) ^ (lane >> 3));
    const u16* Ag = A + (size_t)(row0 + srow) * K + scol;
    const u16* Bg = B + (size_t)(col0 + srow) * K + scol;

    for (int k0 = 0; k0 < K; k0 += 64) {
        #pragma unroll
        for (int i = 0; i < 4; ++i) {
            gload16(Ag + (size_t)i * 8 * K + k0, &As[w * 2048 + i * 512]);
            gload16(Bg + (size_t)i * 8 * K + k0, &Bs[w * 2048 + i * 512]);
        }
        __syncthreads();
        #pragma unroll
        for (int kk = 0; kk < 64; kk += 32) {
            int sl = (kk >> 3);
            bf16x8 af[4], bfr[4];
            #pragma unroll
            for (int mf = 0; mf < 4; ++mf)
                af[mf] = *reinterpret_cast<const bf16x8*>(
                    &As[(wm * 64 + mf * 16 + lr) * 64 + 8 * ((sl + lg) ^ lr7)]);
            #pragma unroll
            for (int nf = 0; nf < 4; ++nf)
                bfr[nf] = *reinterpret_cast<const bf16x8*>(
                    &Bs[(wn * 64 + nf * 16 + lr) * 64 + 8 * ((sl + lg) ^ lr7)]);
            #pragma unroll
            for (int mf = 0; mf < 4; ++mf)
                #pragma unroll
                for (int nf = 0; nf < 4; ++nf)
                    acc[mf][nf] = __builtin_amdgcn_mfma_f32_16x16x32_bf16(af[mf], bfr[nf], acc[mf][nf], 0, 0, 0);
        }
        __syncthreads();
    }

    float alpha = alpha_p[3];
    #pragma unroll
    for (int mf = 0; mf < 4; ++mf) {
        #pragma unroll
        for (int reg = 0; reg < 4; ++reg) {
            int row = row0 + wm * 64 + mf * 16 + lg * 4 + reg;
            float sc = gamma[row] * alpha;
            #pragma unroll
            for (int nf = 0; nf < 4; ++nf)
                C[(size_t)row * 1024 + col0 + wn * 64 + nf * 16 + lr] = acc[mf][nf][reg] * sc;
        }
    }
}

// ---------------- rope table ----------------
__global__ __launch_bounds__(256) void k_rope(float* __restrict__ c, float* __restrict__ s) {
    int idx = blockIdx.x * 256 + threadIdx.x;  // < 32768
    int t = idx >> 5, i = idx & 31;
    float inv = 1.0f / powf(10000.0f, (float)(2 * i) * (1.0f / 64.0f));
    float f = (float)t * inv;
    c[idx] = cosf(f);
    s[idx] = sinf(f);
}

// ---------------- v transpose: Cv [8192][256] f32 -> Vt [b,kv,d,pos] bf16 ----------------
// pos permutation matches swapped-QK P layout: for s-in-tile = sr+16*i:
// pos = 8*(sr>>2) + (sr&3) + 4*(i&1) + 32*(i>>1)
__global__ __launch_bounds__(256) void k_vtransT(const float* __restrict__ Cv,
                                                 u16* __restrict__ Vt) {
    __shared__ u16 T[64][72];
    int st = blockIdx.x, kv = blockIdx.y, b = blockIdx.z;
    int tid = threadIdx.x;
    int sr = tid >> 4, d4 = tid & 15;
    #pragma unroll
    for (int i = 0; i < 4; ++i) {
        int s = sr + 16 * i;
        int pos = 8 * (sr >> 2) + (sr & 3) + 4 * (i & 1) + 32 * (i >> 1);
        float4 v = *reinterpret_cast<const float4*>(
            &Cv[(size_t)(b * 1024 + st * 64 + s) * 256 + kv * 64 + d4 * 4]);
        T[d4 * 4 + 0][pos] = f2bf(v.x);
        T[d4 * 4 + 1][pos] = f2bf(v.y);
        T[d4 * 4 + 2][pos] = f2bf(v.z);
        T[d4 * 4 + 3][pos] = f2bf(v.w);
    }
    __syncthreads();
    int d = tid >> 2, c = tid & 3;
    float4 o0 = *reinterpret_cast<const float4*>(&T[d][c * 16]);
    float4 o1 = *reinterpret_cast<const float4*>(&T[d][c * 16 + 8]);
    u16* out = &Vt[(((size_t)(b * 4 + kv) * 64) + d) * 1024 + st * 64 + c * 16];
    *reinterpret_cast<float4*>(out) = o0;
    *reinterpret_cast<float4*>(out + 8) = o1;
}

// ---------------- swapped-QK softmax + in-register P pack ----------------
static __device__ __forceinline__ void softmax_pack(f32x4 sv[4], float& m, float& lp,
                                                    f32x4 acc[4], int lg,
                                                    bf16x8& pa0, bf16x8& pa1) {
    float vx = -INFINITY;
    #pragma unroll
    for (int t4 = 0; t4 < 4; ++t4)
        vx = fmaxf(vx, fmaxf(fmaxf(sv[t4][0], sv[t4][1]), fmaxf(sv[t4][2], sv[t4][3])));
    if (!__all(vx <= m + 8.0f)) {
        float mm = fmaxf(vx, __shfl_xor(vx, 16));
        mm = fmaxf(mm, __shfl_xor(mm, 32));
        float mn = fmaxf(m, mm);
        float corr = exp2f(m - mn);
        m = mn; lp *= corr;
        float c0 = __shfl(corr, lg * 4 + 0);
        float c1 = __shfl(corr, lg * 4 + 1);
        float c2 = __shfl(corr, lg * 4 + 2);
        float c3 = __shfl(corr, lg * 4 + 3);
        #pragma unroll
        for (int dt = 0; dt < 4; ++dt) {
            acc[dt][0] *= c0; acc[dt][1] *= c1; acc[dt][2] *= c2; acc[dt][3] *= c3;
        }
    }
    float p[4][4];
    float s = 0.f;
    #pragma unroll
    for (int t4 = 0; t4 < 4; ++t4)
        #pragma unroll
        for (int r = 0; r < 4; ++r) { p[t4][r] = exp2f(sv[t4][r] - m); s += p[t4][r]; }
    lp += s;
    union { unsigned u[4]; bf16x8 v; } A0, A1;
    asm("v_cvt_pk_bf16_f32 %0, %1, %2" : "=v"(A0.u[0]) : "v"(p[0][0]), "v"(p[0][1]));
    asm("v_cvt_pk_bf16_f32 %0, %1, %2" : "=v"(A0.u[1]) : "v"(p[0][2]), "v"(p[0][3]));
    asm("v_cvt_pk_bf16_f32 %0, %1, %2" : "=v"(A0.u[2]) : "v"(p[1][0]), "v"(p[1][1]));
    asm("v_cvt_pk_bf16_f32 %0, %1, %2" : "=v"(A0.u[3]) : "v"(p[1][2]), "v"(p[1][3]));
    asm("v_cvt_pk_bf16_f32 %0, %1, %2" : "=v"(A1.u[0]) : "v"(p[2][0]), "v"(p[2][1]));
    asm("v_cvt_pk_bf16_f32 %0, %1, %2" : "=v"(A1.u[1]) : "v"(p[2][2]), "v"(p[2][3]));
    asm("v_cvt_pk_bf16_f32 %0, %1, %2" : "=v"(A1.u[2]) : "v"(p[3][0]), "v"(p[3][1]));
    asm("v_cvt_pk_bf16_f32 %0, %1, %2" : "=v"(A1.u[3]) : "v"(p[3][2]), "v"(p[3][3]));
    pa0 = A0.v; pa1 = A1.v;
}

// ---------------- causal flash attention, swapped-QK bf16 MFMA ----------------
__global__ __launch_bounds__(256) void k_attn_mfma(const u16* __restrict__ Q,
                                                   const u16* __restrict__ K,
                                                   const u16* __restrict__ Vt,
                                                   float* __restrict__ Y) {
    __shared__ __align__(16) u16 KVs[2][2][4096];   // [buf][K/V][64*64], swizzled
    int qta = blockIdx.x, qtb = 15 - qta;
    int h = blockIdx.y, b = blockIdx.z;
    int kvh = h >> 2;
    int tid = threadIdx.x;
    int w = tid >> 6, lane = tid & 63;
    int lr = lane & 15, lg = lane >> 4;
    int lr7 = lr & 7;
    int q0a = qta * 64 + w * 16, q0b = qtb * 64 + w * 16;
    const u16* Qb = Q + (((size_t)b * 16 + h) * 1024) * 64;
    const u16* Kb = K + (((size_t)b * 4 + kvh) * 1024) * 64;
    const u16* Vb = Vt + (((size_t)b * 4 + kvh) * 64) * 1024;

    bf16x8 qa0 = *reinterpret_cast<const bf16x8*>(&Qb[(size_t)(q0a + lr) * 64 + 8 * lg]);
    bf16x8 qa1 = *reinterpret_cast<const bf16x8*>(&Qb[(size_t)(q0a + lr) * 64 + 32 + 8 * lg]);
    bf16x8 qb0 = *reinterpret_cast<const bf16x8*>(&Qb[(size_t)(q0b + lr) * 64 + 8 * lg]);
    bf16x8 qb1 = *reinterpret_cast<const bf16x8*>(&Qb[(size_t)(q0b + lr) * 64 + 32 + 8 * lg]);

    float mA = -INFINITY, lpA = 0.f, mB = -INFINITY, lpB = 0.f;
    f32x4 accA[4], accB[4];
    #pragma unroll
    for (int dt = 0; dt < 4; ++dt) { accA[dt] = (f32x4){0.f,0.f,0.f,0.f}; accB[dt] = (f32x4){0.f,0.f,0.f,0.f}; }

    int sub = lane >> 3, s7 = lane & 7;
    int scol16 = s7 ^ sub;
    int c0 = 2 * w, c1 = 2 * w + 1;

    #define STAGE(buf, t_) do { \
        int kk0 = (t_) * 64; \
        gload16(Kb + (size_t)(kk0 + 8 * c0 + sub) * 64 + scol16 * 8, &KVs[buf][0][c0 * 512]); \
        gload16(Kb + (size_t)(kk0 + 8 * c1 + sub) * 64 + scol16 * 8, &KVs[buf][0][c1 * 512]); \
        gload16(Vb + (size_t)(8 * c0 + sub) * 1024 + kk0 + scol16 * 8, &KVs[buf][1][c0 * 512]); \
        gload16(Vb + (size_t)(8 * c1 + sub) * 1024 + kk0 + scol16 * 8, &KVs[buf][1][c1 * 512]); \
    } while (0)

    STAGE(0, 0);
    asm volatile("s_waitcnt vmcnt(0)" ::: "memory");
    __syncthreads();
    int cur = 0;

    for (int t = 0; t <= qtb; ++t) {
        if (t < qtb) STAGE(cur ^ 1, t + 1);
        const int k0 = t * 64;
        const bool doA = (t <= qta);
        const u16* Kl = KVs[cur][0];
        const u16* Vl = KVs[cur][1];

        f32x4 svA[4], svB[4];
        #pragma unroll
        for (int t4 = 0; t4 < 4; ++t4) {
            int r = t4 * 16 + lr;
            bf16x8 kf0 = *reinterpret_cast<const bf16x8*>(&Kl[r * 64 + ((lg ^ lr7) << 3)]);
            bf16x8 kf1 = *reinterpret_cast<const bf16x8*>(&Kl[r * 64 + (((4 | lg) ^ lr7) << 3)]);
            if (doA) {
                f32x4 z = (f32x4){0.f,0.f,0.f,0.f};
                z = __builtin_amdgcn_mfma_f32_16x16x32_bf16(kf0, qa0, z, 0, 0, 0);
                z = __builtin_amdgcn_mfma_f32_16x16x32_bf16(kf1, qa1, z, 0, 0, 0);
                svA[t4] = z;
            }
            f32x4 z2 = (f32x4){0.f,0.f,0.f,0.f};
            z2 = __builtin_amdgcn_mfma_f32_16x16x32_bf16(kf0, qb0, z2, 0, 0, 0);
            z2 = __builtin_amdgcn_mfma_f32_16x16x32_bf16(kf1, qb1, z2, 0, 0, 0);
            svB[t4] = z2;
        }
        // causal masks: key = k0 + 16*t4 + 4*lg + r, q = q0X + lr
        if (doA && t == qta) {
            #pragma unroll
            for (int t4 = 0; t4 < 4; ++t4)
                #pragma unroll
                for (int r = 0; r < 4; ++r)
                    if (k0 + 16 * t4 + 4 * lg + r > q0a + lr) svA[t4][r] = -3.0e38f;
        }
        if (t == qtb) {
            #pragma unroll
            for (int t4 = 0; t4 < 4; ++t4)
                #pragma unroll
                for (int r = 0; r < 4; ++r)
                    if (k0 + 16 * t4 + 4 * lg + r > q0b + lr) svB[t4][r] = -3.0e38f;
        }

        bf16x8 paA0, paA1, paB0, paB1;
        if (doA) softmax_pack(svA, mA, lpA, accA, lg, paA0, paA1);
        softmax_pack(svB, mB, lpB, accB, lg, paB0, paB1);

        #pragma unroll
        for (int dt = 0; dt < 4; ++dt) {
            int r = dt * 16 + lr;
            bf16x8 vf0 = *reinterpret_cast<const bf16x8*>(&Vl[r * 64 + ((lg ^ lr7) << 3)]);
            bf16x8 vf1 = *reinterpret_cast<const bf16x8*>(&Vl[r * 64 + (((4 | lg) ^ lr7) << 3)]);
            if (doA) {
                accA[dt] = __builtin_amdgcn_mfma_f32_16x16x32_bf16(paA0, vf0, accA[dt], 0, 0, 0);
                accA[dt] = __builtin_amdgcn_mfma_f32_16x16x32_bf16(paA1, vf1, accA[dt], 0, 0, 0);
            }
            accB[dt] = __builtin_amdgcn_mfma_f32_16x16x32_bf16(paB0, vf0, accB[dt], 0, 0, 0);
            accB[dt] = __builtin_amdgcn_mfma_f32_16x16x32_bf16(paB1, vf1, accB[dt], 0, 0, 0);
        }

        asm volatile("s_waitcnt vmcnt(0)" ::: "memory");
        __syncthreads();
        cur ^= 1;
    }
    #undef STAGE

    // final denominator: reduce over the 4 lanes sharing lr, then redistribute
    lpA += __shfl_xor(lpA, 16); lpA += __shfl_xor(lpA, 32);
    lpB += __shfl_xor(lpB, 16); lpB += __shfl_xor(lpB, 32);
    float invA = 1.0f / lpA, invB = 1.0f / lpB;

    #pragma unroll
    for (int rr = 0; rr < 4; ++rr) {
        float iA = __shfl(invA, lg * 4 + rr);
        float iB = __shfl(invB, lg * 4 + rr);
        size_t baseA = ((size_t)(b * 1024 + q0a + lg * 4 + rr)) * 1024 + h * 64;
        size_t baseB = ((size_t)(b * 1024 + q0b + lg * 4 + rr)) * 1024 + h * 64;
        #pragma unroll
        for (int dt = 0; dt < 4; ++dt) {
            Y[baseA + dt * 16 + lr] = accA[dt][rr] * iA;
            Y[baseB + dt * 16 + lr] = accB[dt][rr] * iB;
        }
    }
}

extern "C" void kernel_launch(void* const* d_in, const int* in_sizes, int n_in,
                              void* d_out, int out_size, void* d_ws, size_t ws_size,
                              hipStream_t stream) {
    (void)in_sizes; (void)n_in; (void)out_size; (void)ws_size;
    const float* x  = (const float*)d_in[0];
    const float* Wq = (const float*)d_in[1];
    const float* Wk = (const float*)d_in[2];
    const float* Wv = (const float*)d_in[3];
    const float* Wp = (const float*)d_in[4];
    const float* qg = (const float*)d_in[5];
    float* out = (float*)d_out;

    float* p = (float*)d_ws;
    float* partial = p; p += 256;
    float* alpha = p;   p += 16;
    u16* wtqkv = (u16*)p; p += 786432;   // 1536x1024 u16
    u16* wtp   = (u16*)p; p += 524288;   // 1024x1024 u16
    u16* xq    = (u16*)p; p += 4194304;  // 8192x1024 u16 (= 4M floats) -- r8 bug: was 2097152
    float* gam = p; p += 8192;
    float* y   = p; p += 8388608;        // f32 [8192][1024] attn output
    float* cv  = p; p += 2097152;        // f32 [8192][256] V projection
    u16* qo = (u16*)p; p += 4194304;     // bf16 [b,16,1024,64]
    u16* ko = (u16*)p; p += 1048576;     // bf16 [b,4,1024,64]
    u16* vt = (u16*)p; p += 1048576;     // bf16 [b,4,64,pos]
    float* rc = p; p += 32768;
    float* rs = p; p += 32768;
    u16* yq = xq;   // reuse (xq dead after qkv gemm)

    // weight quantization
    k_absmean<<<64, 256, 0, stream>>>(Wq, 1048576, partial + 0);
    k_absmean<<<64, 256, 0, stream>>>(Wk, 262144, partial + 64);
    k_absmean<<<64, 256, 0, stream>>>(Wv, 262144, partial + 128);
    k_absmean<<<64, 256, 0, stream>>>(Wp, 1048576, partial + 192);
    k_alpha<<<1, 64, 0, stream>>>(partial, alpha);
    k_tern<<<512, 256, 0, stream>>>(Wq, alpha, 0, wtqkv, 262144);
    k_tern<<<128, 256, 0, stream>>>(Wk, alpha, 1, wtqkv + 1048576, 65536);
    k_tern<<<128, 256, 0, stream>>>(Wv, alpha, 2, wtqkv + 1310720, 65536);
    k_tern<<<512, 256, 0, stream>>>(Wp, alpha, 3, wtp, 262144);

    // rope table
    k_rope<<<128, 256, 0, stream>>>(rc, rs);

    // activation quantization + fused QKV projection + norm/rope epilogue
    k_quant<<<ROWS, 256, 0, stream>>>(x, xq, gam);
    k_gemm_qkv<<<dim3(12, 64), 256, 0, stream>>>(xq, wtqkv, gam, alpha, rc, rs, qg, qo, ko, cv);

    // V transpose (pos-permuted for swapped-QK attention)
    k_vtransT<<<dim3(16, 4, 8), 256, 0, stream>>>(cv, vt);

    // attention (swapped-QK, in-register P, paired causal tiles)
    k_attn_mfma<<<dim3(8, 16, 8), 256, 0, stream>>>(qo, ko, vt, y);

    // output projection
    k_quant<<<ROWS, 256, 0, stream>>>(y, yq, gam);
    k_gemm_out<<<dim3(8, 64), 256, 0, stream>>>(yq, wtp, gam, alpha, out);
}

// Round 10
// 236.832 us; speedup vs baseline: 1.1273x; 1.1273x over previous
//
#include <hip/hip_runtime.h>
#include <cmath>

#define DIMM 1024
#define NHEADS 16
#define NKV 4
#define HD 64
#define SEQ 1024
#define BSZ 8
#define ROWS (BSZ * SEQ)   // 8192

typedef unsigned short u16;
typedef __attribute__((ext_vector_type(8))) short bf16x8;
typedef __attribute__((ext_vector_type(4))) float f32x4;
typedef __attribute__((ext_vector_type(4))) unsigned short u16x4;

static __device__ __forceinline__ u16 f2bf(float f) {
    union { float f; unsigned u; } v; v.f = f;
    unsigned r = v.u + 0x7FFFu + ((v.u >> 16) & 1u);
    return (u16)(r >> 16);
}

// async global->LDS, 16B per lane; dst must be wave-uniform base (HW adds lane*16)
static __device__ __forceinline__ void gload16(const u16* g, u16* l) {
    __builtin_amdgcn_global_load_lds(
        (const __attribute__((address_space(1))) unsigned int*)g,
        (__attribute__((address_space(3))) unsigned int*)l, 16, 0, 0);
}

// ---------------- weight abs-mean partial reduce ----------------
__global__ __launch_bounds__(256) void k_absmean(const float* __restrict__ w, int n,
                                                 float* __restrict__ partial) {
    float s = 0.f;
    for (int i = blockIdx.x * 256 + threadIdx.x; i < n; i += 64 * 256) s += fabsf(w[i]);
    #pragma unroll
    for (int off = 32; off; off >>= 1) s += __shfl_xor(s, off);
    __shared__ float red[4];
    if ((threadIdx.x & 63) == 0) red[threadIdx.x >> 6] = s;
    __syncthreads();
    if (threadIdx.x == 0) partial[blockIdx.x] = red[0] + red[1] + red[2] + red[3];
}

// ---------------- alpha = max(mean|w|, eps) ----------------
__global__ void k_alpha(const float* __restrict__ partial, float* __restrict__ alpha) {
    int i = threadIdx.x;
    if (i < 4) {
        const int ns[4] = {1048576, 262144, 262144, 1048576};
        float s = 0.f;
        for (int j = 0; j < 64; ++j) s += partial[i * 64 + j];
        alpha[i] = fmaxf(s / (float)ns[i], 1e-8f);
    }
}

// ---------------- ternarize -> bf16 (values {-1,0,1}, exact) ----------------
__global__ __launch_bounds__(256) void k_tern(const float* __restrict__ w,
                                              const float* __restrict__ alpha, int ai,
                                              u16* __restrict__ wt, int n4) {
    float a = alpha[ai];
    for (int i = blockIdx.x * blockDim.x + threadIdx.x; i < n4; i += gridDim.x * blockDim.x) {
        float4 v = *reinterpret_cast<const float4*>(&w[i * 4]);
        u16x4 o;
        o.x = f2bf(rintf(fminf(fmaxf(v.x / a, -1.f), 1.f)));
        o.y = f2bf(rintf(fminf(fmaxf(v.y / a, -1.f), 1.f)));
        o.z = f2bf(rintf(fminf(fmaxf(v.z / a, -1.f), 1.f)));
        o.w = f2bf(rintf(fminf(fmaxf(v.w / a, -1.f), 1.f)));
        *reinterpret_cast<u16x4*>(&wt[i * 4]) = o;
    }
}

// ---------------- per-row activation quantization -> bf16 ints ----------------
__global__ __launch_bounds__(256) void k_quant(const float* __restrict__ X,
                                               u16* __restrict__ Xq, float* __restrict__ g) {
    int row = blockIdx.x;
    const float* xr = X + (size_t)row * DIMM;
    float4 v = *reinterpret_cast<const float4*>(&xr[threadIdx.x * 4]);
    float mv = fmaxf(fmaxf(fabsf(v.x), fabsf(v.y)), fmaxf(fabsf(v.z), fabsf(v.w)));
    #pragma unroll
    for (int off = 32; off; off >>= 1) mv = fmaxf(mv, __shfl_xor(mv, off));
    __shared__ float red[4];
    if ((threadIdx.x & 63) == 0) red[threadIdx.x >> 6] = mv;
    __syncthreads();
    mv = fmaxf(fmaxf(red[0], red[1]), fmaxf(red[2], red[3]));
    float gamma = fmaxf(mv, 1e-8f) / 127.0f;
    u16x4 o;
    o.x = f2bf(rintf(fminf(fmaxf(v.x / gamma, -128.f), 127.f)));
    o.y = f2bf(rintf(fminf(fmaxf(v.y / gamma, -128.f), 127.f)));
    o.z = f2bf(rintf(fminf(fmaxf(v.z / gamma, -128.f), 127.f)));
    o.w = f2bf(rintf(fminf(fmaxf(v.w / gamma, -128.f), 127.f)));
    *reinterpret_cast<u16x4*>(&Xq[(size_t)row * DIMM + threadIdx.x * 4]) = o;
    if (threadIdx.x == 0) g[row] = gamma;
}

// ---------------- QKV GEMM with fused rms_norm+rope epilogue ----------------
__global__ __launch_bounds__(256) void k_gemm_qkv(const u16* __restrict__ A,
                                                  const u16* __restrict__ B,
                                                  const float* __restrict__ gamma,
                                                  const float* __restrict__ alpha_p,
                                                  const float* __restrict__ rc,
                                                  const float* __restrict__ rs,
                                                  const float* __restrict__ gain,
                                                  u16* __restrict__ Qo,
                                                  u16* __restrict__ Ko,
                                                  float* __restrict__ Cv) {
    __shared__ u16 As[128 * 64];
    __shared__ u16 Bs[128 * 64];
    const int K = DIMM;
    int tid = threadIdx.x;
    int w = tid >> 6, lane = tid & 63;
    int lr = lane & 15, lg = lane >> 4;
    int lr7 = lr & 7;
    int wm = w >> 1, wn = w & 1;
    int row0 = blockIdx.y * 128, col0 = blockIdx.x * 128;

    f32x4 acc[4][4];
    #pragma unroll
    for (int mf = 0; mf < 4; ++mf)
        #pragma unroll
        for (int nf = 0; nf < 4; ++nf) acc[mf][nf] = (f32x4){0.f, 0.f, 0.f, 0.f};

    int srow = w * 32 + (lane >> 3);
    int scol = 8 * ((lane & 7) ^ (lane >> 3));
    const u16* Ag = A + (size_t)(row0 + srow) * K + scol;
    const u16* Bg = B + (size_t)(col0 + srow) * K + scol;

    for (int k0 = 0; k0 < K; k0 += 64) {
        #pragma unroll
        for (int i = 0; i < 4; ++i) {
            gload16(Ag + (size_t)i * 8 * K + k0, &As[w * 2048 + i * 512]);
            gload16(Bg + (size_t)i * 8 * K + k0, &Bs[w * 2048 + i * 512]);
        }
        __syncthreads();
        #pragma unroll
        for (int kk = 0; kk < 64; kk += 32) {
            int sl = (kk >> 3);
            bf16x8 af[4], bfr[4];
            #pragma unroll
            for (int mf = 0; mf < 4; ++mf)
                af[mf] = *reinterpret_cast<const bf16x8*>(
                    &As[(wm * 64 + mf * 16 + lr) * 64 + 8 * ((sl + lg) ^ lr7)]);
            #pragma unroll
            for (int nf = 0; nf < 4; ++nf)
                bfr[nf] = *reinterpret_cast<const bf16x8*>(
                    &Bs[(wn * 64 + nf * 16 + lr) * 64 + 8 * ((sl + lg) ^ lr7)]);
            #pragma unroll
            for (int mf = 0; mf < 4; ++mf)
                #pragma unroll
                for (int nf = 0; nf < 4; ++nf)
                    acc[mf][nf] = __builtin_amdgcn_mfma_f32_16x16x32_bf16(af[mf], bfr[nf], acc[mf][nf], 0, 0, 0);
        }
        __syncthreads();
    }

    int c0 = col0 + wn * 64;
    int hh = c0 >> 6;   // 0..15 Q heads, 16..19 K heads, 20..23 V heads
    float alpha = alpha_p[hh < 16 ? 0 : (hh < 20 ? 1 : 2)];
    float ga = (hh < 16) ? gain[hh] * (0.125f * 1.4426950408889634f) : 1.0f;

    #pragma unroll
    for (int mf = 0; mf < 4; ++mf) {
        #pragma unroll
        for (int reg = 0; reg < 4; ++reg) {
            int row = row0 + wm * 64 + mf * 16 + lg * 4 + reg;
            float sc = gamma[row] * alpha;
            float v0 = acc[mf][0][reg] * sc;
            float v1 = acc[mf][1][reg] * sc;
            float v2 = acc[mf][2][reg] * sc;
            float v3 = acc[mf][3][reg] * sc;
            int s = row & 1023, b = row >> 10;
            if (hh < 20) {
                float ss = v0 * v0 + v1 * v1 + v2 * v2 + v3 * v3;
                #pragma unroll
                for (int off = 8; off; off >>= 1) ss += __shfl_xor(ss, off);
                float rn = 1.0f / sqrtf(ss * (1.0f / 64.0f) + 1.1920929e-07f);
                v0 *= rn; v1 *= rn; v2 *= rn; v3 *= rn;
                float cA = rc[s * 32 + lr],      sA = rs[s * 32 + lr];
                float cB = rc[s * 32 + 16 + lr], sB = rs[s * 32 + 16 + lr];
                float y0 = v0 * cA + v2 * sA, y2 = v2 * cA - v0 * sA;
                float y1 = v1 * cB + v3 * sB, y3 = v3 * cB - v1 * sB;
                u16* dst;
                if (hh < 16) {
                    y0 *= ga; y1 *= ga; y2 *= ga; y3 *= ga;
                    dst = Qo + ((size_t)((b * 16 + hh) * 1024 + s)) * 64;
                } else {
                    dst = Ko + ((size_t)((b * 4 + (hh - 16)) * 1024 + s)) * 64;
                }
                dst[lr] = f2bf(y0); dst[16 + lr] = f2bf(y1);
                dst[32 + lr] = f2bf(y2); dst[48 + lr] = f2bf(y3);
            } else {
                float* dst = Cv + (size_t)row * 256 + (hh - 20) * 64;
                dst[lr] = v0; dst[16 + lr] = v1; dst[32 + lr] = v2; dst[48 + lr] = v3;
            }
        }
    }
}

// ---------------- plain GEMM for output projection ----------------
__global__ __launch_bounds__(256) void k_gemm_out(const u16* __restrict__ A,
                                                  const u16* __restrict__ B,
                                                  const float* __restrict__ gamma,
                                                  const float* __restrict__ alpha_p,
                                                  float* __restrict__ C) {
    __shared__ u16 As[128 * 64];
    __shared__ u16 Bs[128 * 64];
    const int K = DIMM;
    int tid = threadIdx.x;
    int w = tid >> 6, lane = tid & 63;
    int lr = lane & 15, lg = lane >> 4;
    int lr7 = lr & 7;
    int wm = w >> 1, wn = w & 1;
    int row0 = blockIdx.y * 128, col0 = blockIdx.x * 128;

    f32x4 acc[4][4];
    #pragma unroll
    for (int mf = 0; mf < 4; ++mf)
        #pragma unroll
        for (int nf = 0; nf < 4; ++nf) acc[mf][nf] = (f32x4){0.f, 0.f, 0.f, 0.f};

    int srow = w * 32 + (lane >> 3);
    int scol = 8 * ((lane & 7) ^ (lane >> 3));
    const u16* Ag = A + (size_t)(row0 + srow) * K + scol;
    const u16* Bg = B + (size_t)(col0 + srow) * K + scol;

    for (int k0 = 0; k0 < K; k0 += 64) {
        #pragma unroll
        for (int i = 0; i < 4; ++i) {
            gload16(Ag + (size_t)i * 8 * K + k0, &As[w * 2048 + i * 512]);
            gload16(Bg + (size_t)i * 8 * K + k0, &Bs[w * 2048 + i * 512]);
        }
        __syncthreads();
        #pragma unroll
        for (int kk = 0; kk < 64; kk += 32) {
            int sl = (kk >> 3);
            bf16x8 af[4], bfr[4];
            #pragma unroll
            for (int mf = 0; mf < 4; ++mf)
                af[mf] = *reinterpret_cast<const bf16x8*>(
                    &As[(wm * 64 + mf * 16 + lr) * 64 + 8 * ((sl + lg) ^ lr7)]);
            #pragma unroll
            for (int nf = 0; nf < 4; ++nf)
                bfr[nf] = *reinterpret_cast<const bf16x8*>(
                    &Bs[(wn * 64 + nf * 16 + lr) * 64 + 8 * ((sl + lg) ^ lr7)]);
            #pragma unroll
            for (int mf = 0; mf < 4; ++mf)
                #pragma unroll
                for (int nf = 0; nf < 4; ++nf)
                    acc[mf][nf] = __builtin_amdgcn_mfma_f32_16x16x32_bf16(af[mf], bfr[nf], acc[mf][nf], 0, 0, 0);
        }
        __syncthreads();
    }

    float alpha = alpha_p[3];
    #pragma unroll
    for (int mf = 0; mf < 4; ++mf) {
        #pragma unroll
        for (int reg = 0; reg < 4; ++reg) {
            int row = row0 + wm * 64 + mf * 16 + lg * 4 + reg;
            float sc = gamma[row] * alpha;
            #pragma unroll
            for (int nf = 0; nf < 4; ++nf)
                C[(size_t)row * 1024 + col0 + wn * 64 + nf * 16 + lr] = acc[mf][nf][reg] * sc;
        }
    }
}

// ---------------- rope table ----------------
__global__ __launch_bounds__(256) void k_rope(float* __restrict__ c, float* __restrict__ s) {
    int idx = blockIdx.x * 256 + threadIdx.x;  // < 32768
    int t = idx >> 5, i = idx & 31;
    float inv = 1.0f / powf(10000.0f, (float)(2 * i) * (1.0f / 64.0f));
    float f = (float)t * inv;
    c[idx] = cosf(f);
    s[idx] = sinf(f);
}

// ---------------- v transpose: Cv [8192][256] f32 -> Vt [b,kv,d,pos] bf16 ----------------
// key pos within each 64-block INTERLEAVED (round-7 mapping, matches packed-P):
// for s = sr+16*i: pos = 2*sr + (i&1) + 32*(i>>1)
__global__ __launch_bounds__(256) void k_vtransT(const float* __restrict__ Cv,
                                                 u16* __restrict__ Vt) {
    __shared__ u16 T[64][72];
    int st = blockIdx.x, kv = blockIdx.y, b = blockIdx.z;
    int tid = threadIdx.x;
    int sr = tid >> 4, d4 = tid & 15;
    #pragma unroll
    for (int i = 0; i < 4; ++i) {
        int s = sr + 16 * i;
        int pos = 2 * sr + (i & 1) + 32 * (i >> 1);
        float4 v = *reinterpret_cast<const float4*>(
            &Cv[(size_t)(b * 1024 + st * 64 + s) * 256 + kv * 64 + d4 * 4]);
        T[d4 * 4 + 0][pos] = f2bf(v.x);
        T[d4 * 4 + 1][pos] = f2bf(v.y);
        T[d4 * 4 + 2][pos] = f2bf(v.z);
        T[d4 * 4 + 3][pos] = f2bf(v.w);
    }
    __syncthreads();
    int d = tid >> 2, c = tid & 3;
    float4 o0 = *reinterpret_cast<const float4*>(&T[d][c * 16]);
    float4 o1 = *reinterpret_cast<const float4*>(&T[d][c * 16 + 8]);
    u16* out = &Vt[(((size_t)(b * 4 + kv) * 64) + d) * 1024 + st * 64 + c * 16];
    *reinterpret_cast<float4*>(out) = o0;
    *reinterpret_cast<float4*>(out + 8) = o1;
}

// ---------------- causal flash attention, bf16 MFMA, paired q-tiles ----------------
// Round-7 structure (76.8 us proven): packed P via per-wave LDS strip, defer-max,
// per-lane denominator partials. LDS 40960 B, plain launch_bounds (VGPR ~116).
__global__ __launch_bounds__(256) void k_attn_mfma(const u16* __restrict__ Q,
                                                   const u16* __restrict__ K,
                                                   const u16* __restrict__ Vt,
                                                   float* __restrict__ Y) {
    __shared__ __align__(16) u16 KVs[2][2][4096];   // [buf][K/V][64*64], swizzled
    __shared__ __align__(16) u16 Ps[4][1024];       // per-wave P strip [16 q][64 pos], swizzled
    int qta = blockIdx.x, qtb = 15 - qta;
    int h = blockIdx.y, b = blockIdx.z;
    int kvh = h >> 2;
    int tid = threadIdx.x;
    int w = tid >> 6, lane = tid & 63;
    int lr = lane & 15, lg = lane >> 4;
    int lr7 = lr & 7;
    int q0a = qta * 64 + w * 16, q0b = qtb * 64 + w * 16;
    const u16* Qb = Q + (((size_t)b * 16 + h) * 1024) * 64;
    const u16* Kb = K + (((size_t)b * 4 + kvh) * 1024) * 64;
    const u16* Vb = Vt + (((size_t)b * 4 + kvh) * 64) * 1024;
    u16* Psw = Ps[w];
    unsigned* Pw32 = reinterpret_cast<unsigned*>(Psw);

    bf16x8 qa0 = *reinterpret_cast<const bf16x8*>(&Qb[(size_t)(q0a + lr) * 64 + 8 * lg]);
    bf16x8 qa1 = *reinterpret_cast<const bf16x8*>(&Qb[(size_t)(q0a + lr) * 64 + 32 + 8 * lg]);
    bf16x8 qb0 = *reinterpret_cast<const bf16x8*>(&Qb[(size_t)(q0b + lr) * 64 + 8 * lg]);
    bf16x8 qb1 = *reinterpret_cast<const bf16x8*>(&Qb[(size_t)(q0b + lr) * 64 + 32 + 8 * lg]);

    float mA[4], lpA[4], mB[4], lpB[4];   // lp = per-lane denominator partial
    f32x4 accA[4], accB[4];
    #pragma unroll
    for (int r = 0; r < 4; ++r) { mA[r] = -INFINITY; lpA[r] = 0.f; mB[r] = -INFINITY; lpB[r] = 0.f; }
    #pragma unroll
    for (int dt = 0; dt < 4; ++dt) { accA[dt] = (f32x4){0.f,0.f,0.f,0.f}; accB[dt] = (f32x4){0.f,0.f,0.f,0.f}; }

    int sub = lane >> 3, s7 = lane & 7;
    int scol16 = s7 ^ sub;
    int c0 = 2 * w, c1 = 2 * w + 1;

    #define STAGE(buf, t_) do { \
        int kk0 = (t_) * 64; \
        gload16(Kb + (size_t)(kk0 + 8 * c0 + sub) * 64 + scol16 * 8, &KVs[buf][0][c0 * 512]); \
        gload16(Kb + (size_t)(kk0 + 8 * c1 + sub) * 64 + scol16 * 8, &KVs[buf][0][c1 * 512]); \
        gload16(Vb + (size_t)(8 * c0 + sub) * 1024 + kk0 + scol16 * 8, &KVs[buf][1][c0 * 512]); \
        gload16(Vb + (size_t)(8 * c1 + sub) * 1024 + kk0 + scol16 * 8, &KVs[buf][1][c1 * 512]); \
    } while (0)

    STAGE(0, 0);
    asm volatile("s_waitcnt vmcnt(0)" ::: "memory");
    __syncthreads();
    int cur = 0;

    for (int t = 0; t <= qtb; ++t) {
        if (t < qtb) STAGE(cur ^ 1, t + 1);
        const int k0 = t * 64;
        const bool doA = (t <= qta);
        const u16* Kl = KVs[cur][0];
        const u16* Vl = KVs[cur][1];

        // ---- QK^T for both tiles (K-frags shared) ----
        float svA[4][4], svB[4][4];
        #pragma unroll
        for (int t4 = 0; t4 < 4; ++t4) {
            int r = t4 * 16 + lr;
            bf16x8 kf0 = *reinterpret_cast<const bf16x8*>(&Kl[r * 64 + ((lg ^ lr7) << 3)]);
            bf16x8 kf1 = *reinterpret_cast<const bf16x8*>(&Kl[r * 64 + (((4 | lg) ^ lr7) << 3)]);
            if (doA) {
                f32x4 z = (f32x4){0.f,0.f,0.f,0.f};
                z = __builtin_amdgcn_mfma_f32_16x16x32_bf16(qa0, kf0, z, 0, 0, 0);
                z = __builtin_amdgcn_mfma_f32_16x16x32_bf16(qa1, kf1, z, 0, 0, 0);
                #pragma unroll
                for (int rr = 0; rr < 4; ++rr) svA[t4][rr] = z[rr];
            }
            f32x4 z2 = (f32x4){0.f,0.f,0.f,0.f};
            z2 = __builtin_amdgcn_mfma_f32_16x16x32_bf16(qb0, kf0, z2, 0, 0, 0);
            z2 = __builtin_amdgcn_mfma_f32_16x16x32_bf16(qb1, kf1, z2, 0, 0, 0);
            #pragma unroll
            for (int rr = 0; rr < 4; ++rr) svB[t4][rr] = z2[rr];
        }
        if (doA && t == qta) {
            #pragma unroll
            for (int t4 = 0; t4 < 4; ++t4) {
                int key = k0 + t4 * 16 + lr;
                #pragma unroll
                for (int rr = 0; rr < 4; ++rr)
                    if (key > q0a + lg * 4 + rr) svA[t4][rr] = -3.0e38f;
            }
        }
        if (t == qtb) {
            #pragma unroll
            for (int t4 = 0; t4 < 4; ++t4) {
                int key = k0 + t4 * 16 + lr;
                #pragma unroll
                for (int rr = 0; rr < 4; ++rr)
                    if (key > q0b + lg * 4 + rr) svB[t4][rr] = -3.0e38f;
            }
        }

        // ---- softmax A (defer-max, packed P store) ----
        bf16x8 paA0, paA1, paB0, paB1;
        if (doA) {
            float vx[4]; int ok = 1;
            #pragma unroll
            for (int rr = 0; rr < 4; ++rr) {
                vx[rr] = fmaxf(fmaxf(svA[0][rr], svA[1][rr]), fmaxf(svA[2][rr], svA[3][rr]));
                ok &= (vx[rr] <= mA[rr] + 8.0f);
            }
            if (!__all(ok)) {
                #pragma unroll
                for (int rr = 0; rr < 4; ++rr) {
                    float mm = vx[rr];
                    #pragma unroll
                    for (int off = 8; off; off >>= 1) mm = fmaxf(mm, __shfl_xor(mm, off));
                    float mn = fmaxf(mA[rr], mm);
                    float corr = exp2f(mA[rr] - mn);
                    mA[rr] = mn;
                    lpA[rr] *= corr;
                    #pragma unroll
                    for (int dt = 0; dt < 4; ++dt) accA[dt][rr] *= corr;
                }
            }
            #pragma unroll
            for (int rr = 0; rr < 4; ++rr) {
                float p0 = exp2f(svA[0][rr] - mA[rr]);
                float p1 = exp2f(svA[1][rr] - mA[rr]);
                float p2 = exp2f(svA[2][rr] - mA[rr]);
                float p3 = exp2f(svA[3][rr] - mA[rr]);
                lpA[rr] += (p0 + p1) + (p2 + p3);
                unsigned pk01, pk23;
                asm("v_cvt_pk_bf16_f32 %0, %1, %2" : "=v"(pk01) : "v"(p0), "v"(p1));
                asm("v_cvt_pk_bf16_f32 %0, %1, %2" : "=v"(pk23) : "v"(p2), "v"(p3));
                int row = lg * 4 + rr, r7 = row & 7;
                Pw32[row * 32 + (((lr >> 2) ^ r7) << 2) + (lr & 3)] = pk01;
                Pw32[row * 32 + ((((lr >> 2) + 4) ^ r7) << 2) + (lr & 3)] = pk23;
            }
            paA0 = *reinterpret_cast<const bf16x8*>(&Psw[lr * 64 + ((lg ^ lr7) << 3)]);
            paA1 = *reinterpret_cast<const bf16x8*>(&Psw[lr * 64 + (((4 | lg) ^ lr7) << 3)]);
        }

        // ---- softmax B (defer-max, packed P store) ----
        {
            float vx[4]; int ok = 1;
            #pragma unroll
            for (int rr = 0; rr < 4; ++rr) {
                vx[rr] = fmaxf(fmaxf(svB[0][rr], svB[1][rr]), fmaxf(svB[2][rr], svB[3][rr]));
                ok &= (vx[rr] <= mB[rr] + 8.0f);
            }
            if (!__all(ok)) {
                #pragma unroll
                for (int rr = 0; rr < 4; ++rr) {
                    float mm = vx[rr];
                    #pragma unroll
                    for (int off = 8; off; off >>= 1) mm = fmaxf(mm, __shfl_xor(mm, off));
                    float mn = fmaxf(mB[rr], mm);
                    float corr = exp2f(mB[rr] - mn);
                    mB[rr] = mn;
                    lpB[rr] *= corr;
                    #pragma unroll
                    for (int dt = 0; dt < 4; ++dt) accB[dt][rr] *= corr;
                }
            }
            #pragma unroll
            for (int rr = 0; rr < 4; ++rr) {
                float p0 = exp2f(svB[0][rr] - mB[rr]);
                float p1 = exp2f(svB[1][rr] - mB[rr]);
                float p2 = exp2f(svB[2][rr] - mB[rr]);
                float p3 = exp2f(svB[3][rr] - mB[rr]);
                lpB[rr] += (p0 + p1) + (p2 + p3);
                unsigned pk01, pk23;
                asm("v_cvt_pk_bf16_f32 %0, %1, %2" : "=v"(pk01) : "v"(p0), "v"(p1));
                asm("v_cvt_pk_bf16_f32 %0, %1, %2" : "=v"(pk23) : "v"(p2), "v"(p3));
                int row = lg * 4 + rr, r7 = row & 7;
                Pw32[row * 32 + (((lr >> 2) ^ r7) << 2) + (lr & 3)] = pk01;
                Pw32[row * 32 + ((((lr >> 2) + 4) ^ r7) << 2) + (lr & 3)] = pk23;
            }
            paB0 = *reinterpret_cast<const bf16x8*>(&Psw[lr * 64 + ((lg ^ lr7) << 3)]);
            paB1 = *reinterpret_cast<const bf16x8*>(&Psw[lr * 64 + (((4 | lg) ^ lr7) << 3)]);
        }

        // ---- PV for both tiles (V-frags shared) ----
        #pragma unroll
        for (int dt = 0; dt < 4; ++dt) {
            int r = dt * 16 + lr;
            bf16x8 vf0 = *reinterpret_cast<const bf16x8*>(&Vl[r * 64 + ((lg ^ lr7) << 3)]);
            bf16x8 vf1 = *reinterpret_cast<const bf16x8*>(&Vl[r * 64 + (((4 | lg) ^ lr7) << 3)]);
            if (doA) {
                accA[dt] = __builtin_amdgcn_mfma_f32_16x16x32_bf16(paA0, vf0, accA[dt], 0, 0, 0);
                accA[dt] = __builtin_amdgcn_mfma_f32_16x16x32_bf16(paA1, vf1, accA[dt], 0, 0, 0);
            }
            accB[dt] = __builtin_amdgcn_mfma_f32_16x16x32_bf16(paB0, vf0, accB[dt], 0, 0, 0);
            accB[dt] = __builtin_amdgcn_mfma_f32_16x16x32_bf16(paB1, vf1, accB[dt], 0, 0, 0);
        }

        asm volatile("s_waitcnt vmcnt(0)" ::: "memory");
        __syncthreads();
        cur ^= 1;
    }
    #undef STAGE

    // final denominator reduce (deferred)
    #pragma unroll
    for (int rr = 0; rr < 4; ++rr) {
        #pragma unroll
        for (int off = 8; off; off >>= 1) {
            lpA[rr] += __shfl_xor(lpA[rr], off);
            lpB[rr] += __shfl_xor(lpB[rr], off);
        }
    }

    #pragma unroll
    for (int rr = 0; rr < 4; ++rr) {
        float invA = 1.0f / lpA[rr];
        float invB = 1.0f / lpB[rr];
        size_t baseA = ((size_t)(b * 1024 + q0a + lg * 4 + rr)) * 1024 + h * 64;
        size_t baseB = ((size_t)(b * 1024 + q0b + lg * 4 + rr)) * 1024 + h * 64;
        #pragma unroll
        for (int dt = 0; dt < 4; ++dt) {
            Y[baseA + dt * 16 + lr] = accA[dt][rr] * invA;
            Y[baseB + dt * 16 + lr] = accB[dt][rr] * invB;
        }
    }
}

extern "C" void kernel_launch(void* const* d_in, const int* in_sizes, int n_in,
                              void* d_out, int out_size, void* d_ws, size_t ws_size,
                              hipStream_t stream) {
    (void)in_sizes; (void)n_in; (void)out_size; (void)ws_size;
    const float* x  = (const float*)d_in[0];
    const float* Wq = (const float*)d_in[1];
    const float* Wk = (const float*)d_in[2];
    const float* Wv = (const float*)d_in[3];
    const float* Wp = (const float*)d_in[4];
    const float* qg = (const float*)d_in[5];
    float* out = (float*)d_out;

    float* p = (float*)d_ws;
    float* partial = p; p += 256;
    float* alpha = p;   p += 16;
    u16* wtqkv = (u16*)p; p += 786432;   // 1536x1024 u16
    u16* wtp   = (u16*)p; p += 524288;   // 1024x1024 u16
    u16* xq    = (u16*)p; p += 4194304;  // 8192x1024 u16 (= 4M floats)
    float* gam = p; p += 8192;
    float* y   = p; p += 8388608;        // f32 [8192][1024] attn output
    float* cv  = p; p += 2097152;        // f32 [8192][256] V projection
    u16* qo = (u16*)p; p += 4194304;     // bf16 [b,16,1024,64]
    u16* ko = (u16*)p; p += 1048576;     // bf16 [b,4,1024,64]
    u16* vt = (u16*)p; p += 1048576;     // bf16 [b,4,64,pos]
    float* rc = p; p += 32768;
    float* rs = p; p += 32768;
    u16* yq = xq;   // reuse (xq dead after qkv gemm)

    // weight quantization
    k_absmean<<<64, 256, 0, stream>>>(Wq, 1048576, partial + 0);
    k_absmean<<<64, 256, 0, stream>>>(Wk, 262144, partial + 64);
    k_absmean<<<64, 256, 0, stream>>>(Wv, 262144, partial + 128);
    k_absmean<<<64, 256, 0, stream>>>(Wp, 1048576, partial + 192);
    k_alpha<<<1, 64, 0, stream>>>(partial, alpha);
    k_tern<<<512, 256, 0, stream>>>(Wq, alpha, 0, wtqkv, 262144);
    k_tern<<<128, 256, 0, stream>>>(Wk, alpha, 1, wtqkv + 1048576, 65536);
    k_tern<<<128, 256, 0, stream>>>(Wv, alpha, 2, wtqkv + 1310720, 65536);
    k_tern<<<512, 256, 0, stream>>>(Wp, alpha, 3, wtp, 262144);

    // rope table
    k_rope<<<128, 256, 0, stream>>>(rc, rs);

    // activation quantization + fused QKV projection + norm/rope epilogue
    k_quant<<<ROWS, 256, 0, stream>>>(x, xq, gam);
    k_gemm_qkv<<<dim3(12, 64), 256, 0, stream>>>(xq, wtqkv, gam, alpha, rc, rs, qg, qo, ko, cv);

    // V transpose (interleaved pos for packed-P attention)
    k_vtransT<<<dim3(16, 4, 8), 256, 0, stream>>>(cv, vt);

    // attention (round-7 structure: packed P via LDS, paired causal tiles)
    k_attn_mfma<<<dim3(8, 16, 8), 256, 0, stream>>>(qo, ko, vt, y);

    // output projection
    k_quant<<<ROWS, 256, 0, stream>>>(y, yq, gam);
    k_gemm_out<<<dim3(8, 64), 256, 0, stream>>>(yq, wtp, gam, alpha, out);
}

// Round 11
// 196.227 us; speedup vs baseline: 1.3606x; 1.2069x over previous
//
#include <hip/hip_runtime.h>
#include <cmath>

#define DIMM 1024
#define NHEADS 16
#define NKV 4
#define HD 64
#define SEQ 1024
#define BSZ 8
#define ROWS (BSZ * SEQ)   // 8192

typedef unsigned short u16;
typedef __attribute__((ext_vector_type(8))) short bf16x8;
typedef __attribute__((ext_vector_type(4))) float f32x4;
typedef __attribute__((ext_vector_type(4))) unsigned short u16x4;

static __device__ __forceinline__ u16 f2bf(float f) {
    union { float f; unsigned u; } v; v.f = f;
    unsigned r = v.u + 0x7FFFu + ((v.u >> 16) & 1u);
    return (u16)(r >> 16);
}
static __device__ __forceinline__ float bf2f(u16 h) {
    union { unsigned u; float f; } v; v.u = ((unsigned)h) << 16;
    return v.f;
}

// async global->LDS, 16B per lane; dst must be wave-uniform base (HW adds lane*16)
static __device__ __forceinline__ void gload16(const u16* g, u16* l) {
    __builtin_amdgcn_global_load_lds(
        (const __attribute__((address_space(1))) unsigned int*)g,
        (__attribute__((address_space(3))) unsigned int*)l, 16, 0, 0);
}

// ---------------- fused weight abs-mean: 4 weights, one dispatch ----------------
// grid 256: blocks [0,64) Wq, [64,128) Wk, [128,192) Wv, [192,256) Wp
__global__ __launch_bounds__(256) void k_absmean_all(const float* __restrict__ Wq,
                                                     const float* __restrict__ Wk,
                                                     const float* __restrict__ Wv,
                                                     const float* __restrict__ Wp,
                                                     float* __restrict__ partial) {
    int wi = blockIdx.x >> 6, local = blockIdx.x & 63;
    const float* w = (wi == 0) ? Wq : (wi == 1) ? Wk : (wi == 2) ? Wv : Wp;
    int n = (wi == 0 || wi == 3) ? 1048576 : 262144;
    float s = 0.f;
    for (int i = local * 256 + threadIdx.x; i < n; i += 64 * 256) s += fabsf(w[i]);
    #pragma unroll
    for (int off = 32; off; off >>= 1) s += __shfl_xor(s, off);
    __shared__ float red[4];
    if ((threadIdx.x & 63) == 0) red[threadIdx.x >> 6] = s;
    __syncthreads();
    if (threadIdx.x == 0) partial[blockIdx.x] = red[0] + red[1] + red[2] + red[3];
}

// ---------------- rope table + alpha (fused) ----------------
__global__ __launch_bounds__(256) void k_rope_alpha(float* __restrict__ c, float* __restrict__ s,
                                                    const float* __restrict__ partial,
                                                    float* __restrict__ alpha) {
    int idx = blockIdx.x * 256 + threadIdx.x;  // < 32768
    int t = idx >> 5, i = idx & 31;
    float inv = 1.0f / powf(10000.0f, (float)(2 * i) * (1.0f / 64.0f));
    float f = (float)t * inv;
    c[idx] = cosf(f);
    s[idx] = sinf(f);
    if (blockIdx.x == 0 && threadIdx.x < 4) {
        const int ns[4] = {1048576, 262144, 262144, 1048576};
        float su = 0.f;
        for (int j = 0; j < 64; ++j) su += partial[threadIdx.x * 64 + j];
        alpha[threadIdx.x] = fmaxf(su / (float)ns[threadIdx.x], 1e-8f);
    }
}

// ---------------- fused ternarize: all 4 weights, one dispatch ----------------
// flat float4 index: [0,262144) Wq, [262144,327680) Wk, [327680,393216) Wv, rest Wp
__global__ __launch_bounds__(256) void k_tern_all(const float* __restrict__ Wq,
                                                  const float* __restrict__ Wk,
                                                  const float* __restrict__ Wv,
                                                  const float* __restrict__ Wp,
                                                  const float* __restrict__ alpha,
                                                  u16* __restrict__ wtqkv,
                                                  u16* __restrict__ wtp) {
    int idx = blockIdx.x * 256 + threadIdx.x;   // < 655360
    const float* src; u16* dst; float a;
    if (idx < 262144)      { src = Wq + (size_t)idx * 4;            dst = wtqkv + (size_t)idx * 4;                 a = alpha[0]; }
    else if (idx < 327680) { src = Wk + (size_t)(idx - 262144) * 4; dst = wtqkv + 1048576 + (size_t)(idx - 262144) * 4; a = alpha[1]; }
    else if (idx < 393216) { src = Wv + (size_t)(idx - 327680) * 4; dst = wtqkv + 1310720 + (size_t)(idx - 327680) * 4; a = alpha[2]; }
    else                   { src = Wp + (size_t)(idx - 393216) * 4; dst = wtp + (size_t)(idx - 393216) * 4;        a = alpha[3]; }
    float4 v = *reinterpret_cast<const float4*>(src);
    u16x4 o;
    o.x = f2bf(rintf(fminf(fmaxf(v.x / a, -1.f), 1.f)));
    o.y = f2bf(rintf(fminf(fmaxf(v.y / a, -1.f), 1.f)));
    o.z = f2bf(rintf(fminf(fmaxf(v.z / a, -1.f), 1.f)));
    o.w = f2bf(rintf(fminf(fmaxf(v.w / a, -1.f), 1.f)));
    *reinterpret_cast<u16x4*>(dst) = o;
}

// ---------------- per-row activation quantization (f32 input) -> bf16 ints ----------------
__global__ __launch_bounds__(256) void k_quant(const float* __restrict__ X,
                                               u16* __restrict__ Xq, float* __restrict__ g) {
    int row = blockIdx.x;
    const float* xr = X + (size_t)row * DIMM;
    float4 v = *reinterpret_cast<const float4*>(&xr[threadIdx.x * 4]);
    float mv = fmaxf(fmaxf(fabsf(v.x), fabsf(v.y)), fmaxf(fabsf(v.z), fabsf(v.w)));
    #pragma unroll
    for (int off = 32; off; off >>= 1) mv = fmaxf(mv, __shfl_xor(mv, off));
    __shared__ float red[4];
    if ((threadIdx.x & 63) == 0) red[threadIdx.x >> 6] = mv;
    __syncthreads();
    mv = fmaxf(fmaxf(red[0], red[1]), fmaxf(red[2], red[3]));
    float gamma = fmaxf(mv, 1e-8f) / 127.0f;
    u16x4 o;
    o.x = f2bf(rintf(fminf(fmaxf(v.x / gamma, -128.f), 127.f)));
    o.y = f2bf(rintf(fminf(fmaxf(v.y / gamma, -128.f), 127.f)));
    o.z = f2bf(rintf(fminf(fmaxf(v.z / gamma, -128.f), 127.f)));
    o.w = f2bf(rintf(fminf(fmaxf(v.w / gamma, -128.f), 127.f)));
    *reinterpret_cast<u16x4*>(&Xq[(size_t)row * DIMM + threadIdx.x * 4]) = o;
    if (threadIdx.x == 0) g[row] = gamma;
}

// ---------------- per-row activation quantization (bf16 input) -> bf16 ints ----------------
__global__ __launch_bounds__(256) void k_quant_bf16(const u16* __restrict__ X,
                                                    u16* __restrict__ Xq, float* __restrict__ g) {
    int row = blockIdx.x;
    const u16* xr = X + (size_t)row * DIMM;
    u16x4 h = *reinterpret_cast<const u16x4*>(&xr[threadIdx.x * 4]);
    float v0 = bf2f(h.x), v1 = bf2f(h.y), v2 = bf2f(h.z), v3 = bf2f(h.w);
    float mv = fmaxf(fmaxf(fabsf(v0), fabsf(v1)), fmaxf(fabsf(v2), fabsf(v3)));
    #pragma unroll
    for (int off = 32; off; off >>= 1) mv = fmaxf(mv, __shfl_xor(mv, off));
    __shared__ float red[4];
    if ((threadIdx.x & 63) == 0) red[threadIdx.x >> 6] = mv;
    __syncthreads();
    mv = fmaxf(fmaxf(red[0], red[1]), fmaxf(red[2], red[3]));
    float gamma = fmaxf(mv, 1e-8f) / 127.0f;
    u16x4 o;
    o.x = f2bf(rintf(fminf(fmaxf(v0 / gamma, -128.f), 127.f)));
    o.y = f2bf(rintf(fminf(fmaxf(v1 / gamma, -128.f), 127.f)));
    o.z = f2bf(rintf(fminf(fmaxf(v2 / gamma, -128.f), 127.f)));
    o.w = f2bf(rintf(fminf(fmaxf(v3 / gamma, -128.f), 127.f)));
    *reinterpret_cast<u16x4*>(&Xq[(size_t)row * DIMM + threadIdx.x * 4]) = o;
    if (threadIdx.x == 0) g[row] = gamma;
}

// ---------------- QKV GEMM with fused rms_norm+rope epilogue ----------------
__global__ __launch_bounds__(256) void k_gemm_qkv(const u16* __restrict__ A,
                                                  const u16* __restrict__ B,
                                                  const float* __restrict__ gamma,
                                                  const float* __restrict__ alpha_p,
                                                  const float* __restrict__ rc,
                                                  const float* __restrict__ rs,
                                                  const float* __restrict__ gain,
                                                  u16* __restrict__ Qo,
                                                  u16* __restrict__ Ko,
                                                  float* __restrict__ Cv) {
    __shared__ u16 As[128 * 64];
    __shared__ u16 Bs[128 * 64];
    const int K = DIMM;
    int tid = threadIdx.x;
    int w = tid >> 6, lane = tid & 63;
    int lr = lane & 15, lg = lane >> 4;
    int lr7 = lr & 7;
    int wm = w >> 1, wn = w & 1;
    int row0 = blockIdx.y * 128, col0 = blockIdx.x * 128;

    f32x4 acc[4][4];
    #pragma unroll
    for (int mf = 0; mf < 4; ++mf)
        #pragma unroll
        for (int nf = 0; nf < 4; ++nf) acc[mf][nf] = (f32x4){0.f, 0.f, 0.f, 0.f};

    int srow = w * 32 + (lane >> 3);
    int scol = 8 * ((lane & 7) ^ (lane >> 3));
    const u16* Ag = A + (size_t)(row0 + srow) * K + scol;
    const u16* Bg = B + (size_t)(col0 + srow) * K + scol;

    for (int k0 = 0; k0 < K; k0 += 64) {
        #pragma unroll
        for (int i = 0; i < 4; ++i) {
            gload16(Ag + (size_t)i * 8 * K + k0, &As[w * 2048 + i * 512]);
            gload16(Bg + (size_t)i * 8 * K + k0, &Bs[w * 2048 + i * 512]);
        }
        __syncthreads();
        #pragma unroll
        for (int kk = 0; kk < 64; kk += 32) {
            int sl = (kk >> 3);
            bf16x8 af[4], bfr[4];
            #pragma unroll
            for (int mf = 0; mf < 4; ++mf)
                af[mf] = *reinterpret_cast<const bf16x8*>(
                    &As[(wm * 64 + mf * 16 + lr) * 64 + 8 * ((sl + lg) ^ lr7)]);
            #pragma unroll
            for (int nf = 0; nf < 4; ++nf)
                bfr[nf] = *reinterpret_cast<const bf16x8*>(
                    &Bs[(wn * 64 + nf * 16 + lr) * 64 + 8 * ((sl + lg) ^ lr7)]);
            #pragma unroll
            for (int mf = 0; mf < 4; ++mf)
                #pragma unroll
                for (int nf = 0; nf < 4; ++nf)
                    acc[mf][nf] = __builtin_amdgcn_mfma_f32_16x16x32_bf16(af[mf], bfr[nf], acc[mf][nf], 0, 0, 0);
        }
        __syncthreads();
    }

    int c0 = col0 + wn * 64;
    int hh = c0 >> 6;   // 0..15 Q heads, 16..19 K heads, 20..23 V heads
    float alpha = alpha_p[hh < 16 ? 0 : (hh < 20 ? 1 : 2)];
    float ga = (hh < 16) ? gain[hh] * (0.125f * 1.4426950408889634f) : 1.0f;

    #pragma unroll
    for (int mf = 0; mf < 4; ++mf) {
        #pragma unroll
        for (int reg = 0; reg < 4; ++reg) {
            int row = row0 + wm * 64 + mf * 16 + lg * 4 + reg;
            float sc = gamma[row] * alpha;
            float v0 = acc[mf][0][reg] * sc;
            float v1 = acc[mf][1][reg] * sc;
            float v2 = acc[mf][2][reg] * sc;
            float v3 = acc[mf][3][reg] * sc;
            int s = row & 1023, b = row >> 10;
            if (hh < 20) {
                float ss = v0 * v0 + v1 * v1 + v2 * v2 + v3 * v3;
                #pragma unroll
                for (int off = 8; off; off >>= 1) ss += __shfl_xor(ss, off);
                float rn = 1.0f / sqrtf(ss * (1.0f / 64.0f) + 1.1920929e-07f);
                v0 *= rn; v1 *= rn; v2 *= rn; v3 *= rn;
                float cA = rc[s * 32 + lr],      sA = rs[s * 32 + lr];
                float cB = rc[s * 32 + 16 + lr], sB = rs[s * 32 + 16 + lr];
                float y0 = v0 * cA + v2 * sA, y2 = v2 * cA - v0 * sA;
                float y1 = v1 * cB + v3 * sB, y3 = v3 * cB - v1 * sB;
                u16* dst;
                if (hh < 16) {
                    y0 *= ga; y1 *= ga; y2 *= ga; y3 *= ga;
                    dst = Qo + ((size_t)((b * 16 + hh) * 1024 + s)) * 64;
                } else {
                    dst = Ko + ((size_t)((b * 4 + (hh - 16)) * 1024 + s)) * 64;
                }
                dst[lr] = f2bf(y0); dst[16 + lr] = f2bf(y1);
                dst[32 + lr] = f2bf(y2); dst[48 + lr] = f2bf(y3);
            } else {
                float* dst = Cv + (size_t)row * 256 + (hh - 20) * 64;
                dst[lr] = v0; dst[16 + lr] = v1; dst[32 + lr] = v2; dst[48 + lr] = v3;
            }
        }
    }
}

// ---------------- plain GEMM for output projection ----------------
__global__ __launch_bounds__(256) void k_gemm_out(const u16* __restrict__ A,
                                                  const u16* __restrict__ B,
                                                  const float* __restrict__ gamma,
                                                  const float* __restrict__ alpha_p,
                                                  float* __restrict__ C) {
    __shared__ u16 As[128 * 64];
    __shared__ u16 Bs[128 * 64];
    const int K = DIMM;
    int tid = threadIdx.x;
    int w = tid >> 6, lane = tid & 63;
    int lr = lane & 15, lg = lane >> 4;
    int lr7 = lr & 7;
    int wm = w >> 1, wn = w & 1;
    int row0 = blockIdx.y * 128, col0 = blockIdx.x * 128;

    f32x4 acc[4][4];
    #pragma unroll
    for (int mf = 0; mf < 4; ++mf)
        #pragma unroll
        for (int nf = 0; nf < 4; ++nf) acc[mf][nf] = (f32x4){0.f, 0.f, 0.f, 0.f};

    int srow = w * 32 + (lane >> 3);
    int scol = 8 * ((lane & 7) ^ (lane >> 3));
    const u16* Ag = A + (size_t)(row0 + srow) * K + scol;
    const u16* Bg = B + (size_t)(col0 + srow) * K + scol;

    for (int k0 = 0; k0 < K; k0 += 64) {
        #pragma unroll
        for (int i = 0; i < 4; ++i) {
            gload16(Ag + (size_t)i * 8 * K + k0, &As[w * 2048 + i * 512]);
            gload16(Bg + (size_t)i * 8 * K + k0, &Bs[w * 2048 + i * 512]);
        }
        __syncthreads();
        #pragma unroll
        for (int kk = 0; kk < 64; kk += 32) {
            int sl = (kk >> 3);
            bf16x8 af[4], bfr[4];
            #pragma unroll
            for (int mf = 0; mf < 4; ++mf)
                af[mf] = *reinterpret_cast<const bf16x8*>(
                    &As[(wm * 64 + mf * 16 + lr) * 64 + 8 * ((sl + lg) ^ lr7)]);
            #pragma unroll
            for (int nf = 0; nf < 4; ++nf)
                bfr[nf] = *reinterpret_cast<const bf16x8*>(
                    &Bs[(wn * 64 + nf * 16 + lr) * 64 + 8 * ((sl + lg) ^ lr7)]);
            #pragma unroll
            for (int mf = 0; mf < 4; ++mf)
                #pragma unroll
                for (int nf = 0; nf < 4; ++nf)
                    acc[mf][nf] = __builtin_amdgcn_mfma_f32_16x16x32_bf16(af[mf], bfr[nf], acc[mf][nf], 0, 0, 0);
        }
        __syncthreads();
    }

    float alpha = alpha_p[3];
    #pragma unroll
    for (int mf = 0; mf < 4; ++mf) {
        #pragma unroll
        for (int reg = 0; reg < 4; ++reg) {
            int row = row0 + wm * 64 + mf * 16 + lg * 4 + reg;
            float sc = gamma[row] * alpha;
            #pragma unroll
            for (int nf = 0; nf < 4; ++nf)
                C[(size_t)row * 1024 + col0 + wn * 64 + nf * 16 + lr] = acc[mf][nf][reg] * sc;
        }
    }
}

// ---------------- v transpose: Cv [8192][256] f32 -> Vt [b,kv,d,pos] bf16 ----------------
// key pos within each 64-block INTERLEAVED: for s = sr+16*i: pos = 2*sr + (i&1) + 32*(i>>1)
__global__ __launch_bounds__(256) void k_vtransT(const float* __restrict__ Cv,
                                                 u16* __restrict__ Vt) {
    __shared__ u16 T[64][72];
    int st = blockIdx.x, kv = blockIdx.y, b = blockIdx.z;
    int tid = threadIdx.x;
    int sr = tid >> 4, d4 = tid & 15;
    #pragma unroll
    for (int i = 0; i < 4; ++i) {
        int s = sr + 16 * i;
        int pos = 2 * sr + (i & 1) + 32 * (i >> 1);
        float4 v = *reinterpret_cast<const float4*>(
            &Cv[(size_t)(b * 1024 + st * 64 + s) * 256 + kv * 64 + d4 * 4]);
        T[d4 * 4 + 0][pos] = f2bf(v.x);
        T[d4 * 4 + 1][pos] = f2bf(v.y);
        T[d4 * 4 + 2][pos] = f2bf(v.z);
        T[d4 * 4 + 3][pos] = f2bf(v.w);
    }
    __syncthreads();
    int d = tid >> 2, c = tid & 3;
    float4 o0 = *reinterpret_cast<const float4*>(&T[d][c * 16]);
    float4 o1 = *reinterpret_cast<const float4*>(&T[d][c * 16 + 8]);
    u16* out = &Vt[(((size_t)(b * 4 + kv) * 64) + d) * 1024 + st * 64 + c * 16];
    *reinterpret_cast<float4*>(out) = o0;
    *reinterpret_cast<float4*>(out + 8) = o1;
}

// ---------------- causal flash attention, bf16 MFMA, paired q-tiles ----------------
// Round-10 proven structure + setprio(T5) + bf16 Y output.
__global__ __launch_bounds__(256) void k_attn_mfma(const u16* __restrict__ Q,
                                                   const u16* __restrict__ K,
                                                   const u16* __restrict__ Vt,
                                                   u16* __restrict__ Y) {
    __shared__ __align__(16) u16 KVs[2][2][4096];   // [buf][K/V][64*64], swizzled
    __shared__ __align__(16) u16 Ps[4][1024];       // per-wave P strip [16 q][64 pos], swizzled
    int qta = blockIdx.x, qtb = 15 - qta;
    int h = blockIdx.y, b = blockIdx.z;
    int kvh = h >> 2;
    int tid = threadIdx.x;
    int w = tid >> 6, lane = tid & 63;
    int lr = lane & 15, lg = lane >> 4;
    int lr7 = lr & 7;
    int q0a = qta * 64 + w * 16, q0b = qtb * 64 + w * 16;
    const u16* Qb = Q + (((size_t)b * 16 + h) * 1024) * 64;
    const u16* Kb = K + (((size_t)b * 4 + kvh) * 1024) * 64;
    const u16* Vb = Vt + (((size_t)b * 4 + kvh) * 64) * 1024;
    u16* Psw = Ps[w];
    unsigned* Pw32 = reinterpret_cast<unsigned*>(Psw);

    bf16x8 qa0 = *reinterpret_cast<const bf16x8*>(&Qb[(size_t)(q0a + lr) * 64 + 8 * lg]);
    bf16x8 qa1 = *reinterpret_cast<const bf16x8*>(&Qb[(size_t)(q0a + lr) * 64 + 32 + 8 * lg]);
    bf16x8 qb0 = *reinterpret_cast<const bf16x8*>(&Qb[(size_t)(q0b + lr) * 64 + 8 * lg]);
    bf16x8 qb1 = *reinterpret_cast<const bf16x8*>(&Qb[(size_t)(q0b + lr) * 64 + 32 + 8 * lg]);

    float mA[4], lpA[4], mB[4], lpB[4];   // lp = per-lane denominator partial
    f32x4 accA[4], accB[4];
    #pragma unroll
    for (int r = 0; r < 4; ++r) { mA[r] = -INFINITY; lpA[r] = 0.f; mB[r] = -INFINITY; lpB[r] = 0.f; }
    #pragma unroll
    for (int dt = 0; dt < 4; ++dt) { accA[dt] = (f32x4){0.f,0.f,0.f,0.f}; accB[dt] = (f32x4){0.f,0.f,0.f,0.f}; }

    int sub = lane >> 3, s7 = lane & 7;
    int scol16 = s7 ^ sub;
    int c0 = 2 * w, c1 = 2 * w + 1;

    #define STAGE(buf, t_) do { \
        int kk0 = (t_) * 64; \
        gload16(Kb + (size_t)(kk0 + 8 * c0 + sub) * 64 + scol16 * 8, &KVs[buf][0][c0 * 512]); \
        gload16(Kb + (size_t)(kk0 + 8 * c1 + sub) * 64 + scol16 * 8, &KVs[buf][0][c1 * 512]); \
        gload16(Vb + (size_t)(8 * c0 + sub) * 1024 + kk0 + scol16 * 8, &KVs[buf][1][c0 * 512]); \
        gload16(Vb + (size_t)(8 * c1 + sub) * 1024 + kk0 + scol16 * 8, &KVs[buf][1][c1 * 512]); \
    } while (0)

    STAGE(0, 0);
    asm volatile("s_waitcnt vmcnt(0)" ::: "memory");
    __syncthreads();
    int cur = 0;

    for (int t = 0; t <= qtb; ++t) {
        if (t < qtb) STAGE(cur ^ 1, t + 1);
        const int k0 = t * 64;
        const bool doA = (t <= qta);
        const u16* Kl = KVs[cur][0];
        const u16* Vl = KVs[cur][1];

        // ---- QK^T for both tiles (K-frags shared) ----
        float svA[4][4], svB[4][4];
        __builtin_amdgcn_s_setprio(1);
        #pragma unroll
        for (int t4 = 0; t4 < 4; ++t4) {
            int r = t4 * 16 + lr;
            bf16x8 kf0 = *reinterpret_cast<const bf16x8*>(&Kl[r * 64 + ((lg ^ lr7) << 3)]);
            bf16x8 kf1 = *reinterpret_cast<const bf16x8*>(&Kl[r * 64 + (((4 | lg) ^ lr7) << 3)]);
            if (doA) {
                f32x4 z = (f32x4){0.f,0.f,0.f,0.f};
                z = __builtin_amdgcn_mfma_f32_16x16x32_bf16(qa0, kf0, z, 0, 0, 0);
                z = __builtin_amdgcn_mfma_f32_16x16x32_bf16(qa1, kf1, z, 0, 0, 0);
                #pragma unroll
                for (int rr = 0; rr < 4; ++rr) svA[t4][rr] = z[rr];
            }
            f32x4 z2 = (f32x4){0.f,0.f,0.f,0.f};
            z2 = __builtin_amdgcn_mfma_f32_16x16x32_bf16(qb0, kf0, z2, 0, 0, 0);
            z2 = __builtin_amdgcn_mfma_f32_16x16x32_bf16(qb1, kf1, z2, 0, 0, 0);
            #pragma unroll
            for (int rr = 0; rr < 4; ++rr) svB[t4][rr] = z2[rr];
        }
        __builtin_amdgcn_s_setprio(0);
        if (doA && t == qta) {
            #pragma unroll
            for (int t4 = 0; t4 < 4; ++t4) {
                int key = k0 + t4 * 16 + lr;
                #pragma unroll
                for (int rr = 0; rr < 4; ++rr)
                    if (key > q0a + lg * 4 + rr) svA[t4][rr] = -3.0e38f;
            }
        }
        if (t == qtb) {
            #pragma unroll
            for (int t4 = 0; t4 < 4; ++t4) {
                int key = k0 + t4 * 16 + lr;
                #pragma unroll
                for (int rr = 0; rr < 4; ++rr)
                    if (key > q0b + lg * 4 + rr) svB[t4][rr] = -3.0e38f;
            }
        }

        // ---- softmax A (defer-max, packed P store) ----
        bf16x8 paA0, paA1, paB0, paB1;
        if (doA) {
            float vx[4]; int ok = 1;
            #pragma unroll
            for (int rr = 0; rr < 4; ++rr) {
                vx[rr] = fmaxf(fmaxf(svA[0][rr], svA[1][rr]), fmaxf(svA[2][rr], svA[3][rr]));
                ok &= (vx[rr] <= mA[rr] + 8.0f);
            }
            if (!__all(ok)) {
                #pragma unroll
                for (int rr = 0; rr < 4; ++rr) {
                    float mm = vx[rr];
                    #pragma unroll
                    for (int off = 8; off; off >>= 1) mm = fmaxf(mm, __shfl_xor(mm, off));
                    float mn = fmaxf(mA[rr], mm);
                    float corr = exp2f(mA[rr] - mn);
                    mA[rr] = mn;
                    lpA[rr] *= corr;
                    #pragma unroll
                    for (int dt = 0; dt < 4; ++dt) accA[dt][rr] *= corr;
                }
            }
            #pragma unroll
            for (int rr = 0; rr < 4; ++rr) {
                float p0 = exp2f(svA[0][rr] - mA[rr]);
                float p1 = exp2f(svA[1][rr] - mA[rr]);
                float p2 = exp2f(svA[2][rr] - mA[rr]);
                float p3 = exp2f(svA[3][rr] - mA[rr]);
                lpA[rr] += (p0 + p1) + (p2 + p3);
                unsigned pk01, pk23;
                asm("v_cvt_pk_bf16_f32 %0, %1, %2" : "=v"(pk01) : "v"(p0), "v"(p1));
                asm("v_cvt_pk_bf16_f32 %0, %1, %2" : "=v"(pk23) : "v"(p2), "v"(p3));
                int row = lg * 4 + rr, r7 = row & 7;
                Pw32[row * 32 + (((lr >> 2) ^ r7) << 2) + (lr & 3)] = pk01;
                Pw32[row * 32 + ((((lr >> 2) + 4) ^ r7) << 2) + (lr & 3)] = pk23;
            }
            paA0 = *reinterpret_cast<const bf16x8*>(&Psw[lr * 64 + ((lg ^ lr7) << 3)]);
            paA1 = *reinterpret_cast<const bf16x8*>(&Psw[lr * 64 + (((4 | lg) ^ lr7) << 3)]);
        }

        // ---- softmax B (defer-max, packed P store) ----
        {
            float vx[4]; int ok = 1;
            #pragma unroll
            for (int rr = 0; rr < 4; ++rr) {
                vx[rr] = fmaxf(fmaxf(svB[0][rr], svB[1][rr]), fmaxf(svB[2][rr], svB[3][rr]));
                ok &= (vx[rr] <= mB[rr] + 8.0f);
            }
            if (!__all(ok)) {
                #pragma unroll
                for (int rr = 0; rr < 4; ++rr) {
                    float mm = vx[rr];
                    #pragma unroll
                    for (int off = 8; off; off >>= 1) mm = fmaxf(mm, __shfl_xor(mm, off));
                    float mn = fmaxf(mB[rr], mm);
                    float corr = exp2f(mB[rr] - mn);
                    mB[rr] = mn;
                    lpB[rr] *= corr;
                    #pragma unroll
                    for (int dt = 0; dt < 4; ++dt) accB[dt][rr] *= corr;
                }
            }
            #pragma unroll
            for (int rr = 0; rr < 4; ++rr) {
                float p0 = exp2f(svB[0][rr] - mB[rr]);
                float p1 = exp2f(svB[1][rr] - mB[rr]);
                float p2 = exp2f(svB[2][rr] - mB[rr]);
                float p3 = exp2f(svB[3][rr] - mB[rr]);
                lpB[rr] += (p0 + p1) + (p2 + p3);
                unsigned pk01, pk23;
                asm("v_cvt_pk_bf16_f32 %0, %1, %2" : "=v"(pk01) : "v"(p0), "v"(p1));
                asm("v_cvt_pk_bf16_f32 %0, %1, %2" : "=v"(pk23) : "v"(p2), "v"(p3));
                int row = lg * 4 + rr, r7 = row & 7;
                Pw32[row * 32 + (((lr >> 2) ^ r7) << 2) + (lr & 3)] = pk01;
                Pw32[row * 32 + ((((lr >> 2) + 4) ^ r7) << 2) + (lr & 3)] = pk23;
            }
            paB0 = *reinterpret_cast<const bf16x8*>(&Psw[lr * 64 + ((lg ^ lr7) << 3)]);
            paB1 = *reinterpret_cast<const bf16x8*>(&Psw[lr * 64 + (((4 | lg) ^ lr7) << 3)]);
        }

        // ---- PV for both tiles (V-frags shared) ----
        __builtin_amdgcn_s_setprio(1);
        #pragma unroll
        for (int dt = 0; dt < 4; ++dt) {
            int r = dt * 16 + lr;
            bf16x8 vf0 = *reinterpret_cast<const bf16x8*>(&Vl[r * 64 + ((lg ^ lr7) << 3)]);
            bf16x8 vf1 = *reinterpret_cast<const bf16x8*>(&Vl[r * 64 + (((4 | lg) ^ lr7) << 3)]);
            if (doA) {
                accA[dt] = __builtin_amdgcn_mfma_f32_16x16x32_bf16(paA0, vf0, accA[dt], 0, 0, 0);
                accA[dt] = __builtin_amdgcn_mfma_f32_16x16x32_bf16(paA1, vf1, accA[dt], 0, 0, 0);
            }
            accB[dt] = __builtin_amdgcn_mfma_f32_16x16x32_bf16(paB0, vf0, accB[dt], 0, 0, 0);
            accB[dt] = __builtin_amdgcn_mfma_f32_16x16x32_bf16(paB1, vf1, accB[dt], 0, 0, 0);
        }
        __builtin_amdgcn_s_setprio(0);

        asm volatile("s_waitcnt vmcnt(0)" ::: "memory");
        __syncthreads();
        cur ^= 1;
    }
    #undef STAGE

    // final denominator reduce (deferred)
    #pragma unroll
    for (int rr = 0; rr < 4; ++rr) {
        #pragma unroll
        for (int off = 8; off; off >>= 1) {
            lpA[rr] += __shfl_xor(lpA[rr], off);
            lpB[rr] += __shfl_xor(lpB[rr], off);
        }
    }

    #pragma unroll
    for (int rr = 0; rr < 4; ++rr) {
        float invA = 1.0f / lpA[rr];
        float invB = 1.0f / lpB[rr];
        size_t baseA = ((size_t)(b * 1024 + q0a + lg * 4 + rr)) * 1024 + h * 64;
        size_t baseB = ((size_t)(b * 1024 + q0b + lg * 4 + rr)) * 1024 + h * 64;
        #pragma unroll
        for (int dt = 0; dt < 4; ++dt) {
            Y[baseA + dt * 16 + lr] = f2bf(accA[dt][rr] * invA);
            Y[baseB + dt * 16 + lr] = f2bf(accB[dt][rr] * invB);
        }
    }
}

extern "C" void kernel_launch(void* const* d_in, const int* in_sizes, int n_in,
                              void* d_out, int out_size, void* d_ws, size_t ws_size,
                              hipStream_t stream) {
    (void)in_sizes; (void)n_in; (void)out_size; (void)ws_size;
    const float* x  = (const float*)d_in[0];
    const float* Wq = (const float*)d_in[1];
    const float* Wk = (const float*)d_in[2];
    const float* Wv = (const float*)d_in[3];
    const float* Wp = (const float*)d_in[4];
    const float* qg = (const float*)d_in[5];
    float* out = (float*)d_out;

    float* p = (float*)d_ws;
    float* partial = p; p += 256;
    float* alpha = p;   p += 16;
    u16* wtqkv = (u16*)p; p += 786432;   // 1536x1024 u16
    u16* wtp   = (u16*)p; p += 524288;   // 1024x1024 u16
    u16* xq    = (u16*)p; p += 4194304;  // 8192x1024 u16
    float* gam = p; p += 8192;
    u16* y16   = (u16*)p; p += 4194304;  // bf16 [8192][1024] attn output
    float* cv  = p; p += 2097152;        // f32 [8192][256] V projection
    u16* qo = (u16*)p; p += 4194304;     // bf16 [b,16,1024,64]
    u16* ko = (u16*)p; p += 1048576;     // bf16 [b,4,1024,64]
    u16* vt = (u16*)p; p += 1048576;     // bf16 [b,4,64,pos]
    float* rc = p; p += 32768;
    float* rs = p; p += 32768;
    u16* yq = xq;   // reuse (xq dead after qkv gemm)

    // weight quantization (fused: 3 dispatches)
    k_absmean_all<<<256, 256, 0, stream>>>(Wq, Wk, Wv, Wp, partial);
    k_rope_alpha<<<128, 256, 0, stream>>>(rc, rs, partial, alpha);
    k_tern_all<<<2560, 256, 0, stream>>>(Wq, Wk, Wv, Wp, alpha, wtqkv, wtp);

    // activation quantization + fused QKV projection + norm/rope epilogue
    k_quant<<<ROWS, 256, 0, stream>>>(x, xq, gam);
    k_gemm_qkv<<<dim3(12, 64), 256, 0, stream>>>(xq, wtqkv, gam, alpha, rc, rs, qg, qo, ko, cv);

    // V transpose (interleaved pos for packed-P attention)
    k_vtransT<<<dim3(16, 4, 8), 256, 0, stream>>>(cv, vt);

    // attention (packed P via LDS, paired causal tiles, setprio, bf16 output)
    k_attn_mfma<<<dim3(8, 16, 8), 256, 0, stream>>>(qo, ko, vt, y16);

    // output projection
    k_quant_bf16<<<ROWS, 256, 0, stream>>>(y16, yq, gam);
    k_gemm_out<<<dim3(8, 64), 256, 0, stream>>>(yq, wtp, gam, alpha, out);
}

// Round 12
// 165.556 us; speedup vs baseline: 1.6127x; 1.1853x over previous
//
#include <hip/hip_runtime.h>
#include <cmath>

#define DIMM 1024
#define NHEADS 16
#define NKV 4
#define HD 64
#define SEQ 1024
#define BSZ 8
#define ROWS (BSZ * SEQ)   // 8192

typedef unsigned short u16;
typedef signed char s8;
typedef __attribute__((ext_vector_type(8))) short bf16x8;
typedef __attribute__((ext_vector_type(4))) float f32x4;
typedef __attribute__((ext_vector_type(4))) int i32x4;
typedef __attribute__((ext_vector_type(4))) unsigned short u16x4;

static __device__ __forceinline__ u16 f2bf(float f) {
    union { float f; unsigned u; } v; v.f = f;
    unsigned r = v.u + 0x7FFFu + ((v.u >> 16) & 1u);
    return (u16)(r >> 16);
}
static __device__ __forceinline__ float bf2f(u16 h) {
    union { unsigned u; float f; } v; v.u = ((unsigned)h) << 16;
    return v.f;
}

// async global->LDS, 16B per lane; dst must be wave-uniform base (HW adds lane*16)
static __device__ __forceinline__ void gload16(const void* g, void* l) {
    __builtin_amdgcn_global_load_lds(
        (const __attribute__((address_space(1))) unsigned int*)g,
        (__attribute__((address_space(3))) unsigned int*)l, 16, 0, 0);
}

// ---------------- fused weight abs-mean: 4 weights, one dispatch ----------------
__global__ __launch_bounds__(256) void k_absmean_all(const float* __restrict__ Wq,
                                                     const float* __restrict__ Wk,
                                                     const float* __restrict__ Wv,
                                                     const float* __restrict__ Wp,
                                                     float* __restrict__ partial) {
    int wi = blockIdx.x >> 6, local = blockIdx.x & 63;
    const float* w = (wi == 0) ? Wq : (wi == 1) ? Wk : (wi == 2) ? Wv : Wp;
    int n = (wi == 0 || wi == 3) ? 1048576 : 262144;
    float s = 0.f;
    for (int i = local * 256 + threadIdx.x; i < n; i += 64 * 256) s += fabsf(w[i]);
    #pragma unroll
    for (int off = 32; off; off >>= 1) s += __shfl_xor(s, off);
    __shared__ float red[4];
    if ((threadIdx.x & 63) == 0) red[threadIdx.x >> 6] = s;
    __syncthreads();
    if (threadIdx.x == 0) partial[blockIdx.x] = red[0] + red[1] + red[2] + red[3];
}

// ---------------- rope table + alpha (fused) ----------------
__global__ __launch_bounds__(256) void k_rope_alpha(float* __restrict__ c, float* __restrict__ s,
                                                    const float* __restrict__ partial,
                                                    float* __restrict__ alpha) {
    int idx = blockIdx.x * 256 + threadIdx.x;  // < 32768
    int t = idx >> 5, i = idx & 31;
    float inv = 1.0f / powf(10000.0f, (float)(2 * i) * (1.0f / 64.0f));
    float f = (float)t * inv;
    c[idx] = cosf(f);
    s[idx] = sinf(f);
    if (blockIdx.x == 0 && threadIdx.x < 4) {
        const int ns[4] = {1048576, 262144, 262144, 1048576};
        float su = 0.f;
        for (int j = 0; j < 64; ++j) su += partial[threadIdx.x * 64 + j];
        alpha[threadIdx.x] = fmaxf(su / (float)ns[threadIdx.x], 1e-8f);
    }
}

// ---------------- fused ternarize -> i8 {-1,0,1}, one dispatch ----------------
__global__ __launch_bounds__(256) void k_tern_all(const float* __restrict__ Wq,
                                                  const float* __restrict__ Wk,
                                                  const float* __restrict__ Wv,
                                                  const float* __restrict__ Wp,
                                                  const float* __restrict__ alpha,
                                                  s8* __restrict__ wtqkv,
                                                  s8* __restrict__ wtp) {
    int idx = blockIdx.x * 256 + threadIdx.x;   // < 655360
    const float* src; s8* dst; float a;
    if (idx < 262144)      { src = Wq + (size_t)idx * 4;            dst = wtqkv + (size_t)idx * 4;                 a = alpha[0]; }
    else if (idx < 327680) { src = Wk + (size_t)(idx - 262144) * 4; dst = wtqkv + 1048576 + (size_t)(idx - 262144) * 4; a = alpha[1]; }
    else if (idx < 393216) { src = Wv + (size_t)(idx - 327680) * 4; dst = wtqkv + 1310720 + (size_t)(idx - 327680) * 4; a = alpha[2]; }
    else                   { src = Wp + (size_t)(idx - 393216) * 4; dst = wtp + (size_t)(idx - 393216) * 4;        a = alpha[3]; }
    float4 v = *reinterpret_cast<const float4*>(src);
    int q0 = (int)rintf(fminf(fmaxf(v.x / a, -1.f), 1.f));
    int q1 = (int)rintf(fminf(fmaxf(v.y / a, -1.f), 1.f));
    int q2 = (int)rintf(fminf(fmaxf(v.z / a, -1.f), 1.f));
    int q3 = (int)rintf(fminf(fmaxf(v.w / a, -1.f), 1.f));
    *reinterpret_cast<unsigned*>(dst) =
        (q0 & 0xff) | ((q1 & 0xff) << 8) | ((q2 & 0xff) << 16) | ((q3 & 0xff) << 24);
}

// ---------------- per-row activation quantization (f32 input) -> i8 ----------------
__global__ __launch_bounds__(256) void k_quant(const float* __restrict__ X,
                                               s8* __restrict__ Xq, float* __restrict__ g) {
    int row = blockIdx.x;
    const float* xr = X + (size_t)row * DIMM;
    float4 v = *reinterpret_cast<const float4*>(&xr[threadIdx.x * 4]);
    float mv = fmaxf(fmaxf(fabsf(v.x), fabsf(v.y)), fmaxf(fabsf(v.z), fabsf(v.w)));
    #pragma unroll
    for (int off = 32; off; off >>= 1) mv = fmaxf(mv, __shfl_xor(mv, off));
    __shared__ float red[4];
    if ((threadIdx.x & 63) == 0) red[threadIdx.x >> 6] = mv;
    __syncthreads();
    mv = fmaxf(fmaxf(red[0], red[1]), fmaxf(red[2], red[3]));
    float gamma = fmaxf(mv, 1e-8f) / 127.0f;
    int q0 = (int)rintf(fminf(fmaxf(v.x / gamma, -128.f), 127.f));
    int q1 = (int)rintf(fminf(fmaxf(v.y / gamma, -128.f), 127.f));
    int q2 = (int)rintf(fminf(fmaxf(v.z / gamma, -128.f), 127.f));
    int q3 = (int)rintf(fminf(fmaxf(v.w / gamma, -128.f), 127.f));
    reinterpret_cast<unsigned*>(Xq + (size_t)row * DIMM)[threadIdx.x] =
        (q0 & 0xff) | ((q1 & 0xff) << 8) | ((q2 & 0xff) << 16) | ((q3 & 0xff) << 24);
    if (threadIdx.x == 0) g[row] = gamma;
}

// ---------------- per-row activation quantization (bf16 input) -> i8 ----------------
__global__ __launch_bounds__(256) void k_quant_bf16(const u16* __restrict__ X,
                                                    s8* __restrict__ Xq, float* __restrict__ g) {
    int row = blockIdx.x;
    const u16* xr = X + (size_t)row * DIMM;
    u16x4 h = *reinterpret_cast<const u16x4*>(&xr[threadIdx.x * 4]);
    float v0 = bf2f(h.x), v1 = bf2f(h.y), v2 = bf2f(h.z), v3 = bf2f(h.w);
    float mv = fmaxf(fmaxf(fabsf(v0), fabsf(v1)), fmaxf(fabsf(v2), fabsf(v3)));
    #pragma unroll
    for (int off = 32; off; off >>= 1) mv = fmaxf(mv, __shfl_xor(mv, off));
    __shared__ float red[4];
    if ((threadIdx.x & 63) == 0) red[threadIdx.x >> 6] = mv;
    __syncthreads();
    mv = fmaxf(fmaxf(red[0], red[1]), fmaxf(red[2], red[3]));
    float gamma = fmaxf(mv, 1e-8f) / 127.0f;
    int q0 = (int)rintf(fminf(fmaxf(v0 / gamma, -128.f), 127.f));
    int q1 = (int)rintf(fminf(fmaxf(v1 / gamma, -128.f), 127.f));
    int q2 = (int)rintf(fminf(fmaxf(v2 / gamma, -128.f), 127.f));
    int q3 = (int)rintf(fminf(fmaxf(v3 / gamma, -128.f), 127.f));
    reinterpret_cast<unsigned*>(Xq + (size_t)row * DIMM)[threadIdx.x] =
        (q0 & 0xff) | ((q1 & 0xff) << 8) | ((q2 & 0xff) << 16) | ((q3 & 0xff) << 24);
    if (threadIdx.x == 0) g[row] = gamma;
}

// ---------------- i8 QKV GEMM with fused rms_norm+rope epilogue ----------------
// A: [8192][1024] i8, B: [1536][1024] i8 ternary. 128x128 tile, BK=128 bytes,
// mfma_i32_16x16x64_i8 (K=64/instr, 2 k-halves per BK). Same LDS byte geometry
// (128B/row = 8 x 16B slots, XOR swizzle) as the proven bf16 kernel.
__global__ __launch_bounds__(256) void k_gemm_qkv(const s8* __restrict__ A,
                                                  const s8* __restrict__ B,
                                                  const float* __restrict__ gamma,
                                                  const float* __restrict__ alpha_p,
                                                  const float* __restrict__ rc,
                                                  const float* __restrict__ rs,
                                                  const float* __restrict__ gain,
                                                  u16* __restrict__ Qo,
                                                  u16* __restrict__ Ko,
                                                  float* __restrict__ Cv) {
    __shared__ s8 As[128 * 128];
    __shared__ s8 Bs[128 * 128];
    const int K = DIMM;
    int tid = threadIdx.x;
    int w = tid >> 6, lane = tid & 63;
    int lr = lane & 15, lg = lane >> 4;
    int lr7 = lr & 7;
    int wm = w >> 1, wn = w & 1;
    int row0 = blockIdx.y * 128, col0 = blockIdx.x * 128;

    i32x4 acc[4][4];
    #pragma unroll
    for (int mf = 0; mf < 4; ++mf)
        #pragma unroll
        for (int nf = 0; nf < 4; ++nf) acc[mf][nf] = (i32x4){0, 0, 0, 0};

    int srow = w * 32 + (lane >> 3);
    int scol = 16 * ((lane & 7) ^ (lane >> 3));   // pre-swizzled source slot (bytes)
    const s8* Ag = A + (size_t)(row0 + srow) * K + scol;
    const s8* Bg = B + (size_t)(col0 + srow) * K + scol;

    for (int k0 = 0; k0 < K; k0 += 128) {
        #pragma unroll
        for (int i = 0; i < 4; ++i) {
            gload16(Ag + (size_t)i * 8 * K + k0, &As[w * 4096 + i * 1024]);
            gload16(Bg + (size_t)i * 8 * K + k0, &Bs[w * 4096 + i * 1024]);
        }
        __syncthreads();
        #pragma unroll
        for (int kh = 0; kh < 2; ++kh) {
            i32x4 af[4], bfr[4];
            #pragma unroll
            for (int mf = 0; mf < 4; ++mf)
                af[mf] = *reinterpret_cast<const i32x4*>(
                    &As[(wm * 64 + mf * 16 + lr) * 128 + 16 * (((kh << 2) + lg) ^ lr7)]);
            #pragma unroll
            for (int nf = 0; nf < 4; ++nf)
                bfr[nf] = *reinterpret_cast<const i32x4*>(
                    &Bs[(wn * 64 + nf * 16 + lr) * 128 + 16 * (((kh << 2) + lg) ^ lr7)]);
            #pragma unroll
            for (int mf = 0; mf < 4; ++mf)
                #pragma unroll
                for (int nf = 0; nf < 4; ++nf)
                    acc[mf][nf] = __builtin_amdgcn_mfma_i32_16x16x64_i8(af[mf], bfr[nf], acc[mf][nf], 0, 0, 0);
        }
        __syncthreads();
    }

    int c0 = col0 + wn * 64;
    int hh = c0 >> 6;   // 0..15 Q heads, 16..19 K heads, 20..23 V heads
    float alpha = alpha_p[hh < 16 ? 0 : (hh < 20 ? 1 : 2)];
    float ga = (hh < 16) ? gain[hh] * (0.125f * 1.4426950408889634f) : 1.0f;

    #pragma unroll
    for (int mf = 0; mf < 4; ++mf) {
        #pragma unroll
        for (int reg = 0; reg < 4; ++reg) {
            int row = row0 + wm * 64 + mf * 16 + lg * 4 + reg;
            float sc = gamma[row] * alpha;
            float v0 = (float)acc[mf][0][reg] * sc;
            float v1 = (float)acc[mf][1][reg] * sc;
            float v2 = (float)acc[mf][2][reg] * sc;
            float v3 = (float)acc[mf][3][reg] * sc;
            int s = row & 1023, b = row >> 10;
            if (hh < 20) {
                float ss = v0 * v0 + v1 * v1 + v2 * v2 + v3 * v3;
                #pragma unroll
                for (int off = 8; off; off >>= 1) ss += __shfl_xor(ss, off);
                float rn = 1.0f / sqrtf(ss * (1.0f / 64.0f) + 1.1920929e-07f);
                v0 *= rn; v1 *= rn; v2 *= rn; v3 *= rn;
                float cA = rc[s * 32 + lr],      sA = rs[s * 32 + lr];
                float cB = rc[s * 32 + 16 + lr], sB = rs[s * 32 + 16 + lr];
                float y0 = v0 * cA + v2 * sA, y2 = v2 * cA - v0 * sA;
                float y1 = v1 * cB + v3 * sB, y3 = v3 * cB - v1 * sB;
                u16* dst;
                if (hh < 16) {
                    y0 *= ga; y1 *= ga; y2 *= ga; y3 *= ga;
                    dst = Qo + ((size_t)((b * 16 + hh) * 1024 + s)) * 64;
                } else {
                    dst = Ko + ((size_t)((b * 4 + (hh - 16)) * 1024 + s)) * 64;
                }
                dst[lr] = f2bf(y0); dst[16 + lr] = f2bf(y1);
                dst[32 + lr] = f2bf(y2); dst[48 + lr] = f2bf(y3);
            } else {
                float* dst = Cv + (size_t)row * 256 + (hh - 20) * 64;
                dst[lr] = v0; dst[16 + lr] = v1; dst[32 + lr] = v2; dst[48 + lr] = v3;
            }
        }
    }
}

// ---------------- i8 GEMM for output projection ----------------
__global__ __launch_bounds__(256) void k_gemm_out(const s8* __restrict__ A,
                                                  const s8* __restrict__ B,
                                                  const float* __restrict__ gamma,
                                                  const float* __restrict__ alpha_p,
                                                  float* __restrict__ C) {
    __shared__ s8 As[128 * 128];
    __shared__ s8 Bs[128 * 128];
    const int K = DIMM;
    int tid = threadIdx.x;
    int w = tid >> 6, lane = tid & 63;
    int lr = lane & 15, lg = lane >> 4;
    int lr7 = lr & 7;
    int wm = w >> 1, wn = w & 1;
    int row0 = blockIdx.y * 128, col0 = blockIdx.x * 128;

    i32x4 acc[4][4];
    #pragma unroll
    for (int mf = 0; mf < 4; ++mf)
        #pragma unroll
        for (int nf = 0; nf < 4; ++nf) acc[mf][nf] = (i32x4){0, 0, 0, 0};

    int srow = w * 32 + (lane >> 3);
    int scol = 16 * ((lane & 7) ^ (lane >> 3));
    const s8* Ag = A + (size_t)(row0 + srow) * K + scol;
    const s8* Bg = B + (size_t)(col0 + srow) * K + scol;

    for (int k0 = 0; k0 < K; k0 += 128) {
        #pragma unroll
        for (int i = 0; i < 4; ++i) {
            gload16(Ag + (size_t)i * 8 * K + k0, &As[w * 4096 + i * 1024]);
            gload16(Bg + (size_t)i * 8 * K + k0, &Bs[w * 4096 + i * 1024]);
        }
        __syncthreads();
        #pragma unroll
        for (int kh = 0; kh < 2; ++kh) {
            i32x4 af[4], bfr[4];
            #pragma unroll
            for (int mf = 0; mf < 4; ++mf)
                af[mf] = *reinterpret_cast<const i32x4*>(
                    &As[(wm * 64 + mf * 16 + lr) * 128 + 16 * (((kh << 2) + lg) ^ lr7)]);
            #pragma unroll
            for (int nf = 0; nf < 4; ++nf)
                bfr[nf] = *reinterpret_cast<const i32x4*>(
                    &Bs[(wn * 64 + nf * 16 + lr) * 128 + 16 * (((kh << 2) + lg) ^ lr7)]);
            #pragma unroll
            for (int mf = 0; mf < 4; ++mf)
                #pragma unroll
                for (int nf = 0; nf < 4; ++nf)
                    acc[mf][nf] = __builtin_amdgcn_mfma_i32_16x16x64_i8(af[mf], bfr[nf], acc[mf][nf], 0, 0, 0);
        }
        __syncthreads();
    }

    float alpha = alpha_p[3];
    #pragma unroll
    for (int mf = 0; mf < 4; ++mf) {
        #pragma unroll
        for (int reg = 0; reg < 4; ++reg) {
            int row = row0 + wm * 64 + mf * 16 + lg * 4 + reg;
            float sc = gamma[row] * alpha;
            #pragma unroll
            for (int nf = 0; nf < 4; ++nf)
                C[(size_t)row * 1024 + col0 + wn * 64 + nf * 16 + lr] = (float)acc[mf][nf][reg] * sc;
        }
    }
}

// ---------------- v transpose: Cv [8192][256] f32 -> Vt [b,kv,d,pos] bf16 ----------------
// key pos within each 64-block INTERLEAVED: for s = sr+16*i: pos = 2*sr + (i&1) + 32*(i>>1)
__global__ __launch_bounds__(256) void k_vtransT(const float* __restrict__ Cv,
                                                 u16* __restrict__ Vt) {
    __shared__ u16 T[64][72];
    int st = blockIdx.x, kv = blockIdx.y, b = blockIdx.z;
    int tid = threadIdx.x;
    int sr = tid >> 4, d4 = tid & 15;
    #pragma unroll
    for (int i = 0; i < 4; ++i) {
        int s = sr + 16 * i;
        int pos = 2 * sr + (i & 1) + 32 * (i >> 1);
        float4 v = *reinterpret_cast<const float4*>(
            &Cv[(size_t)(b * 1024 + st * 64 + s) * 256 + kv * 64 + d4 * 4]);
        T[d4 * 4 + 0][pos] = f2bf(v.x);
        T[d4 * 4 + 1][pos] = f2bf(v.y);
        T[d4 * 4 + 2][pos] = f2bf(v.z);
        T[d4 * 4 + 3][pos] = f2bf(v.w);
    }
    __syncthreads();
    int d = tid >> 2, c = tid & 3;
    float4 o0 = *reinterpret_cast<const float4*>(&T[d][c * 16]);
    float4 o1 = *reinterpret_cast<const float4*>(&T[d][c * 16 + 8]);
    u16* out = &Vt[(((size_t)(b * 4 + kv) * 64) + d) * 1024 + st * 64 + c * 16];
    *reinterpret_cast<float4*>(out) = o0;
    *reinterpret_cast<float4*>(out + 8) = o1;
}

// ---------------- causal flash attention, bf16 MFMA, paired q-tiles ----------------
// Round-11 proven (73.8 us): packed P, defer-max, setprio, bf16 Y.
__global__ __launch_bounds__(256) void k_attn_mfma(const u16* __restrict__ Q,
                                                   const u16* __restrict__ K,
                                                   const u16* __restrict__ Vt,
                                                   u16* __restrict__ Y) {
    __shared__ __align__(16) u16 KVs[2][2][4096];   // [buf][K/V][64*64], swizzled
    __shared__ __align__(16) u16 Ps[4][1024];       // per-wave P strip [16 q][64 pos], swizzled
    int qta = blockIdx.x, qtb = 15 - qta;
    int h = blockIdx.y, b = blockIdx.z;
    int kvh = h >> 2;
    int tid = threadIdx.x;
    int w = tid >> 6, lane = tid & 63;
    int lr = lane & 15, lg = lane >> 4;
    int lr7 = lr & 7;
    int q0a = qta * 64 + w * 16, q0b = qtb * 64 + w * 16;
    const u16* Qb = Q + (((size_t)b * 16 + h) * 1024) * 64;
    const u16* Kb = K + (((size_t)b * 4 + kvh) * 1024) * 64;
    const u16* Vb = Vt + (((size_t)b * 4 + kvh) * 64) * 1024;
    u16* Psw = Ps[w];
    unsigned* Pw32 = reinterpret_cast<unsigned*>(Psw);

    bf16x8 qa0 = *reinterpret_cast<const bf16x8*>(&Qb[(size_t)(q0a + lr) * 64 + 8 * lg]);
    bf16x8 qa1 = *reinterpret_cast<const bf16x8*>(&Qb[(size_t)(q0a + lr) * 64 + 32 + 8 * lg]);
    bf16x8 qb0 = *reinterpret_cast<const bf16x8*>(&Qb[(size_t)(q0b + lr) * 64 + 8 * lg]);
    bf16x8 qb1 = *reinterpret_cast<const bf16x8*>(&Qb[(size_t)(q0b + lr) * 64 + 32 + 8 * lg]);

    float mA[4], lpA[4], mB[4], lpB[4];
    f32x4 accA[4], accB[4];
    #pragma unroll
    for (int r = 0; r < 4; ++r) { mA[r] = -INFINITY; lpA[r] = 0.f; mB[r] = -INFINITY; lpB[r] = 0.f; }
    #pragma unroll
    for (int dt = 0; dt < 4; ++dt) { accA[dt] = (f32x4){0.f,0.f,0.f,0.f}; accB[dt] = (f32x4){0.f,0.f,0.f,0.f}; }

    int sub = lane >> 3, s7 = lane & 7;
    int scol16 = s7 ^ sub;
    int c0 = 2 * w, c1 = 2 * w + 1;

    #define STAGE(buf, t_) do { \
        int kk0 = (t_) * 64; \
        gload16(Kb + (size_t)(kk0 + 8 * c0 + sub) * 64 + scol16 * 8, &KVs[buf][0][c0 * 512]); \
        gload16(Kb + (size_t)(kk0 + 8 * c1 + sub) * 64 + scol16 * 8, &KVs[buf][0][c1 * 512]); \
        gload16(Vb + (size_t)(8 * c0 + sub) * 1024 + kk0 + scol16 * 8, &KVs[buf][1][c0 * 512]); \
        gload16(Vb + (size_t)(8 * c1 + sub) * 1024 + kk0 + scol16 * 8, &KVs[buf][1][c1 * 512]); \
    } while (0)

    STAGE(0, 0);
    asm volatile("s_waitcnt vmcnt(0)" ::: "memory");
    __syncthreads();
    int cur = 0;

    for (int t = 0; t <= qtb; ++t) {
        if (t < qtb) STAGE(cur ^ 1, t + 1);
        const int k0 = t * 64;
        const bool doA = (t <= qta);
        const u16* Kl = KVs[cur][0];
        const u16* Vl = KVs[cur][1];

        float svA[4][4], svB[4][4];
        __builtin_amdgcn_s_setprio(1);
        #pragma unroll
        for (int t4 = 0; t4 < 4; ++t4) {
            int r = t4 * 16 + lr;
            bf16x8 kf0 = *reinterpret_cast<const bf16x8*>(&Kl[r * 64 + ((lg ^ lr7) << 3)]);
            bf16x8 kf1 = *reinterpret_cast<const bf16x8*>(&Kl[r * 64 + (((4 | lg) ^ lr7) << 3)]);
            if (doA) {
                f32x4 z = (f32x4){0.f,0.f,0.f,0.f};
                z = __builtin_amdgcn_mfma_f32_16x16x32_bf16(qa0, kf0, z, 0, 0, 0);
                z = __builtin_amdgcn_mfma_f32_16x16x32_bf16(qa1, kf1, z, 0, 0, 0);
                #pragma unroll
                for (int rr = 0; rr < 4; ++rr) svA[t4][rr] = z[rr];
            }
            f32x4 z2 = (f32x4){0.f,0.f,0.f,0.f};
            z2 = __builtin_amdgcn_mfma_f32_16x16x32_bf16(qb0, kf0, z2, 0, 0, 0);
            z2 = __builtin_amdgcn_mfma_f32_16x16x32_bf16(qb1, kf1, z2, 0, 0, 0);
            #pragma unroll
            for (int rr = 0; rr < 4; ++rr) svB[t4][rr] = z2[rr];
        }
        __builtin_amdgcn_s_setprio(0);
        if (doA && t == qta) {
            #pragma unroll
            for (int t4 = 0; t4 < 4; ++t4) {
                int key = k0 + t4 * 16 + lr;
                #pragma unroll
                for (int rr = 0; rr < 4; ++rr)
                    if (key > q0a + lg * 4 + rr) svA[t4][rr] = -3.0e38f;
            }
        }
        if (t == qtb) {
            #pragma unroll
            for (int t4 = 0; t4 < 4; ++t4) {
                int key = k0 + t4 * 16 + lr;
                #pragma unroll
                for (int rr = 0; rr < 4; ++rr)
                    if (key > q0b + lg * 4 + rr) svB[t4][rr] = -3.0e38f;
            }
        }

        bf16x8 paA0, paA1, paB0, paB1;
        if (doA) {
            float vx[4]; int ok = 1;
            #pragma unroll
            for (int rr = 0; rr < 4; ++rr) {
                vx[rr] = fmaxf(fmaxf(svA[0][rr], svA[1][rr]), fmaxf(svA[2][rr], svA[3][rr]));
                ok &= (vx[rr] <= mA[rr] + 8.0f);
            }
            if (!__all(ok)) {
                #pragma unroll
                for (int rr = 0; rr < 4; ++rr) {
                    float mm = vx[rr];
                    #pragma unroll
                    for (int off = 8; off; off >>= 1) mm = fmaxf(mm, __shfl_xor(mm, off));
                    float mn = fmaxf(mA[rr], mm);
                    float corr = exp2f(mA[rr] - mn);
                    mA[rr] = mn;
                    lpA[rr] *= corr;
                    #pragma unroll
                    for (int dt = 0; dt < 4; ++dt) accA[dt][rr] *= corr;
                }
            }
            #pragma unroll
            for (int rr = 0; rr < 4; ++rr) {
                float p0 = exp2f(svA[0][rr] - mA[rr]);
                float p1 = exp2f(svA[1][rr] - mA[rr]);
                float p2 = exp2f(svA[2][rr] - mA[rr]);
                float p3 = exp2f(svA[3][rr] - mA[rr]);
                lpA[rr] += (p0 + p1) + (p2 + p3);
                unsigned pk01, pk23;
                asm("v_cvt_pk_bf16_f32 %0, %1, %2" : "=v"(pk01) : "v"(p0), "v"(p1));
                asm("v_cvt_pk_bf16_f32 %0, %1, %2" : "=v"(pk23) : "v"(p2), "v"(p3));
                int row = lg * 4 + rr, r7 = row & 7;
                Pw32[row * 32 + (((lr >> 2) ^ r7) << 2) + (lr & 3)] = pk01;
                Pw32[row * 32 + ((((lr >> 2) + 4) ^ r7) << 2) + (lr & 3)] = pk23;
            }
            paA0 = *reinterpret_cast<const bf16x8*>(&Psw[lr * 64 + ((lg ^ lr7) << 3)]);
            paA1 = *reinterpret_cast<const bf16x8*>(&Psw[lr * 64 + (((4 | lg) ^ lr7) << 3)]);
        }

        {
            float vx[4]; int ok = 1;
            #pragma unroll
            for (int rr = 0; rr < 4; ++rr) {
                vx[rr] = fmaxf(fmaxf(svB[0][rr], svB[1][rr]), fmaxf(svB[2][rr], svB[3][rr]));
                ok &= (vx[rr] <= mB[rr] + 8.0f);
            }
            if (!__all(ok)) {
                #pragma unroll
                for (int rr = 0; rr < 4; ++rr) {
                    float mm = vx[rr];
                    #pragma unroll
                    for (int off = 8; off; off >>= 1) mm = fmaxf(mm, __shfl_xor(mm, off));
                    float mn = fmaxf(mB[rr], mm);
                    float corr = exp2f(mB[rr] - mn);
                    mB[rr] = mn;
                    lpB[rr] *= corr;
                    #pragma unroll
                    for (int dt = 0; dt < 4; ++dt) accB[dt][rr] *= corr;
                }
            }
            #pragma unroll
            for (int rr = 0; rr < 4; ++rr) {
                float p0 = exp2f(svB[0][rr] - mB[rr]);
                float p1 = exp2f(svB[1][rr] - mB[rr]);
                float p2 = exp2f(svB[2][rr] - mB[rr]);
                float p3 = exp2f(svB[3][rr] - mB[rr]);
                lpB[rr] += (p0 + p1) + (p2 + p3);
                unsigned pk01, pk23;
                asm("v_cvt_pk_bf16_f32 %0, %1, %2" : "=v"(pk01) : "v"(p0), "v"(p1));
                asm("v_cvt_pk_bf16_f32 %0, %1, %2" : "=v"(pk23) : "v"(p2), "v"(p3));
                int row = lg * 4 + rr, r7 = row & 7;
                Pw32[row * 32 + (((lr >> 2) ^ r7) << 2) + (lr & 3)] = pk01;
                Pw32[row * 32 + ((((lr >> 2) + 4) ^ r7) << 2) + (lr & 3)] = pk23;
            }
            paB0 = *reinterpret_cast<const bf16x8*>(&Psw[lr * 64 + ((lg ^ lr7) << 3)]);
            paB1 = *reinterpret_cast<const bf16x8*>(&Psw[lr * 64 + (((4 | lg) ^ lr7) << 3)]);
        }

        __builtin_amdgcn_s_setprio(1);
        #pragma unroll
        for (int dt = 0; dt < 4; ++dt) {
            int r = dt * 16 + lr;
            bf16x8 vf0 = *reinterpret_cast<const bf16x8*>(&Vl[r * 64 + ((lg ^ lr7) << 3)]);
            bf16x8 vf1 = *reinterpret_cast<const bf16x8*>(&Vl[r * 64 + (((4 | lg) ^ lr7) << 3)]);
            if (doA) {
                accA[dt] = __builtin_amdgcn_mfma_f32_16x16x32_bf16(paA0, vf0, accA[dt], 0, 0, 0);
                accA[dt] = __builtin_amdgcn_mfma_f32_16x16x32_bf16(paA1, vf1, accA[dt], 0, 0, 0);
            }
            accB[dt] = __builtin_amdgcn_mfma_f32_16x16x32_bf16(paB0, vf0, accB[dt], 0, 0, 0);
            accB[dt] = __builtin_amdgcn_mfma_f32_16x16x32_bf16(paB1, vf1, accB[dt], 0, 0, 0);
        }
        __builtin_amdgcn_s_setprio(0);

        asm volatile("s_waitcnt vmcnt(0)" ::: "memory");
        __syncthreads();
        cur ^= 1;
    }
    #undef STAGE

    #pragma unroll
    for (int rr = 0; rr < 4; ++rr) {
        #pragma unroll
        for (int off = 8; off; off >>= 1) {
            lpA[rr] += __shfl_xor(lpA[rr], off);
            lpB[rr] += __shfl_xor(lpB[rr], off);
        }
    }

    #pragma unroll
    for (int rr = 0; rr < 4; ++rr) {
        float invA = 1.0f / lpA[rr];
        float invB = 1.0f / lpB[rr];
        size_t baseA = ((size_t)(b * 1024 + q0a + lg * 4 + rr)) * 1024 + h * 64;
        size_t baseB = ((size_t)(b * 1024 + q0b + lg * 4 + rr)) * 1024 + h * 64;
        #pragma unroll
        for (int dt = 0; dt < 4; ++dt) {
            Y[baseA + dt * 16 + lr] = f2bf(accA[dt][rr] * invA);
            Y[baseB + dt * 16 + lr] = f2bf(accB[dt][rr] * invB);
        }
    }
}

extern "C" void kernel_launch(void* const* d_in, const int* in_sizes, int n_in,
                              void* d_out, int out_size, void* d_ws, size_t ws_size,
                              hipStream_t stream) {
    (void)in_sizes; (void)n_in; (void)out_size; (void)ws_size;
    const float* x  = (const float*)d_in[0];
    const float* Wq = (const float*)d_in[1];
    const float* Wk = (const float*)d_in[2];
    const float* Wv = (const float*)d_in[3];
    const float* Wp = (const float*)d_in[4];
    const float* qg = (const float*)d_in[5];
    float* out = (float*)d_out;

    float* p = (float*)d_ws;
    float* partial = p; p += 256;
    float* alpha = p;   p += 16;
    s8* wtqkv = (s8*)p; p += 393216;     // 1536x1024 i8
    s8* wtp   = (s8*)p; p += 262144;     // 1024x1024 i8
    s8* xq    = (s8*)p; p += 2097152;    // 8192x1024 i8
    float* gam = p; p += 8192;
    u16* y16   = (u16*)p; p += 4194304;  // bf16 [8192][1024] attn output
    float* cv  = p; p += 2097152;        // f32 [8192][256] V projection
    u16* qo = (u16*)p; p += 4194304;     // bf16 [b,16,1024,64]
    u16* ko = (u16*)p; p += 1048576;     // bf16 [b,4,1024,64]
    u16* vt = (u16*)p; p += 1048576;     // bf16 [b,4,64,pos]
    float* rc = p; p += 32768;
    float* rs = p; p += 32768;
    s8* yq = xq;   // reuse (xq dead after qkv gemm)

    // weight quantization (fused: 3 dispatches, i8 output)
    k_absmean_all<<<256, 256, 0, stream>>>(Wq, Wk, Wv, Wp, partial);
    k_rope_alpha<<<128, 256, 0, stream>>>(rc, rs, partial, alpha);
    k_tern_all<<<2560, 256, 0, stream>>>(Wq, Wk, Wv, Wp, alpha, wtqkv, wtp);

    // activation quantization + fused i8 QKV projection + norm/rope epilogue
    k_quant<<<ROWS, 256, 0, stream>>>(x, xq, gam);
    k_gemm_qkv<<<dim3(12, 64), 256, 0, stream>>>(xq, wtqkv, gam, alpha, rc, rs, qg, qo, ko, cv);

    // V transpose (interleaved pos for packed-P attention)
    k_vtransT<<<dim3(16, 4, 8), 256, 0, stream>>>(cv, vt);

    // attention (packed P via LDS, paired causal tiles, setprio, bf16 output)
    k_attn_mfma<<<dim3(8, 16, 8), 256, 0, stream>>>(qo, ko, vt, y16);

    // output projection (i8)
    k_quant_bf16<<<ROWS, 256, 0, stream>>>(y16, yq, gam);
    k_gemm_out<<<dim3(8, 64), 256, 0, stream>>>(yq, wtp, gam, alpha, out);
}

// Round 13
// 156.234 us; speedup vs baseline: 1.7089x; 1.0597x over previous
//
#include <hip/hip_runtime.h>
#include <cmath>

#define DIMM 1024
#define NHEADS 16
#define NKV 4
#define HD 64
#define SEQ 1024
#define BSZ 8
#define ROWS (BSZ * SEQ)   // 8192

typedef unsigned short u16;
typedef signed char s8;
typedef __attribute__((ext_vector_type(8))) short bf16x8;
typedef __attribute__((ext_vector_type(8))) unsigned short u16x8;
typedef __attribute__((ext_vector_type(4))) float f32x4;
typedef __attribute__((ext_vector_type(4))) int i32x4;
typedef __attribute__((ext_vector_type(4))) unsigned short u16x4;

static __device__ __forceinline__ u16 f2bf(float f) {
    union { float f; unsigned u; } v; v.f = f;
    unsigned r = v.u + 0x7FFFu + ((v.u >> 16) & 1u);
    return (u16)(r >> 16);
}
static __device__ __forceinline__ float bf2f(u16 h) {
    union { unsigned u; float f; } v; v.u = ((unsigned)h) << 16;
    return v.f;
}

// async global->LDS, 16B per lane; dst must be wave-uniform base (HW adds lane*16)
static __device__ __forceinline__ void gload16(const void* g, void* l) {
    __builtin_amdgcn_global_load_lds(
        (const __attribute__((address_space(1))) unsigned int*)g,
        (__attribute__((address_space(3))) unsigned int*)l, 16, 0, 0);
}

// ---------------- fused weight abs-mean: 4 weights, one dispatch ----------------
__global__ __launch_bounds__(256) void k_absmean_all(const float* __restrict__ Wq,
                                                     const float* __restrict__ Wk,
                                                     const float* __restrict__ Wv,
                                                     const float* __restrict__ Wp,
                                                     float* __restrict__ partial) {
    int wi = blockIdx.x >> 6, local = blockIdx.x & 63;
    const float* w = (wi == 0) ? Wq : (wi == 1) ? Wk : (wi == 2) ? Wv : Wp;
    int n = (wi == 0 || wi == 3) ? 1048576 : 262144;
    float s = 0.f;
    for (int i = local * 256 + threadIdx.x; i < n; i += 64 * 256) s += fabsf(w[i]);
    #pragma unroll
    for (int off = 32; off; off >>= 1) s += __shfl_xor(s, off);
    __shared__ float red[4];
    if ((threadIdx.x & 63) == 0) red[threadIdx.x >> 6] = s;
    __syncthreads();
    if (threadIdx.x == 0) partial[blockIdx.x] = red[0] + red[1] + red[2] + red[3];
}

// ---------------- rope table + alpha (fused) ----------------
__global__ __launch_bounds__(256) void k_rope_alpha(float* __restrict__ c, float* __restrict__ s,
                                                    const float* __restrict__ partial,
                                                    float* __restrict__ alpha) {
    int idx = blockIdx.x * 256 + threadIdx.x;  // < 32768
    int t = idx >> 5, i = idx & 31;
    float inv = 1.0f / powf(10000.0f, (float)(2 * i) * (1.0f / 64.0f));
    float f = (float)t * inv;
    c[idx] = cosf(f);
    s[idx] = sinf(f);
    if (blockIdx.x == 0 && threadIdx.x < 4) {
        const int ns[4] = {1048576, 262144, 262144, 1048576};
        float su = 0.f;
        for (int j = 0; j < 64; ++j) su += partial[threadIdx.x * 64 + j];
        alpha[threadIdx.x] = fmaxf(su / (float)ns[threadIdx.x], 1e-8f);
    }
}

// ---------------- fused ternarize -> i8 {-1,0,1}, one dispatch ----------------
__global__ __launch_bounds__(256) void k_tern_all(const float* __restrict__ Wq,
                                                  const float* __restrict__ Wk,
                                                  const float* __restrict__ Wv,
                                                  const float* __restrict__ Wp,
                                                  const float* __restrict__ alpha,
                                                  s8* __restrict__ wtqkv,
                                                  s8* __restrict__ wtp) {
    int idx = blockIdx.x * 256 + threadIdx.x;   // < 655360
    const float* src; s8* dst; float a;
    if (idx < 262144)      { src = Wq + (size_t)idx * 4;            dst = wtqkv + (size_t)idx * 4;                 a = alpha[0]; }
    else if (idx < 327680) { src = Wk + (size_t)(idx - 262144) * 4; dst = wtqkv + 1048576 + (size_t)(idx - 262144) * 4; a = alpha[1]; }
    else if (idx < 393216) { src = Wv + (size_t)(idx - 327680) * 4; dst = wtqkv + 1310720 + (size_t)(idx - 327680) * 4; a = alpha[2]; }
    else                   { src = Wp + (size_t)(idx - 393216) * 4; dst = wtp + (size_t)(idx - 393216) * 4;        a = alpha[3]; }
    float4 v = *reinterpret_cast<const float4*>(src);
    int q0 = (int)rintf(fminf(fmaxf(v.x / a, -1.f), 1.f));
    int q1 = (int)rintf(fminf(fmaxf(v.y / a, -1.f), 1.f));
    int q2 = (int)rintf(fminf(fmaxf(v.z / a, -1.f), 1.f));
    int q3 = (int)rintf(fminf(fmaxf(v.w / a, -1.f), 1.f));
    *reinterpret_cast<unsigned*>(dst) =
        (q0 & 0xff) | ((q1 & 0xff) << 8) | ((q2 & 0xff) << 16) | ((q3 & 0xff) << 24);
}

// ---------------- per-row activation quantization (f32 input) -> i8 ----------------
__global__ __launch_bounds__(256) void k_quant(const float* __restrict__ X,
                                               s8* __restrict__ Xq, float* __restrict__ g) {
    int row = blockIdx.x;
    const float* xr = X + (size_t)row * DIMM;
    float4 v = *reinterpret_cast<const float4*>(&xr[threadIdx.x * 4]);
    float mv = fmaxf(fmaxf(fabsf(v.x), fabsf(v.y)), fmaxf(fabsf(v.z), fabsf(v.w)));
    #pragma unroll
    for (int off = 32; off; off >>= 1) mv = fmaxf(mv, __shfl_xor(mv, off));
    __shared__ float red[4];
    if ((threadIdx.x & 63) == 0) red[threadIdx.x >> 6] = mv;
    __syncthreads();
    mv = fmaxf(fmaxf(red[0], red[1]), fmaxf(red[2], red[3]));
    float gamma = fmaxf(mv, 1e-8f) / 127.0f;
    int q0 = (int)rintf(fminf(fmaxf(v.x / gamma, -128.f), 127.f));
    int q1 = (int)rintf(fminf(fmaxf(v.y / gamma, -128.f), 127.f));
    int q2 = (int)rintf(fminf(fmaxf(v.z / gamma, -128.f), 127.f));
    int q3 = (int)rintf(fminf(fmaxf(v.w / gamma, -128.f), 127.f));
    reinterpret_cast<unsigned*>(Xq + (size_t)row * DIMM)[threadIdx.x] =
        (q0 & 0xff) | ((q1 & 0xff) << 8) | ((q2 & 0xff) << 16) | ((q3 & 0xff) << 24);
    if (threadIdx.x == 0) g[row] = gamma;
}

// ---------------- per-row activation quantization (bf16 input) -> i8 ----------------
__global__ __launch_bounds__(256) void k_quant_bf16(const u16* __restrict__ X,
                                                    s8* __restrict__ Xq, float* __restrict__ g) {
    int row = blockIdx.x;
    const u16* xr = X + (size_t)row * DIMM;
    u16x4 h = *reinterpret_cast<const u16x4*>(&xr[threadIdx.x * 4]);
    float v0 = bf2f(h.x), v1 = bf2f(h.y), v2 = bf2f(h.z), v3 = bf2f(h.w);
    float mv = fmaxf(fmaxf(fabsf(v0), fabsf(v1)), fmaxf(fabsf(v2), fabsf(v3)));
    #pragma unroll
    for (int off = 32; off; off >>= 1) mv = fmaxf(mv, __shfl_xor(mv, off));
    __shared__ float red[4];
    if ((threadIdx.x & 63) == 0) red[threadIdx.x >> 6] = mv;
    __syncthreads();
    mv = fmaxf(fmaxf(red[0], red[1]), fmaxf(red[2], red[3]));
    float gamma = fmaxf(mv, 1e-8f) / 127.0f;
    int q0 = (int)rintf(fminf(fmaxf(v0 / gamma, -128.f), 127.f));
    int q1 = (int)rintf(fminf(fmaxf(v1 / gamma, -128.f), 127.f));
    int q2 = (int)rintf(fminf(fmaxf(v2 / gamma, -128.f), 127.f));
    int q3 = (int)rintf(fminf(fmaxf(v3 / gamma, -128.f), 127.f));
    reinterpret_cast<unsigned*>(Xq + (size_t)row * DIMM)[threadIdx.x] =
        (q0 & 0xff) | ((q1 & 0xff) << 8) | ((q2 & 0xff) << 16) | ((q3 & 0xff) << 24);
    if (threadIdx.x == 0) g[row] = gamma;
}

// ---------------- i8 QKV GEMM: fused rms_norm+rope epilogue + fused V transpose ----------------
// grid (12,64) XCD-swizzled. V waves (hh>=20) transpose in LDS (reusing As/Bs) and
// write bf16 Vt [b,kv,d,pos] directly (pos interleaved, matching attention's packed P).
__global__ __launch_bounds__(256) void k_gemm_qkv(const s8* __restrict__ A,
                                                  const s8* __restrict__ B,
                                                  const float* __restrict__ gamma,
                                                  const float* __restrict__ alpha_p,
                                                  const float* __restrict__ rc,
                                                  const float* __restrict__ rs,
                                                  const float* __restrict__ gain,
                                                  u16* __restrict__ Qo,
                                                  u16* __restrict__ Ko,
                                                  u16* __restrict__ Vt) {
    __shared__ __align__(16) s8 SMEM[32768];
    s8* As = SMEM;
    s8* Bs = SMEM + 16384;
    const int K = DIMM;
    int tid = threadIdx.x;
    int w = tid >> 6, lane = tid & 63;
    int lr = lane & 15, lg = lane >> 4;
    int lr7 = lr & 7;
    int wm = w >> 1, wn = w & 1;
    // XCD swizzle: groups of 8 row-panels per XCD (768 blocks, 768%8==0, bijective)
    int orig = blockIdx.x + 12 * blockIdx.y;
    int wgid = (orig & 7) * 96 + (orig >> 3);
    int bx = wgid % 12, by = wgid / 12;
    int row0 = by * 128, col0 = bx * 128;

    i32x4 acc[4][4];
    #pragma unroll
    for (int mf = 0; mf < 4; ++mf)
        #pragma unroll
        for (int nf = 0; nf < 4; ++nf) acc[mf][nf] = (i32x4){0, 0, 0, 0};

    int srow = w * 32 + (lane >> 3);
    int scol = 16 * ((lane & 7) ^ (lane >> 3));   // pre-swizzled source slot (bytes)
    const s8* Ag = A + (size_t)(row0 + srow) * K + scol;
    const s8* Bg = B + (size_t)(col0 + srow) * K + scol;

    for (int k0 = 0; k0 < K; k0 += 128) {
        #pragma unroll
        for (int i = 0; i < 4; ++i) {
            gload16(Ag + (size_t)i * 8 * K + k0, &As[w * 4096 + i * 1024]);
            gload16(Bg + (size_t)i * 8 * K + k0, &Bs[w * 4096 + i * 1024]);
        }
        __syncthreads();
        #pragma unroll
        for (int kh = 0; kh < 2; ++kh) {
            i32x4 af[4], bfr[4];
            #pragma unroll
            for (int mf = 0; mf < 4; ++mf)
                af[mf] = *reinterpret_cast<const i32x4*>(
                    &As[(wm * 64 + mf * 16 + lr) * 128 + 16 * (((kh << 2) + lg) ^ lr7)]);
            #pragma unroll
            for (int nf = 0; nf < 4; ++nf)
                bfr[nf] = *reinterpret_cast<const i32x4*>(
                    &Bs[(wn * 64 + nf * 16 + lr) * 128 + 16 * (((kh << 2) + lg) ^ lr7)]);
            #pragma unroll
            for (int mf = 0; mf < 4; ++mf)
                #pragma unroll
                for (int nf = 0; nf < 4; ++nf)
                    acc[mf][nf] = __builtin_amdgcn_mfma_i32_16x16x64_i8(af[mf], bfr[nf], acc[mf][nf], 0, 0, 0);
        }
        __syncthreads();
    }

    int c0 = col0 + wn * 64;
    int hh = c0 >> 6;   // 0..15 Q heads, 16..19 K heads, 20..23 V heads
    float alpha = alpha_p[hh < 16 ? 0 : (hh < 20 ? 1 : 2)];

    if (hh < 20) {
        float ga = (hh < 16) ? gain[hh] * (0.125f * 1.4426950408889634f) : 1.0f;
        #pragma unroll
        for (int mf = 0; mf < 4; ++mf) {
            #pragma unroll
            for (int reg = 0; reg < 4; ++reg) {
                int row = row0 + wm * 64 + mf * 16 + lg * 4 + reg;
                float sc = gamma[row] * alpha;
                float v0 = (float)acc[mf][0][reg] * sc;
                float v1 = (float)acc[mf][1][reg] * sc;
                float v2 = (float)acc[mf][2][reg] * sc;
                float v3 = (float)acc[mf][3][reg] * sc;
                int s = row & 1023, b = row >> 10;
                float ss = v0 * v0 + v1 * v1 + v2 * v2 + v3 * v3;
                #pragma unroll
                for (int off = 8; off; off >>= 1) ss += __shfl_xor(ss, off);
                float rn = 1.0f / sqrtf(ss * (1.0f / 64.0f) + 1.1920929e-07f);
                v0 *= rn; v1 *= rn; v2 *= rn; v3 *= rn;
                float cA = rc[s * 32 + lr],      sA = rs[s * 32 + lr];
                float cB = rc[s * 32 + 16 + lr], sB = rs[s * 32 + 16 + lr];
                float y0 = v0 * cA + v2 * sA, y2 = v2 * cA - v0 * sA;
                float y1 = v1 * cB + v3 * sB, y3 = v3 * cB - v1 * sB;
                u16* dst;
                if (hh < 16) {
                    y0 *= ga; y1 *= ga; y2 *= ga; y3 *= ga;
                    dst = Qo + ((size_t)((b * 16 + hh) * 1024 + s)) * 64;
                } else {
                    dst = Ko + ((size_t)((b * 4 + (hh - 16)) * 1024 + s)) * 64;
                }
                dst[lr] = f2bf(y0); dst[16 + lr] = f2bf(y1);
                dst[32 + lr] = f2bf(y2); dst[48 + lr] = f2bf(y3);
            }
        }
    } else {
        // V: transpose via per-wave LDS strip [64 d][64 pos] (8-granular XOR),
        // write bf16 Vt directly. T reuses As/Bs memory (all waves past final barrier).
        int kv = hh - 20;
        u16* T = reinterpret_cast<u16*>(SMEM) + w * 4096;
        #pragma unroll
        for (int mf = 0; mf < 4; ++mf) {
            int pb = (mf & 1) + 32 * (mf >> 1);
            #pragma unroll
            for (int reg = 0; reg < 4; ++reg) {
                int row = row0 + wm * 64 + mf * 16 + lg * 4 + reg;
                float sc = gamma[row] * alpha;
                int pos = 2 * (lg * 4 + reg) + pb;
                #pragma unroll
                for (int nf = 0; nf < 4; ++nf) {
                    int d = nf * 16 + lr;
                    T[d * 64 + (pos ^ (lr7 << 3))] = f2bf((float)acc[mf][nf][reg] * sc);
                }
            }
        }
        // same-wave write->read: compiler inserts lgkmcnt wait
        int b = row0 >> 10;
        int st = ((row0 & 1023) + wm * 64) >> 6;
        int d = lane, h3 = lane & 7;
        u16* dst = Vt + (((size_t)(b * 4 + kv) * 64) + d) * 1024 + st * 64;
        #pragma unroll
        for (int j = 0; j < 8; ++j) {
            u16x8 gv = *reinterpret_cast<const u16x8*>(&T[d * 64 + 8 * (j ^ h3)]);
            *reinterpret_cast<u16x8*>(&dst[8 * j]) = gv;
        }
    }
}

// ---------------- i8 GEMM for output projection (XCD-swizzled) ----------------
__global__ __launch_bounds__(256) void k_gemm_out(const s8* __restrict__ A,
                                                  const s8* __restrict__ B,
                                                  const float* __restrict__ gamma,
                                                  const float* __restrict__ alpha_p,
                                                  float* __restrict__ C) {
    __shared__ s8 As[128 * 128];
    __shared__ s8 Bs[128 * 128];
    const int K = DIMM;
    int tid = threadIdx.x;
    int w = tid >> 6, lane = tid & 63;
    int lr = lane & 15, lg = lane >> 4;
    int lr7 = lr & 7;
    int wm = w >> 1, wn = w & 1;
    int orig = blockIdx.x + 8 * blockIdx.y;
    int wgid = ((orig & 7) << 6) + (orig >> 3);
    int row0 = (wgid >> 3) * 128, col0 = (wgid & 7) * 128;

    i32x4 acc[4][4];
    #pragma unroll
    for (int mf = 0; mf < 4; ++mf)
        #pragma unroll
        for (int nf = 0; nf < 4; ++nf) acc[mf][nf] = (i32x4){0, 0, 0, 0};

    int srow = w * 32 + (lane >> 3);
    int scol = 16 * ((lane & 7) ^ (lane >> 3));
    const s8* Ag = A + (size_t)(row0 + srow) * K + scol;
    const s8* Bg = B + (size_t)(col0 + srow) * K + scol;

    for (int k0 = 0; k0 < K; k0 += 128) {
        #pragma unroll
        for (int i = 0; i < 4; ++i) {
            gload16(Ag + (size_t)i * 8 * K + k0, &As[w * 4096 + i * 1024]);
            gload16(Bg + (size_t)i * 8 * K + k0, &Bs[w * 4096 + i * 1024]);
        }
        __syncthreads();
        #pragma unroll
        for (int kh = 0; kh < 2; ++kh) {
            i32x4 af[4], bfr[4];
            #pragma unroll
            for (int mf = 0; mf < 4; ++mf)
                af[mf] = *reinterpret_cast<const i32x4*>(
                    &As[(wm * 64 + mf * 16 + lr) * 128 + 16 * (((kh << 2) + lg) ^ lr7)]);
            #pragma unroll
            for (int nf = 0; nf < 4; ++nf)
                bfr[nf] = *reinterpret_cast<const i32x4*>(
                    &Bs[(wn * 64 + nf * 16 + lr) * 128 + 16 * (((kh << 2) + lg) ^ lr7)]);
            #pragma unroll
            for (int mf = 0; mf < 4; ++mf)
                #pragma unroll
                for (int nf = 0; nf < 4; ++nf)
                    acc[mf][nf] = __builtin_amdgcn_mfma_i32_16x16x64_i8(af[mf], bfr[nf], acc[mf][nf], 0, 0, 0);
        }
        __syncthreads();
    }

    float alpha = alpha_p[3];
    #pragma unroll
    for (int mf = 0; mf < 4; ++mf) {
        #pragma unroll
        for (int reg = 0; reg < 4; ++reg) {
            int row = row0 + wm * 64 + mf * 16 + lg * 4 + reg;
            float sc = gamma[row] * alpha;
            #pragma unroll
            for (int nf = 0; nf < 4; ++nf)
                C[(size_t)row * 1024 + col0 + wn * 64 + nf * 16 + lr] = (float)acc[mf][nf][reg] * sc;
        }
    }
}

// ---------------- causal flash attention, bf16 MFMA, paired q-tiles ----------------
// Round-12 proven structure + XCD swizzle (each XCD owns one batch b's K/V in L2).
__global__ __launch_bounds__(256) void k_attn_mfma(const u16* __restrict__ Q,
                                                   const u16* __restrict__ K,
                                                   const u16* __restrict__ Vt,
                                                   u16* __restrict__ Y) {
    __shared__ __align__(16) u16 KVs[2][2][4096];   // [buf][K/V][64*64], swizzled
    __shared__ __align__(16) u16 Ps[4][1024];       // per-wave P strip [16 q][64 pos], swizzled
    // XCD swizzle: 1024 blocks -> each XCD gets one contiguous b (bijective)
    int orig = blockIdx.x + ((blockIdx.y + (blockIdx.z << 4)) << 3);
    int wgid = ((orig & 7) << 7) + (orig >> 3);
    int qta = wgid & 7, qtb = 15 - qta;
    int h = (wgid >> 3) & 15, b = wgid >> 7;
    int kvh = h >> 2;
    int tid = threadIdx.x;
    int w = tid >> 6, lane = tid & 63;
    int lr = lane & 15, lg = lane >> 4;
    int lr7 = lr & 7;
    int q0a = qta * 64 + w * 16, q0b = qtb * 64 + w * 16;
    const u16* Qb = Q + (((size_t)b * 16 + h) * 1024) * 64;
    const u16* Kb = K + (((size_t)b * 4 + kvh) * 1024) * 64;
    const u16* Vb = Vt + (((size_t)b * 4 + kvh) * 64) * 1024;
    u16* Psw = Ps[w];
    unsigned* Pw32 = reinterpret_cast<unsigned*>(Psw);

    bf16x8 qa0 = *reinterpret_cast<const bf16x8*>(&Qb[(size_t)(q0a + lr) * 64 + 8 * lg]);
    bf16x8 qa1 = *reinterpret_cast<const bf16x8*>(&Qb[(size_t)(q0a + lr) * 64 + 32 + 8 * lg]);
    bf16x8 qb0 = *reinterpret_cast<const bf16x8*>(&Qb[(size_t)(q0b + lr) * 64 + 8 * lg]);
    bf16x8 qb1 = *reinterpret_cast<const bf16x8*>(&Qb[(size_t)(q0b + lr) * 64 + 32 + 8 * lg]);

    float mA[4], lpA[4], mB[4], lpB[4];
    f32x4 accA[4], accB[4];
    #pragma unroll
    for (int r = 0; r < 4; ++r) { mA[r] = -INFINITY; lpA[r] = 0.f; mB[r] = -INFINITY; lpB[r] = 0.f; }
    #pragma unroll
    for (int dt = 0; dt < 4; ++dt) { accA[dt] = (f32x4){0.f,0.f,0.f,0.f}; accB[dt] = (f32x4){0.f,0.f,0.f,0.f}; }

    int sub = lane >> 3, s7 = lane & 7;
    int scol16 = s7 ^ sub;
    int c0 = 2 * w, c1 = 2 * w + 1;

    #define STAGE(buf, t_) do { \
        int kk0 = (t_) * 64; \
        gload16(Kb + (size_t)(kk0 + 8 * c0 + sub) * 64 + scol16 * 8, &KVs[buf][0][c0 * 512]); \
        gload16(Kb + (size_t)(kk0 + 8 * c1 + sub) * 64 + scol16 * 8, &KVs[buf][0][c1 * 512]); \
        gload16(Vb + (size_t)(8 * c0 + sub) * 1024 + kk0 + scol16 * 8, &KVs[buf][1][c0 * 512]); \
        gload16(Vb + (size_t)(8 * c1 + sub) * 1024 + kk0 + scol16 * 8, &KVs[buf][1][c1 * 512]); \
    } while (0)

    STAGE(0, 0);
    asm volatile("s_waitcnt vmcnt(0)" ::: "memory");
    __syncthreads();
    int cur = 0;

    for (int t = 0; t <= qtb; ++t) {
        if (t < qtb) STAGE(cur ^ 1, t + 1);
        const int k0 = t * 64;
        const bool doA = (t <= qta);
        const u16* Kl = KVs[cur][0];
        const u16* Vl = KVs[cur][1];

        float svA[4][4], svB[4][4];
        __builtin_amdgcn_s_setprio(1);
        #pragma unroll
        for (int t4 = 0; t4 < 4; ++t4) {
            int r = t4 * 16 + lr;
            bf16x8 kf0 = *reinterpret_cast<const bf16x8*>(&Kl[r * 64 + ((lg ^ lr7) << 3)]);
            bf16x8 kf1 = *reinterpret_cast<const bf16x8*>(&Kl[r * 64 + (((4 | lg) ^ lr7) << 3)]);
            if (doA) {
                f32x4 z = (f32x4){0.f,0.f,0.f,0.f};
                z = __builtin_amdgcn_mfma_f32_16x16x32_bf16(qa0, kf0, z, 0, 0, 0);
                z = __builtin_amdgcn_mfma_f32_16x16x32_bf16(qa1, kf1, z, 0, 0, 0);
                #pragma unroll
                for (int rr = 0; rr < 4; ++rr) svA[t4][rr] = z[rr];
            }
            f32x4 z2 = (f32x4){0.f,0.f,0.f,0.f};
            z2 = __builtin_amdgcn_mfma_f32_16x16x32_bf16(qb0, kf0, z2, 0, 0, 0);
            z2 = __builtin_amdgcn_mfma_f32_16x16x32_bf16(qb1, kf1, z2, 0, 0, 0);
            #pragma unroll
            for (int rr = 0; rr < 4; ++rr) svB[t4][rr] = z2[rr];
        }
        __builtin_amdgcn_s_setprio(0);
        if (doA && t == qta) {
            #pragma unroll
            for (int t4 = 0; t4 < 4; ++t4) {
                int key = k0 + t4 * 16 + lr;
                #pragma unroll
                for (int rr = 0; rr < 4; ++rr)
                    if (key > q0a + lg * 4 + rr) svA[t4][rr] = -3.0e38f;
            }
        }
        if (t == qtb) {
            #pragma unroll
            for (int t4 = 0; t4 < 4; ++t4) {
                int key = k0 + t4 * 16 + lr;
                #pragma unroll
                for (int rr = 0; rr < 4; ++rr)
                    if (key > q0b + lg * 4 + rr) svB[t4][rr] = -3.0e38f;
            }
        }

        bf16x8 paA0, paA1, paB0, paB1;
        if (doA) {
            float vx[4]; int ok = 1;
            #pragma unroll
            for (int rr = 0; rr < 4; ++rr) {
                vx[rr] = fmaxf(fmaxf(svA[0][rr], svA[1][rr]), fmaxf(svA[2][rr], svA[3][rr]));
                ok &= (vx[rr] <= mA[rr] + 8.0f);
            }
            if (!__all(ok)) {
                #pragma unroll
                for (int rr = 0; rr < 4; ++rr) {
                    float mm = vx[rr];
                    #pragma unroll
                    for (int off = 8; off; off >>= 1) mm = fmaxf(mm, __shfl_xor(mm, off));
                    float mn = fmaxf(mA[rr], mm);
                    float corr = exp2f(mA[rr] - mn);
                    mA[rr] = mn;
                    lpA[rr] *= corr;
                    #pragma unroll
                    for (int dt = 0; dt < 4; ++dt) accA[dt][rr] *= corr;
                }
            }
            #pragma unroll
            for (int rr = 0; rr < 4; ++rr) {
                float p0 = exp2f(svA[0][rr] - mA[rr]);
                float p1 = exp2f(svA[1][rr] - mA[rr]);
                float p2 = exp2f(svA[2][rr] - mA[rr]);
                float p3 = exp2f(svA[3][rr] - mA[rr]);
                lpA[rr] += (p0 + p1) + (p2 + p3);
                unsigned pk01, pk23;
                asm("v_cvt_pk_bf16_f32 %0, %1, %2" : "=v"(pk01) : "v"(p0), "v"(p1));
                asm("v_cvt_pk_bf16_f32 %0, %1, %2" : "=v"(pk23) : "v"(p2), "v"(p3));
                int row = lg * 4 + rr, r7 = row & 7;
                Pw32[row * 32 + (((lr >> 2) ^ r7) << 2) + (lr & 3)] = pk01;
                Pw32[row * 32 + ((((lr >> 2) + 4) ^ r7) << 2) + (lr & 3)] = pk23;
            }
            paA0 = *reinterpret_cast<const bf16x8*>(&Psw[lr * 64 + ((lg ^ lr7) << 3)]);
            paA1 = *reinterpret_cast<const bf16x8*>(&Psw[lr * 64 + (((4 | lg) ^ lr7) << 3)]);
        }

        {
            float vx[4]; int ok = 1;
            #pragma unroll
            for (int rr = 0; rr < 4; ++rr) {
                vx[rr] = fmaxf(fmaxf(svB[0][rr], svB[1][rr]), fmaxf(svB[2][rr], svB[3][rr]));
                ok &= (vx[rr] <= mB[rr] + 8.0f);
            }
            if (!__all(ok)) {
                #pragma unroll
                for (int rr = 0; rr < 4; ++rr) {
                    float mm = vx[rr];
                    #pragma unroll
                    for (int off = 8; off; off >>= 1) mm = fmaxf(mm, __shfl_xor(mm, off));
                    float mn = fmaxf(mB[rr], mm);
                    float corr = exp2f(mB[rr] - mn);
                    mB[rr] = mn;
                    lpB[rr] *= corr;
                    #pragma unroll
                    for (int dt = 0; dt < 4; ++dt) accB[dt][rr] *= corr;
                }
            }
            #pragma unroll
            for (int rr = 0; rr < 4; ++rr) {
                float p0 = exp2f(svB[0][rr] - mB[rr]);
                float p1 = exp2f(svB[1][rr] - mB[rr]);
                float p2 = exp2f(svB[2][rr] - mB[rr]);
                float p3 = exp2f(svB[3][rr] - mB[rr]);
                lpB[rr] += (p0 + p1) + (p2 + p3);
                unsigned pk01, pk23;
                asm("v_cvt_pk_bf16_f32 %0, %1, %2" : "=v"(pk01) : "v"(p0), "v"(p1));
                asm("v_cvt_pk_bf16_f32 %0, %1, %2" : "=v"(pk23) : "v"(p2), "v"(p3));
                int row = lg * 4 + rr, r7 = row & 7;
                Pw32[row * 32 + (((lr >> 2) ^ r7) << 2) + (lr & 3)] = pk01;
                Pw32[row * 32 + ((((lr >> 2) + 4) ^ r7) << 2) + (lr & 3)] = pk23;
            }
            paB0 = *reinterpret_cast<const bf16x8*>(&Psw[lr * 64 + ((lg ^ lr7) << 3)]);
            paB1 = *reinterpret_cast<const bf16x8*>(&Psw[lr * 64 + (((4 | lg) ^ lr7) << 3)]);
        }

        __builtin_amdgcn_s_setprio(1);
        #pragma unroll
        for (int dt = 0; dt < 4; ++dt) {
            int r = dt * 16 + lr;
            bf16x8 vf0 = *reinterpret_cast<const bf16x8*>(&Vl[r * 64 + ((lg ^ lr7) << 3)]);
            bf16x8 vf1 = *reinterpret_cast<const bf16x8*>(&Vl[r * 64 + (((4 | lg) ^ lr7) << 3)]);
            if (doA) {
                accA[dt] = __builtin_amdgcn_mfma_f32_16x16x32_bf16(paA0, vf0, accA[dt], 0, 0, 0);
                accA[dt] = __builtin_amdgcn_mfma_f32_16x16x32_bf16(paA1, vf1, accA[dt], 0, 0, 0);
            }
            accB[dt] = __builtin_amdgcn_mfma_f32_16x16x32_bf16(paB0, vf0, accB[dt], 0, 0, 0);
            accB[dt] = __builtin_amdgcn_mfma_f32_16x16x32_bf16(paB1, vf1, accB[dt], 0, 0, 0);
        }
        __builtin_amdgcn_s_setprio(0);

        asm volatile("s_waitcnt vmcnt(0)" ::: "memory");
        __syncthreads();
        cur ^= 1;
    }
    #undef STAGE

    #pragma unroll
    for (int rr = 0; rr < 4; ++rr) {
        #pragma unroll
        for (int off = 8; off; off >>= 1) {
            lpA[rr] += __shfl_xor(lpA[rr], off);
            lpB[rr] += __shfl_xor(lpB[rr], off);
        }
    }

    #pragma unroll
    for (int rr = 0; rr < 4; ++rr) {
        float invA = 1.0f / lpA[rr];
        float invB = 1.0f / lpB[rr];
        size_t baseA = ((size_t)(b * 1024 + q0a + lg * 4 + rr)) * 1024 + h * 64;
        size_t baseB = ((size_t)(b * 1024 + q0b + lg * 4 + rr)) * 1024 + h * 64;
        #pragma unroll
        for (int dt = 0; dt < 4; ++dt) {
            Y[baseA + dt * 16 + lr] = f2bf(accA[dt][rr] * invA);
            Y[baseB + dt * 16 + lr] = f2bf(accB[dt][rr] * invB);
        }
    }
}

extern "C" void kernel_launch(void* const* d_in, const int* in_sizes, int n_in,
                              void* d_out, int out_size, void* d_ws, size_t ws_size,
                              hipStream_t stream) {
    (void)in_sizes; (void)n_in; (void)out_size; (void)ws_size;
    const float* x  = (const float*)d_in[0];
    const float* Wq = (const float*)d_in[1];
    const float* Wk = (const float*)d_in[2];
    const float* Wv = (const float*)d_in[3];
    const float* Wp = (const float*)d_in[4];
    const float* qg = (const float*)d_in[5];
    float* out = (float*)d_out;

    float* p = (float*)d_ws;
    float* partial = p; p += 256;
    float* alpha = p;   p += 16;
    s8* wtqkv = (s8*)p; p += 393216;     // 1536x1024 i8
    s8* wtp   = (s8*)p; p += 262144;     // 1024x1024 i8
    s8* xq    = (s8*)p; p += 2097152;    // 8192x1024 i8
    float* gam = p; p += 8192;
    u16* y16   = (u16*)p; p += 4194304;  // bf16 [8192][1024] attn output
    u16* qo = (u16*)p; p += 4194304;     // bf16 [b,16,1024,64]
    u16* ko = (u16*)p; p += 1048576;     // bf16 [b,4,1024,64]
    u16* vt = (u16*)p; p += 1048576;     // bf16 [b,4,64,pos]
    float* rc = p; p += 32768;
    float* rs = p; p += 32768;
    s8* yq = xq;   // reuse (xq dead after qkv gemm)

    // weight quantization (fused: 3 dispatches, i8 output)
    k_absmean_all<<<256, 256, 0, stream>>>(Wq, Wk, Wv, Wp, partial);
    k_rope_alpha<<<128, 256, 0, stream>>>(rc, rs, partial, alpha);
    k_tern_all<<<2560, 256, 0, stream>>>(Wq, Wk, Wv, Wp, alpha, wtqkv, wtp);

    // activation quantization + fused i8 QKV projection (+norm/rope + V transpose)
    k_quant<<<ROWS, 256, 0, stream>>>(x, xq, gam);
    k_gemm_qkv<<<dim3(12, 64), 256, 0, stream>>>(xq, wtqkv, gam, alpha, rc, rs, qg, qo, ko, vt);

    // attention (packed P via LDS, paired causal tiles, setprio, XCD-swizzled, bf16 out)
    k_attn_mfma<<<dim3(8, 16, 8), 256, 0, stream>>>(qo, ko, vt, y16);

    // output projection (i8)
    k_quant_bf16<<<ROWS, 256, 0, stream>>>(y16, yq, gam);
    k_gemm_out<<<dim3(8, 64), 256, 0, stream>>>(yq, wtp, gam, alpha, out);
}

// Round 16
// 151.190 us; speedup vs baseline: 1.7659x; 1.0334x over previous
//
#include <hip/hip_runtime.h>
#include <cmath>

#define DIMM 1024
#define NHEADS 16
#define NKV 4
#define HD 64
#define SEQ 1024
#define BSZ 8
#define ROWS (BSZ * SEQ)   // 8192

typedef unsigned short u16;
typedef signed char s8;
typedef __attribute__((ext_vector_type(8))) short bf16x8;
typedef __attribute__((ext_vector_type(8))) unsigned short u16x8;
typedef __attribute__((ext_vector_type(4))) float f32x4;
typedef __attribute__((ext_vector_type(4))) int i32x4;
typedef __attribute__((ext_vector_type(4))) unsigned short u16x4;
typedef __attribute__((ext_vector_type(4))) unsigned int u32x4;

static __device__ __forceinline__ u16 f2bf(float f) {
    union { float f; unsigned u; } v; v.f = f;
    unsigned r = v.u + 0x7FFFu + ((v.u >> 16) & 1u);
    return (u16)(r >> 16);
}
static __device__ __forceinline__ float bf2f(u16 h) {
    union { unsigned u; float f; } v; v.u = ((unsigned)h) << 16;
    return v.f;
}

// async global->LDS, 16B per lane; dst must be wave-uniform base (HW adds lane*16)
static __device__ __forceinline__ void gload16(const void* g, void* l) {
    __builtin_amdgcn_global_load_lds(
        (const __attribute__((address_space(1))) unsigned int*)g,
        (__attribute__((address_space(3))) unsigned int*)l, 16, 0, 0);
}

static __device__ __forceinline__ unsigned packdiv4(float a, float b, float c, float d, float gamma) {
    int q0 = (int)rintf(fminf(fmaxf(a / gamma, -128.f), 127.f));
    int q1 = (int)rintf(fminf(fmaxf(b / gamma, -128.f), 127.f));
    int q2 = (int)rintf(fminf(fmaxf(c / gamma, -128.f), 127.f));
    int q3 = (int)rintf(fminf(fmaxf(d / gamma, -128.f), 127.f));
    return (q0 & 0xff) | ((q1 & 0xff) << 8) | ((q2 & 0xff) << 16) | ((q3 & 0xff) << 24);
}

// ---------------- fused: weight abs-mean (blocks 0..255) + x quantization (256..2303) ----------------
__global__ __launch_bounds__(256) void k_prep1(const float* __restrict__ Wq,
                                               const float* __restrict__ Wk,
                                               const float* __restrict__ Wv,
                                               const float* __restrict__ Wp,
                                               float* __restrict__ partial,
                                               const float* __restrict__ X,
                                               s8* __restrict__ Xq, float* __restrict__ g) {
    if (blockIdx.x < 256) {
        int wi = blockIdx.x >> 6, local = blockIdx.x & 63;
        const float* w = (wi == 0) ? Wq : (wi == 1) ? Wk : (wi == 2) ? Wv : Wp;
        int n = (wi == 0 || wi == 3) ? 1048576 : 262144;
        float s = 0.f;
        for (int i = local * 256 + threadIdx.x; i < n; i += 64 * 256) s += fabsf(w[i]);
        #pragma unroll
        for (int off = 32; off; off >>= 1) s += __shfl_xor(s, off);
        __shared__ float red[4];
        if ((threadIdx.x & 63) == 0) red[threadIdx.x >> 6] = s;
        __syncthreads();
        if (threadIdx.x == 0) partial[blockIdx.x] = red[0] + red[1] + red[2] + red[3];
    } else {
        int row = (blockIdx.x - 256) * 4 + (threadIdx.x >> 6);
        int lane = threadIdx.x & 63;
        const float* xr = X + (size_t)row * DIMM + lane * 16;
        float4 v0 = *reinterpret_cast<const float4*>(xr + 0);
        float4 v1 = *reinterpret_cast<const float4*>(xr + 4);
        float4 v2 = *reinterpret_cast<const float4*>(xr + 8);
        float4 v3 = *reinterpret_cast<const float4*>(xr + 12);
        float mv = fmaxf(fmaxf(fmaxf(fabsf(v0.x), fabsf(v0.y)), fmaxf(fabsf(v0.z), fabsf(v0.w))),
                         fmaxf(fmaxf(fabsf(v1.x), fabsf(v1.y)), fmaxf(fabsf(v1.z), fabsf(v1.w))));
        mv = fmaxf(mv, fmaxf(fmaxf(fabsf(v2.x), fabsf(v2.y)), fmaxf(fabsf(v2.z), fabsf(v2.w))));
        mv = fmaxf(mv, fmaxf(fmaxf(fabsf(v3.x), fabsf(v3.y)), fmaxf(fabsf(v3.z), fabsf(v3.w))));
        #pragma unroll
        for (int off = 32; off; off >>= 1) mv = fmaxf(mv, __shfl_xor(mv, off));
        float gamma = fmaxf(mv, 1e-8f) / 127.0f;
        u32x4 st;
        st.x = packdiv4(v0.x, v0.y, v0.z, v0.w, gamma);
        st.y = packdiv4(v1.x, v1.y, v1.z, v1.w, gamma);
        st.z = packdiv4(v2.x, v2.y, v2.z, v2.w, gamma);
        st.w = packdiv4(v3.x, v3.y, v3.z, v3.w, gamma);
        *reinterpret_cast<u32x4*>(Xq + (size_t)row * DIMM + lane * 16) = st;
        if (lane == 0) g[row] = gamma;
    }
}

// ---------------- rope table + alpha (fused) ----------------
__global__ __launch_bounds__(256) void k_rope_alpha(float* __restrict__ c, float* __restrict__ s,
                                                    const float* __restrict__ partial,
                                                    float* __restrict__ alpha) {
    int idx = blockIdx.x * 256 + threadIdx.x;  // < 32768
    int t = idx >> 5, i = idx & 31;
    float inv = 1.0f / powf(10000.0f, (float)(2 * i) * (1.0f / 64.0f));
    float f = (float)t * inv;
    c[idx] = cosf(f);
    s[idx] = sinf(f);
    if (blockIdx.x == 0 && threadIdx.x < 4) {
        const int ns[4] = {1048576, 262144, 262144, 1048576};
        float su = 0.f;
        for (int j = 0; j < 64; ++j) su += partial[threadIdx.x * 64 + j];
        alpha[threadIdx.x] = fmaxf(su / (float)ns[threadIdx.x], 1e-8f);
    }
}

// ---------------- fused ternarize -> i8 {-1,0,1}, one dispatch ----------------
__global__ __launch_bounds__(256) void k_tern_all(const float* __restrict__ Wq,
                                                  const float* __restrict__ Wk,
                                                  const float* __restrict__ Wv,
                                                  const float* __restrict__ Wp,
                                                  const float* __restrict__ alpha,
                                                  s8* __restrict__ wtqkv,
                                                  s8* __restrict__ wtp) {
    int idx = blockIdx.x * 256 + threadIdx.x;   // < 655360
    const float* src; s8* dst; float a;
    if (idx < 262144)      { src = Wq + (size_t)idx * 4;            dst = wtqkv + (size_t)idx * 4;                 a = alpha[0]; }
    else if (idx < 327680) { src = Wk + (size_t)(idx - 262144) * 4; dst = wtqkv + 1048576 + (size_t)(idx - 262144) * 4; a = alpha[1]; }
    else if (idx < 393216) { src = Wv + (size_t)(idx - 327680) * 4; dst = wtqkv + 1310720 + (size_t)(idx - 327680) * 4; a = alpha[2]; }
    else                   { src = Wp + (size_t)(idx - 393216) * 4; dst = wtp + (size_t)(idx - 393216) * 4;        a = alpha[3]; }
    float4 v = *reinterpret_cast<const float4*>(src);
    int q0 = (int)rintf(fminf(fmaxf(v.x / a, -1.f), 1.f));
    int q1 = (int)rintf(fminf(fmaxf(v.y / a, -1.f), 1.f));
    int q2 = (int)rintf(fminf(fmaxf(v.z / a, -1.f), 1.f));
    int q3 = (int)rintf(fminf(fmaxf(v.w / a, -1.f), 1.f));
    *reinterpret_cast<unsigned*>(dst) =
        (q0 & 0xff) | ((q1 & 0xff) << 8) | ((q2 & 0xff) << 16) | ((q3 & 0xff) << 24);
}

// ---------------- per-row activation quantization (bf16 input, wave-per-row) -> i8 ----------------
__global__ __launch_bounds__(256) void k_quant_bf16(const u16* __restrict__ X,
                                                    s8* __restrict__ Xq, float* __restrict__ g) {
    int row = blockIdx.x * 4 + (threadIdx.x >> 6);
    int lane = threadIdx.x & 63;
    const u16* xr = X + (size_t)row * DIMM + lane * 16;
    u16x8 h0 = *reinterpret_cast<const u16x8*>(xr);
    u16x8 h1 = *reinterpret_cast<const u16x8*>(xr + 8);
    float v[16];
    #pragma unroll
    for (int j = 0; j < 8; ++j) { v[j] = bf2f(h0[j]); v[8 + j] = bf2f(h1[j]); }
    float mv = 0.f;
    #pragma unroll
    for (int j = 0; j < 16; ++j) mv = fmaxf(mv, fabsf(v[j]));
    #pragma unroll
    for (int off = 32; off; off >>= 1) mv = fmaxf(mv, __shfl_xor(mv, off));
    float gamma = fmaxf(mv, 1e-8f) / 127.0f;
    u32x4 st;
    st.x = packdiv4(v[0], v[1], v[2], v[3], gamma);
    st.y = packdiv4(v[4], v[5], v[6], v[7], gamma);
    st.z = packdiv4(v[8], v[9], v[10], v[11], gamma);
    st.w = packdiv4(v[12], v[13], v[14], v[15], gamma);
    *reinterpret_cast<u32x4*>(Xq + (size_t)row * DIMM + lane * 16) = st;
    if (lane == 0) g[row] = gamma;
}

// ---------------- i8 QKV GEMM: fused rms_norm+rope epilogue + fused V transpose ----------------
__global__ __launch_bounds__(256) void k_gemm_qkv(const s8* __restrict__ A,
                                                  const s8* __restrict__ B,
                                                  const float* __restrict__ gamma,
                                                  const float* __restrict__ alpha_p,
                                                  const float* __restrict__ rc,
                                                  const float* __restrict__ rs,
                                                  const float* __restrict__ gain,
                                                  u16* __restrict__ Qo,
                                                  u16* __restrict__ Ko,
                                                  u16* __restrict__ Vt) {
    __shared__ __align__(16) s8 SMEM[32768];
    s8* As = SMEM;
    s8* Bs = SMEM + 16384;
    const int K = DIMM;
    int tid = threadIdx.x;
    int w = tid >> 6, lane = tid & 63;
    int lr = lane & 15, lg = lane >> 4;
    int lr7 = lr & 7;
    int wm = w >> 1, wn = w & 1;
    int orig = blockIdx.x + 12 * blockIdx.y;
    int wgid = (orig & 7) * 96 + (orig >> 3);
    int bx = wgid % 12, by = wgid / 12;
    int row0 = by * 128, col0 = bx * 128;

    i32x4 acc[4][4];
    #pragma unroll
    for (int mf = 0; mf < 4; ++mf)
        #pragma unroll
        for (int nf = 0; nf < 4; ++nf) acc[mf][nf] = (i32x4){0, 0, 0, 0};

    int srow = w * 32 + (lane >> 3);
    int scol = 16 * ((lane & 7) ^ (lane >> 3));
    const s8* Ag = A + (size_t)(row0 + srow) * K + scol;
    const s8* Bg = B + (size_t)(col0 + srow) * K + scol;

    for (int k0 = 0; k0 < K; k0 += 128) {
        #pragma unroll
        for (int i = 0; i < 4; ++i) {
            gload16(Ag + (size_t)i * 8 * K + k0, &As[w * 4096 + i * 1024]);
            gload16(Bg + (size_t)i * 8 * K + k0, &Bs[w * 4096 + i * 1024]);
        }
        __syncthreads();
        #pragma unroll
        for (int kh = 0; kh < 2; ++kh) {
            i32x4 af[4], bfr[4];
            #pragma unroll
            for (int mf = 0; mf < 4; ++mf)
                af[mf] = *reinterpret_cast<const i32x4*>(
                    &As[(wm * 64 + mf * 16 + lr) * 128 + 16 * (((kh << 2) + lg) ^ lr7)]);
            #pragma unroll
            for (int nf = 0; nf < 4; ++nf)
                bfr[nf] = *reinterpret_cast<const i32x4*>(
                    &Bs[(wn * 64 + nf * 16 + lr) * 128 + 16 * (((kh << 2) + lg) ^ lr7)]);
            #pragma unroll
            for (int mf = 0; mf < 4; ++mf)
                #pragma unroll
                for (int nf = 0; nf < 4; ++nf)
                    acc[mf][nf] = __builtin_amdgcn_mfma_i32_16x16x64_i8(af[mf], bfr[nf], acc[mf][nf], 0, 0, 0);
        }
        __syncthreads();
    }

    int c0 = col0 + wn * 64;
    int hh = c0 >> 6;   // 0..15 Q heads, 16..19 K heads, 20..23 V heads
    float alpha = alpha_p[hh < 16 ? 0 : (hh < 20 ? 1 : 2)];

    if (hh < 20) {
        float ga = (hh < 16) ? gain[hh] * (0.125f * 1.4426950408889634f) : 1.0f;
        #pragma unroll
        for (int mf = 0; mf < 4; ++mf) {
            #pragma unroll
            for (int reg = 0; reg < 4; ++reg) {
                int row = row0 + wm * 64 + mf * 16 + lg * 4 + reg;
                float sc = gamma[row] * alpha;
                float v0 = (float)acc[mf][0][reg] * sc;
                float v1 = (float)acc[mf][1][reg] * sc;
                float v2 = (float)acc[mf][2][reg] * sc;
                float v3 = (float)acc[mf][3][reg] * sc;
                int s = row & 1023, b = row >> 10;
                float ss = v0 * v0 + v1 * v1 + v2 * v2 + v3 * v3;
                #pragma unroll
                for (int off = 8; off; off >>= 1) ss += __shfl_xor(ss, off);
                float rn = 1.0f / sqrtf(ss * (1.0f / 64.0f) + 1.1920929e-07f);
                v0 *= rn; v1 *= rn; v2 *= rn; v3 *= rn;
                float cA = rc[s * 32 + lr],      sA = rs[s * 32 + lr];
                float cB = rc[s * 32 + 16 + lr], sB = rs[s * 32 + 16 + lr];
                float y0 = v0 * cA + v2 * sA, y2 = v2 * cA - v0 * sA;
                float y1 = v1 * cB + v3 * sB, y3 = v3 * cB - v1 * sB;
                u16* dst;
                if (hh < 16) {
                    y0 *= ga; y1 *= ga; y2 *= ga; y3 *= ga;
                    dst = Qo + ((size_t)((b * 16 + hh) * 1024 + s)) * 64;
                } else {
                    dst = Ko + ((size_t)((b * 4 + (hh - 16)) * 1024 + s)) * 64;
                }
                dst[lr] = f2bf(y0); dst[16 + lr] = f2bf(y1);
                dst[32 + lr] = f2bf(y2); dst[48 + lr] = f2bf(y3);
            }
        }
    } else {
        int kv = hh - 20;
        u16* T = reinterpret_cast<u16*>(SMEM) + w * 4096;
        #pragma unroll
        for (int mf = 0; mf < 4; ++mf) {
            int pb = (mf & 1) + 32 * (mf >> 1);
            #pragma unroll
            for (int reg = 0; reg < 4; ++reg) {
                int row = row0 + wm * 64 + mf * 16 + lg * 4 + reg;
                float sc = gamma[row] * alpha;
                int pos = 2 * (lg * 4 + reg) + pb;
                #pragma unroll
                for (int nf = 0; nf < 4; ++nf) {
                    int d = nf * 16 + lr;
                    T[d * 64 + (pos ^ (lr7 << 3))] = f2bf((float)acc[mf][nf][reg] * sc);
                }
            }
        }
        int b = row0 >> 10;
        int st = ((row0 & 1023) + wm * 64) >> 6;
        int d = lane, h3 = lane & 7;
        u16* dst = Vt + (((size_t)(b * 4 + kv) * 64) + d) * 1024 + st * 64;
        #pragma unroll
        for (int j = 0; j < 8; ++j) {
            u16x8 gv = *reinterpret_cast<const u16x8*>(&T[d * 64 + 8 * (j ^ h3)]);
            *reinterpret_cast<u16x8*>(&dst[8 * j]) = gv;
        }
    }
}

// ---------------- i8 GEMM for output projection (XCD-swizzled) ----------------
__global__ __launch_bounds__(256) void k_gemm_out(const s8* __restrict__ A,
                                                  const s8* __restrict__ B,
                                                  const float* __restrict__ gamma,
                                                  const float* __restrict__ alpha_p,
                                                  float* __restrict__ C) {
    __shared__ s8 As[128 * 128];
    __shared__ s8 Bs[128 * 128];
    const int K = DIMM;
    int tid = threadIdx.x;
    int w = tid >> 6, lane = tid & 63;
    int lr = lane & 15, lg = lane >> 4;
    int lr7 = lr & 7;
    int wm = w >> 1, wn = w & 1;
    int orig = blockIdx.x + 8 * blockIdx.y;
    int wgid = ((orig & 7) << 6) + (orig >> 3);
    int row0 = (wgid >> 3) * 128, col0 = (wgid & 7) * 128;

    i32x4 acc[4][4];
    #pragma unroll
    for (int mf = 0; mf < 4; ++mf)
        #pragma unroll
        for (int nf = 0; nf < 4; ++nf) acc[mf][nf] = (i32x4){0, 0, 0, 0};

    int srow = w * 32 + (lane >> 3);
    int scol = 16 * ((lane & 7) ^ (lane >> 3));
    const s8* Ag = A + (size_t)(row0 + srow) * K + scol;
    const s8* Bg = B + (size_t)(col0 + srow) * K + scol;

    for (int k0 = 0; k0 < K; k0 += 128) {
        #pragma unroll
        for (int i = 0; i < 4; ++i) {
            gload16(Ag + (size_t)i * 8 * K + k0, &As[w * 4096 + i * 1024]);
            gload16(Bg + (size_t)i * 8 * K + k0, &Bs[w * 4096 + i * 1024]);
        }
        __syncthreads();
        #pragma unroll
        for (int kh = 0; kh < 2; ++kh) {
            i32x4 af[4], bfr[4];
            #pragma unroll
            for (int mf = 0; mf < 4; ++mf)
                af[mf] = *reinterpret_cast<const i32x4*>(
                    &As[(wm * 64 + mf * 16 + lr) * 128 + 16 * (((kh << 2) + lg) ^ lr7)]);
            #pragma unroll
            for (int nf = 0; nf < 4; ++nf)
                bfr[nf] = *reinterpret_cast<const i32x4*>(
                    &Bs[(wn * 64 + nf * 16 + lr) * 128 + 16 * (((kh << 2) + lg) ^ lr7)]);
            #pragma unroll
            for (int mf = 0; mf < 4; ++mf)
                #pragma unroll
                for (int nf = 0; nf < 4; ++nf)
                    acc[mf][nf] = __builtin_amdgcn_mfma_i32_16x16x64_i8(af[mf], bfr[nf], acc[mf][nf], 0, 0, 0);
        }
        __syncthreads();
    }

    float alpha = alpha_p[3];
    #pragma unroll
    for (int mf = 0; mf < 4; ++mf) {
        #pragma unroll
        for (int reg = 0; reg < 4; ++reg) {
            int row = row0 + wm * 64 + mf * 16 + lg * 4 + reg;
            float sc = gamma[row] * alpha;
            #pragma unroll
            for (int nf = 0; nf < 4; ++nf)
                C[(size_t)row * 1024 + col0 + wn * 64 + nf * 16 + lr] = (float)acc[mf][nf][reg] * sc;
        }
    }
}

// ---------------- causal flash attention, bf16 MFMA, paired q-tiles ----------------
// Round-13 exact (libm exp2f / plain division — amdgcn exp2/rcp intrinsics are BROKEN here).
__global__ __launch_bounds__(256) void k_attn_mfma(const u16* __restrict__ Q,
                                                   const u16* __restrict__ K,
                                                   const u16* __restrict__ Vt,
                                                   u16* __restrict__ Y) {
    __shared__ __align__(16) u16 KVs[2][2][4096];   // [buf][K/V][64*64], swizzled
    __shared__ __align__(16) u16 Ps[4][1024];       // per-wave P strip [16 q][64 pos], swizzled
    int orig = blockIdx.x + ((blockIdx.y + (blockIdx.z << 4)) << 3);
    int wgid = ((orig & 7) << 7) + (orig >> 3);
    int qta = wgid & 7, qtb = 15 - qta;
    int h = (wgid >> 3) & 15, b = wgid >> 7;
    int kvh = h >> 2;
    int tid = threadIdx.x;
    int w = tid >> 6, lane = tid & 63;
    int lr = lane & 15, lg = lane >> 4;
    int lr7 = lr & 7;
    int q0a = qta * 64 + w * 16, q0b = qtb * 64 + w * 16;
    const u16* Qb = Q + (((size_t)b * 16 + h) * 1024) * 64;
    const u16* Kb = K + (((size_t)b * 4 + kvh) * 1024) * 64;
    const u16* Vb = Vt + (((size_t)b * 4 + kvh) * 64) * 1024;
    u16* Psw = Ps[w];
    unsigned* Pw32 = reinterpret_cast<unsigned*>(Psw);

    bf16x8 qa0 = *reinterpret_cast<const bf16x8*>(&Qb[(size_t)(q0a + lr) * 64 + 8 * lg]);
    bf16x8 qa1 = *reinterpret_cast<const bf16x8*>(&Qb[(size_t)(q0a + lr) * 64 + 32 + 8 * lg]);
    bf16x8 qb0 = *reinterpret_cast<const bf16x8*>(&Qb[(size_t)(q0b + lr) * 64 + 8 * lg]);
    bf16x8 qb1 = *reinterpret_cast<const bf16x8*>(&Qb[(size_t)(q0b + lr) * 64 + 32 + 8 * lg]);

    float mA[4], lpA[4], mB[4], lpB[4];
    f32x4 accA[4], accB[4];
    #pragma unroll
    for (int r = 0; r < 4; ++r) { mA[r] = -INFINITY; lpA[r] = 0.f; mB[r] = -INFINITY; lpB[r] = 0.f; }
    #pragma unroll
    for (int dt = 0; dt < 4; ++dt) { accA[dt] = (f32x4){0.f,0.f,0.f,0.f}; accB[dt] = (f32x4){0.f,0.f,0.f,0.f}; }

    int sub = lane >> 3, s7 = lane & 7;
    int scol16 = s7 ^ sub;
    int c0 = 2 * w, c1 = 2 * w + 1;

    #define STAGE(buf, t_) do { \
        int kk0 = (t_) * 64; \
        gload16(Kb + (size_t)(kk0 + 8 * c0 + sub) * 64 + scol16 * 8, &KVs[buf][0][c0 * 512]); \
        gload16(Kb + (size_t)(kk0 + 8 * c1 + sub) * 64 + scol16 * 8, &KVs[buf][0][c1 * 512]); \
        gload16(Vb + (size_t)(8 * c0 + sub) * 1024 + kk0 + scol16 * 8, &KVs[buf][1][c0 * 512]); \
        gload16(Vb + (size_t)(8 * c1 + sub) * 1024 + kk0 + scol16 * 8, &KVs[buf][1][c1 * 512]); \
    } while (0)

    STAGE(0, 0);
    asm volatile("s_waitcnt vmcnt(0)" ::: "memory");
    __syncthreads();
    int cur = 0;

    for (int t = 0; t <= qtb; ++t) {
        if (t < qtb) STAGE(cur ^ 1, t + 1);
        const int k0 = t * 64;
        const bool doA = (t <= qta);
        const u16* Kl = KVs[cur][0];
        const u16* Vl = KVs[cur][1];

        float svA[4][4], svB[4][4];
        __builtin_amdgcn_s_setprio(1);
        #pragma unroll
        for (int t4 = 0; t4 < 4; ++t4) {
            int r = t4 * 16 + lr;
            bf16x8 kf0 = *reinterpret_cast<const bf16x8*>(&Kl[r * 64 + ((lg ^ lr7) << 3)]);
            bf16x8 kf1 = *reinterpret_cast<const bf16x8*>(&Kl[r * 64 + (((4 | lg) ^ lr7) << 3)]);
            if (doA) {
                f32x4 z = (f32x4){0.f,0.f,0.f,0.f};
                z = __builtin_amdgcn_mfma_f32_16x16x32_bf16(qa0, kf0, z, 0, 0, 0);
                z = __builtin_amdgcn_mfma_f32_16x16x32_bf16(qa1, kf1, z, 0, 0, 0);
                #pragma unroll
                for (int rr = 0; rr < 4; ++rr) svA[t4][rr] = z[rr];
            }
            f32x4 z2 = (f32x4){0.f,0.f,0.f,0.f};
            z2 = __builtin_amdgcn_mfma_f32_16x16x32_bf16(qb0, kf0, z2, 0, 0, 0);
            z2 = __builtin_amdgcn_mfma_f32_16x16x32_bf16(qb1, kf1, z2, 0, 0, 0);
            #pragma unroll
            for (int rr = 0; rr < 4; ++rr) svB[t4][rr] = z2[rr];
        }
        __builtin_amdgcn_s_setprio(0);
        if (doA && t == qta) {
            #pragma unroll
            for (int t4 = 0; t4 < 4; ++t4) {
                int key = k0 + t4 * 16 + lr;
                #pragma unroll
                for (int rr = 0; rr < 4; ++rr)
                    if (key > q0a + lg * 4 + rr) svA[t4][rr] = -3.0e38f;
            }
        }
        if (t == qtb) {
            #pragma unroll
            for (int t4 = 0; t4 < 4; ++t4) {
                int key = k0 + t4 * 16 + lr;
                #pragma unroll
                for (int rr = 0; rr < 4; ++rr)
                    if (key > q0b + lg * 4 + rr) svB[t4][rr] = -3.0e38f;
            }
        }

        bf16x8 paA0, paA1, paB0, paB1;
        if (doA) {
            float vx[4]; int ok = 1;
            #pragma unroll
            for (int rr = 0; rr < 4; ++rr) {
                vx[rr] = fmaxf(fmaxf(svA[0][rr], svA[1][rr]), fmaxf(svA[2][rr], svA[3][rr]));
                ok &= (vx[rr] <= mA[rr] + 8.0f);
            }
            if (!__all(ok)) {
                #pragma unroll
                for (int rr = 0; rr < 4; ++rr) {
                    float mm = vx[rr];
                    #pragma unroll
                    for (int off = 8; off; off >>= 1) mm = fmaxf(mm, __shfl_xor(mm, off));
                    float mn = fmaxf(mA[rr], mm);
                    float corr = exp2f(mA[rr] - mn);
                    mA[rr] = mn;
                    lpA[rr] *= corr;
                    #pragma unroll
                    for (int dt = 0; dt < 4; ++dt) accA[dt][rr] *= corr;
                }
            }
            #pragma unroll
            for (int rr = 0; rr < 4; ++rr) {
                float p0 = exp2f(svA[0][rr] - mA[rr]);
                float p1 = exp2f(svA[1][rr] - mA[rr]);
                float p2 = exp2f(svA[2][rr] - mA[rr]);
                float p3 = exp2f(svA[3][rr] - mA[rr]);
                lpA[rr] += (p0 + p1) + (p2 + p3);
                unsigned pk01, pk23;
                asm("v_cvt_pk_bf16_f32 %0, %1, %2" : "=v"(pk01) : "v"(p0), "v"(p1));
                asm("v_cvt_pk_bf16_f32 %0, %1, %2" : "=v"(pk23) : "v"(p2), "v"(p3));
                int row = lg * 4 + rr, r7 = row & 7;
                Pw32[row * 32 + (((lr >> 2) ^ r7) << 2) + (lr & 3)] = pk01;
                Pw32[row * 32 + ((((lr >> 2) + 4) ^ r7) << 2) + (lr & 3)] = pk23;
            }
            paA0 = *reinterpret_cast<const bf16x8*>(&Psw[lr * 64 + ((lg ^ lr7) << 3)]);
            paA1 = *reinterpret_cast<const bf16x8*>(&Psw[lr * 64 + (((4 | lg) ^ lr7) << 3)]);
        }

        {
            float vx[4]; int ok = 1;
            #pragma unroll
            for (int rr = 0; rr < 4; ++rr) {
                vx[rr] = fmaxf(fmaxf(svB[0][rr], svB[1][rr]), fmaxf(svB[2][rr], svB[3][rr]));
                ok &= (vx[rr] <= mB[rr] + 8.0f);
            }
            if (!__all(ok)) {
                #pragma unroll
                for (int rr = 0; rr < 4; ++rr) {
                    float mm = vx[rr];
                    #pragma unroll
                    for (int off = 8; off; off >>= 1) mm = fmaxf(mm, __shfl_xor(mm, off));
                    float mn = fmaxf(mB[rr], mm);
                    float corr = exp2f(mB[rr] - mn);
                    mB[rr] = mn;
                    lpB[rr] *= corr;
                    #pragma unroll
                    for (int dt = 0; dt < 4; ++dt) accB[dt][rr] *= corr;
                }
            }
            #pragma unroll
            for (int rr = 0; rr < 4; ++rr) {
                float p0 = exp2f(svB[0][rr] - mB[rr]);
                float p1 = exp2f(svB[1][rr] - mB[rr]);
                float p2 = exp2f(svB[2][rr] - mB[rr]);
                float p3 = exp2f(svB[3][rr] - mB[rr]);
                lpB[rr] += (p0 + p1) + (p2 + p3);
                unsigned pk01, pk23;
                asm("v_cvt_pk_bf16_f32 %0, %1, %2" : "=v"(pk01) : "v"(p0), "v"(p1));
                asm("v_cvt_pk_bf16_f32 %0, %1, %2" : "=v"(pk23) : "v"(p2), "v"(p3));
                int row = lg * 4 + rr, r7 = row & 7;
                Pw32[row * 32 + (((lr >> 2) ^ r7) << 2) + (lr & 3)] = pk01;
                Pw32[row * 32 + ((((lr >> 2) + 4) ^ r7) << 2) + (lr & 3)] = pk23;
            }
            paB0 = *reinterpret_cast<const bf16x8*>(&Psw[lr * 64 + ((lg ^ lr7) << 3)]);
            paB1 = *reinterpret_cast<const bf16x8*>(&Psw[lr * 64 + (((4 | lg) ^ lr7) << 3)]);
        }

        __builtin_amdgcn_s_setprio(1);
        #pragma unroll
        for (int dt = 0; dt < 4; ++dt) {
            int r = dt * 16 + lr;
            bf16x8 vf0 = *reinterpret_cast<const bf16x8*>(&Vl[r * 64 + ((lg ^ lr7) << 3)]);
            bf16x8 vf1 = *reinterpret_cast<const bf16x8*>(&Vl[r * 64 + (((4 | lg) ^ lr7) << 3)]);
            if (doA) {
                accA[dt] = __builtin_amdgcn_mfma_f32_16x16x32_bf16(paA0, vf0, accA[dt], 0, 0, 0);
                accA[dt] = __builtin_amdgcn_mfma_f32_16x16x32_bf16(paA1, vf1, accA[dt], 0, 0, 0);
            }
            accB[dt] = __builtin_amdgcn_mfma_f32_16x16x32_bf16(paB0, vf0, accB[dt], 0, 0, 0);
            accB[dt] = __builtin_amdgcn_mfma_f32_16x16x32_bf16(paB1, vf1, accB[dt], 0, 0, 0);
        }
        __builtin_amdgcn_s_setprio(0);

        asm volatile("s_waitcnt vmcnt(0)" ::: "memory");
        __syncthreads();
        cur ^= 1;
    }
    #undef STAGE

    #pragma unroll
    for (int rr = 0; rr < 4; ++rr) {
        #pragma unroll
        for (int off = 8; off; off >>= 1) {
            lpA[rr] += __shfl_xor(lpA[rr], off);
            lpB[rr] += __shfl_xor(lpB[rr], off);
        }
    }

    #pragma unroll
    for (int rr = 0; rr < 4; ++rr) {
        float invA = 1.0f / lpA[rr];
        float invB = 1.0f / lpB[rr];
        size_t baseA = ((size_t)(b * 1024 + q0a + lg * 4 + rr)) * 1024 + h * 64;
        size_t baseB = ((size_t)(b * 1024 + q0b + lg * 4 + rr)) * 1024 + h * 64;
        #pragma unroll
        for (int dt = 0; dt < 4; ++dt) {
            Y[baseA + dt * 16 + lr] = f2bf(accA[dt][rr] * invA);
            Y[baseB + dt * 16 + lr] = f2bf(accB[dt][rr] * invB);
        }
    }
}

extern "C" void kernel_launch(void* const* d_in, const int* in_sizes, int n_in,
                              void* d_out, int out_size, void* d_ws, size_t ws_size,
                              hipStream_t stream) {
    (void)in_sizes; (void)n_in; (void)out_size; (void)ws_size;
    const float* x  = (const float*)d_in[0];
    const float* Wq = (const float*)d_in[1];
    const float* Wk = (const float*)d_in[2];
    const float* Wv = (const float*)d_in[3];
    const float* Wp = (const float*)d_in[4];
    const float* qg = (const float*)d_in[5];
    float* out = (float*)d_out;

    float* p = (float*)d_ws;
    float* partial = p; p += 256;
    float* alpha = p;   p += 16;
    s8* wtqkv = (s8*)p; p += 393216;     // 1536x1024 i8
    s8* wtp   = (s8*)p; p += 262144;     // 1024x1024 i8
    s8* xq    = (s8*)p; p += 2097152;    // 8192x1024 i8
    float* gam = p; p += 8192;
    u16* y16   = (u16*)p; p += 4194304;  // bf16 [8192][1024] attn output
    u16* qo = (u16*)p; p += 4194304;     // bf16 [b,16,1024,64]
    u16* ko = (u16*)p; p += 1048576;     // bf16 [b,4,1024,64]
    u16* vt = (u16*)p; p += 1048576;     // bf16 [b,4,64,pos]
    float* rc = p; p += 32768;
    float* rs = p; p += 32768;
    s8* yq = xq;   // reuse (xq dead after qkv gemm)

    // fused: weight abs-mean + x quantization (one dispatch)
    k_prep1<<<2304, 256, 0, stream>>>(Wq, Wk, Wv, Wp, partial, x, xq, gam);
    k_rope_alpha<<<128, 256, 0, stream>>>(rc, rs, partial, alpha);
    k_tern_all<<<2560, 256, 0, stream>>>(Wq, Wk, Wv, Wp, alpha, wtqkv, wtp);

    // fused i8 QKV projection (+norm/rope + V transpose)
    k_gemm_qkv<<<dim3(12, 64), 256, 0, stream>>>(xq, wtqkv, gam, alpha, rc, rs, qg, qo, ko, vt);

    // attention (packed P via LDS, paired causal tiles, setprio, XCD-swizzled, bf16 out)
    k_attn_mfma<<<dim3(8, 16, 8), 256, 0, stream>>>(qo, ko, vt, y16);

    // output projection (i8)
    k_quant_bf16<<<2048, 256, 0, stream>>>(y16, yq, gam);
    k_gemm_out<<<dim3(8, 64), 256, 0, stream>>>(yq, wtp, gam, alpha, out);
}

// Round 17
// 146.440 us; speedup vs baseline: 1.8232x; 1.0324x over previous
//
#include <hip/hip_runtime.h>
#include <cmath>

#define DIMM 1024
#define NHEADS 16
#define NKV 4
#define HD 64
#define SEQ 1024
#define BSZ 8
#define ROWS (BSZ * SEQ)   // 8192

typedef unsigned short u16;
typedef signed char s8;
typedef __attribute__((ext_vector_type(8))) short bf16x8;
typedef __attribute__((ext_vector_type(8))) unsigned short u16x8;
typedef __attribute__((ext_vector_type(4))) float f32x4;
typedef __attribute__((ext_vector_type(4))) int i32x4;
typedef __attribute__((ext_vector_type(4))) unsigned short u16x4;
typedef __attribute__((ext_vector_type(4))) unsigned int u32x4;

static __device__ __forceinline__ u16 f2bf(float f) {
    union { float f; unsigned u; } v; v.f = f;
    unsigned r = v.u + 0x7FFFu + ((v.u >> 16) & 1u);
    return (u16)(r >> 16);
}
static __device__ __forceinline__ float bf2f(u16 h) {
    union { unsigned u; float f; } v; v.u = ((unsigned)h) << 16;
    return v.f;
}

// async global->LDS, 16B per lane; dst must be wave-uniform base (HW adds lane*16)
static __device__ __forceinline__ void gload16(const void* g, void* l) {
    __builtin_amdgcn_global_load_lds(
        (const __attribute__((address_space(1))) unsigned int*)g,
        (__attribute__((address_space(3))) unsigned int*)l, 16, 0, 0);
}

static __device__ __forceinline__ unsigned packdiv4(float a, float b, float c, float d, float gamma) {
    int q0 = (int)rintf(fminf(fmaxf(a / gamma, -128.f), 127.f));
    int q1 = (int)rintf(fminf(fmaxf(b / gamma, -128.f), 127.f));
    int q2 = (int)rintf(fminf(fmaxf(c / gamma, -128.f), 127.f));
    int q3 = (int)rintf(fminf(fmaxf(d / gamma, -128.f), 127.f));
    return (q0 & 0xff) | ((q1 & 0xff) << 8) | ((q2 & 0xff) << 16) | ((q3 & 0xff) << 24);
}

// alpha_i = max(mean|W_i|, eps) from the 64 partial sums (same order as original reduce)
static __device__ __forceinline__ float alpha_from_partial(const float* partial, int wi) {
    const float* pp = partial + wi * 64;
    float su = 0.f;
    for (int j = 0; j < 64; ++j) su += pp[j];
    float n = (wi == 0 || wi == 3) ? 1048576.f : 262144.f;
    return fmaxf(su / n, 1e-8f);
}

// -------- fused: weight abs-mean (0..255) + x quant (256..2303) + rope table (2304..2431) --------
__global__ __launch_bounds__(256) void k_prep1(const float* __restrict__ Wq,
                                               const float* __restrict__ Wk,
                                               const float* __restrict__ Wv,
                                               const float* __restrict__ Wp,
                                               float* __restrict__ partial,
                                               const float* __restrict__ X,
                                               s8* __restrict__ Xq, float* __restrict__ g,
                                               float* __restrict__ rc, float* __restrict__ rs) {
    if (blockIdx.x < 256) {
        int wi = blockIdx.x >> 6, local = blockIdx.x & 63;
        const float* w = (wi == 0) ? Wq : (wi == 1) ? Wk : (wi == 2) ? Wv : Wp;
        int n = (wi == 0 || wi == 3) ? 1048576 : 262144;
        float s = 0.f;
        for (int i = local * 256 + threadIdx.x; i < n; i += 64 * 256) s += fabsf(w[i]);
        #pragma unroll
        for (int off = 32; off; off >>= 1) s += __shfl_xor(s, off);
        __shared__ float red[4];
        if ((threadIdx.x & 63) == 0) red[threadIdx.x >> 6] = s;
        __syncthreads();
        if (threadIdx.x == 0) partial[blockIdx.x] = red[0] + red[1] + red[2] + red[3];
    } else if (blockIdx.x < 2304) {
        int row = (blockIdx.x - 256) * 4 + (threadIdx.x >> 6);
        int lane = threadIdx.x & 63;
        const float* xr = X + (size_t)row * DIMM + lane * 16;
        float4 v0 = *reinterpret_cast<const float4*>(xr + 0);
        float4 v1 = *reinterpret_cast<const float4*>(xr + 4);
        float4 v2 = *reinterpret_cast<const float4*>(xr + 8);
        float4 v3 = *reinterpret_cast<const float4*>(xr + 12);
        float mv = fmaxf(fmaxf(fmaxf(fabsf(v0.x), fabsf(v0.y)), fmaxf(fabsf(v0.z), fabsf(v0.w))),
                         fmaxf(fmaxf(fabsf(v1.x), fabsf(v1.y)), fmaxf(fabsf(v1.z), fabsf(v1.w))));
        mv = fmaxf(mv, fmaxf(fmaxf(fabsf(v2.x), fabsf(v2.y)), fmaxf(fabsf(v2.z), fabsf(v2.w))));
        mv = fmaxf(mv, fmaxf(fmaxf(fabsf(v3.x), fabsf(v3.y)), fmaxf(fabsf(v3.z), fabsf(v3.w))));
        #pragma unroll
        for (int off = 32; off; off >>= 1) mv = fmaxf(mv, __shfl_xor(mv, off));
        float gamma = fmaxf(mv, 1e-8f) / 127.0f;
        u32x4 st;
        st.x = packdiv4(v0.x, v0.y, v0.z, v0.w, gamma);
        st.y = packdiv4(v1.x, v1.y, v1.z, v1.w, gamma);
        st.z = packdiv4(v2.x, v2.y, v2.z, v2.w, gamma);
        st.w = packdiv4(v3.x, v3.y, v3.z, v3.w, gamma);
        *reinterpret_cast<u32x4*>(Xq + (size_t)row * DIMM + lane * 16) = st;
        if (lane == 0) g[row] = gamma;
    } else {
        int idx = (blockIdx.x - 2304) * 256 + threadIdx.x;  // < 32768
        int t = idx >> 5, i = idx & 31;
        float inv = 1.0f / powf(10000.0f, (float)(2 * i) * (1.0f / 64.0f));
        float f = (float)t * inv;
        rc[idx] = cosf(f);
        rs[idx] = sinf(f);
    }
}

// ---------------- fused ternarize -> i8 {-1,0,1}, one dispatch (alpha inline) ----------------
__global__ __launch_bounds__(256) void k_tern_all(const float* __restrict__ Wq,
                                                  const float* __restrict__ Wk,
                                                  const float* __restrict__ Wv,
                                                  const float* __restrict__ Wp,
                                                  const float* __restrict__ partial,
                                                  s8* __restrict__ wtqkv,
                                                  s8* __restrict__ wtp) {
    int idx = blockIdx.x * 256 + threadIdx.x;   // < 655360 (weight boundaries block-aligned)
    const float* src; s8* dst; int wi;
    if (idx < 262144)      { src = Wq + (size_t)idx * 4;            dst = wtqkv + (size_t)idx * 4;                 wi = 0; }
    else if (idx < 327680) { src = Wk + (size_t)(idx - 262144) * 4; dst = wtqkv + 1048576 + (size_t)(idx - 262144) * 4; wi = 1; }
    else if (idx < 393216) { src = Wv + (size_t)(idx - 327680) * 4; dst = wtqkv + 1310720 + (size_t)(idx - 327680) * 4; wi = 2; }
    else                   { src = Wp + (size_t)(idx - 393216) * 4; dst = wtp + (size_t)(idx - 393216) * 4;        wi = 3; }
    float a = alpha_from_partial(partial, wi);
    float4 v = *reinterpret_cast<const float4*>(src);
    int q0 = (int)rintf(fminf(fmaxf(v.x / a, -1.f), 1.f));
    int q1 = (int)rintf(fminf(fmaxf(v.y / a, -1.f), 1.f));
    int q2 = (int)rintf(fminf(fmaxf(v.z / a, -1.f), 1.f));
    int q3 = (int)rintf(fminf(fmaxf(v.w / a, -1.f), 1.f));
    *reinterpret_cast<unsigned*>(dst) =
        (q0 & 0xff) | ((q1 & 0xff) << 8) | ((q2 & 0xff) << 16) | ((q3 & 0xff) << 24);
}

// ---------------- per-row activation quantization (bf16 input, wave-per-row) -> i8 ----------------
__global__ __launch_bounds__(256) void k_quant_bf16(const u16* __restrict__ X,
                                                    s8* __restrict__ Xq, float* __restrict__ g) {
    int row = blockIdx.x * 4 + (threadIdx.x >> 6);
    int lane = threadIdx.x & 63;
    const u16* xr = X + (size_t)row * DIMM + lane * 16;
    u16x8 h0 = *reinterpret_cast<const u16x8*>(xr);
    u16x8 h1 = *reinterpret_cast<const u16x8*>(xr + 8);
    float v[16];
    #pragma unroll
    for (int j = 0; j < 8; ++j) { v[j] = bf2f(h0[j]); v[8 + j] = bf2f(h1[j]); }
    float mv = 0.f;
    #pragma unroll
    for (int j = 0; j < 16; ++j) mv = fmaxf(mv, fabsf(v[j]));
    #pragma unroll
    for (int off = 32; off; off >>= 1) mv = fmaxf(mv, __shfl_xor(mv, off));
    float gamma = fmaxf(mv, 1e-8f) / 127.0f;
    u32x4 st;
    st.x = packdiv4(v[0], v[1], v[2], v[3], gamma);
    st.y = packdiv4(v[4], v[5], v[6], v[7], gamma);
    st.z = packdiv4(v[8], v[9], v[10], v[11], gamma);
    st.w = packdiv4(v[12], v[13], v[14], v[15], gamma);
    *reinterpret_cast<u32x4*>(Xq + (size_t)row * DIMM + lane * 16) = st;
    if (lane == 0) g[row] = gamma;
}

// ---------------- i8 QKV GEMM: fused rms_norm+rope epilogue + fused V transpose ----------------
__global__ __launch_bounds__(256) void k_gemm_qkv(const s8* __restrict__ A,
                                                  const s8* __restrict__ B,
                                                  const float* __restrict__ gamma,
                                                  const float* __restrict__ partial,
                                                  const float* __restrict__ rc,
                                                  const float* __restrict__ rs,
                                                  const float* __restrict__ gain,
                                                  u16* __restrict__ Qo,
                                                  u16* __restrict__ Ko,
                                                  u16* __restrict__ Vt) {
    __shared__ __align__(16) s8 SMEM[32768];
    s8* As = SMEM;
    s8* Bs = SMEM + 16384;
    const int K = DIMM;
    int tid = threadIdx.x;
    int w = tid >> 6, lane = tid & 63;
    int lr = lane & 15, lg = lane >> 4;
    int lr7 = lr & 7;
    int wm = w >> 1, wn = w & 1;
    int orig = blockIdx.x + 12 * blockIdx.y;
    int wgid = (orig & 7) * 96 + (orig >> 3);
    int bx = wgid % 12, by = wgid / 12;
    int row0 = by * 128, col0 = bx * 128;

    i32x4 acc[4][4];
    #pragma unroll
    for (int mf = 0; mf < 4; ++mf)
        #pragma unroll
        for (int nf = 0; nf < 4; ++nf) acc[mf][nf] = (i32x4){0, 0, 0, 0};

    int srow = w * 32 + (lane >> 3);
    int scol = 16 * ((lane & 7) ^ (lane >> 3));
    const s8* Ag = A + (size_t)(row0 + srow) * K + scol;
    const s8* Bg = B + (size_t)(col0 + srow) * K + scol;

    for (int k0 = 0; k0 < K; k0 += 128) {
        #pragma unroll
        for (int i = 0; i < 4; ++i) {
            gload16(Ag + (size_t)i * 8 * K + k0, &As[w * 4096 + i * 1024]);
            gload16(Bg + (size_t)i * 8 * K + k0, &Bs[w * 4096 + i * 1024]);
        }
        __syncthreads();
        #pragma unroll
        for (int kh = 0; kh < 2; ++kh) {
            i32x4 af[4], bfr[4];
            #pragma unroll
            for (int mf = 0; mf < 4; ++mf)
                af[mf] = *reinterpret_cast<const i32x4*>(
                    &As[(wm * 64 + mf * 16 + lr) * 128 + 16 * (((kh << 2) + lg) ^ lr7)]);
            #pragma unroll
            for (int nf = 0; nf < 4; ++nf)
                bfr[nf] = *reinterpret_cast<const i32x4*>(
                    &Bs[(wn * 64 + nf * 16 + lr) * 128 + 16 * (((kh << 2) + lg) ^ lr7)]);
            #pragma unroll
            for (int mf = 0; mf < 4; ++mf)
                #pragma unroll
                for (int nf = 0; nf < 4; ++nf)
                    acc[mf][nf] = __builtin_amdgcn_mfma_i32_16x16x64_i8(af[mf], bfr[nf], acc[mf][nf], 0, 0, 0);
        }
        __syncthreads();
    }

    int c0 = col0 + wn * 64;
    int hh = c0 >> 6;   // 0..15 Q heads, 16..19 K heads, 20..23 V heads
    float alpha = alpha_from_partial(partial, hh < 16 ? 0 : (hh < 20 ? 1 : 2));

    if (hh < 20) {
        float ga = (hh < 16) ? gain[hh] * (0.125f * 1.4426950408889634f) : 1.0f;
        #pragma unroll
        for (int mf = 0; mf < 4; ++mf) {
            #pragma unroll
            for (int reg = 0; reg < 4; ++reg) {
                int row = row0 + wm * 64 + mf * 16 + lg * 4 + reg;
                float sc = gamma[row] * alpha;
                float v0 = (float)acc[mf][0][reg] * sc;
                float v1 = (float)acc[mf][1][reg] * sc;
                float v2 = (float)acc[mf][2][reg] * sc;
                float v3 = (float)acc[mf][3][reg] * sc;
                int s = row & 1023, b = row >> 10;
                float ss = v0 * v0 + v1 * v1 + v2 * v2 + v3 * v3;
                #pragma unroll
                for (int off = 8; off; off >>= 1) ss += __shfl_xor(ss, off);
                float rn = 1.0f / sqrtf(ss * (1.0f / 64.0f) + 1.1920929e-07f);
                v0 *= rn; v1 *= rn; v2 *= rn; v3 *= rn;
                float cA = rc[s * 32 + lr],      sA = rs[s * 32 + lr];
                float cB = rc[s * 32 + 16 + lr], sB = rs[s * 32 + 16 + lr];
                float y0 = v0 * cA + v2 * sA, y2 = v2 * cA - v0 * sA;
                float y1 = v1 * cB + v3 * sB, y3 = v3 * cB - v1 * sB;
                u16* dst;
                if (hh < 16) {
                    y0 *= ga; y1 *= ga; y2 *= ga; y3 *= ga;
                    dst = Qo + ((size_t)((b * 16 + hh) * 1024 + s)) * 64;
                } else {
                    dst = Ko + ((size_t)((b * 4 + (hh - 16)) * 1024 + s)) * 64;
                }
                dst[lr] = f2bf(y0); dst[16 + lr] = f2bf(y1);
                dst[32 + lr] = f2bf(y2); dst[48 + lr] = f2bf(y3);
            }
        }
    } else {
        int kv = hh - 20;
        u16* T = reinterpret_cast<u16*>(SMEM) + w * 4096;
        #pragma unroll
        for (int mf = 0; mf < 4; ++mf) {
            int pb = (mf & 1) + 32 * (mf >> 1);
            #pragma unroll
            for (int reg = 0; reg < 4; ++reg) {
                int row = row0 + wm * 64 + mf * 16 + lg * 4 + reg;
                float sc = gamma[row] * alpha;
                int pos = 2 * (lg * 4 + reg) + pb;
                #pragma unroll
                for (int nf = 0; nf < 4; ++nf) {
                    int d = nf * 16 + lr;
                    T[d * 64 + (pos ^ (lr7 << 3))] = f2bf((float)acc[mf][nf][reg] * sc);
                }
            }
        }
        int b = row0 >> 10;
        int st = ((row0 & 1023) + wm * 64) >> 6;
        int d = lane, h3 = lane & 7;
        u16* dst = Vt + (((size_t)(b * 4 + kv) * 64) + d) * 1024 + st * 64;
        #pragma unroll
        for (int j = 0; j < 8; ++j) {
            u16x8 gv = *reinterpret_cast<const u16x8*>(&T[d * 64 + 8 * (j ^ h3)]);
            *reinterpret_cast<u16x8*>(&dst[8 * j]) = gv;
        }
    }
}

// ---------------- i8 GEMM for output projection (XCD-swizzled, alpha inline) ----------------
__global__ __launch_bounds__(256) void k_gemm_out(const s8* __restrict__ A,
                                                  const s8* __restrict__ B,
                                                  const float* __restrict__ gamma,
                                                  const float* __restrict__ partial,
                                                  float* __restrict__ C) {
    __shared__ s8 As[128 * 128];
    __shared__ s8 Bs[128 * 128];
    const int K = DIMM;
    int tid = threadIdx.x;
    int w = tid >> 6, lane = tid & 63;
    int lr = lane & 15, lg = lane >> 4;
    int lr7 = lr & 7;
    int wm = w >> 1, wn = w & 1;
    int orig = blockIdx.x + 8 * blockIdx.y;
    int wgid = ((orig & 7) << 6) + (orig >> 3);
    int row0 = (wgid >> 3) * 128, col0 = (wgid & 7) * 128;

    i32x4 acc[4][4];
    #pragma unroll
    for (int mf = 0; mf < 4; ++mf)
        #pragma unroll
        for (int nf = 0; nf < 4; ++nf) acc[mf][nf] = (i32x4){0, 0, 0, 0};

    int srow = w * 32 + (lane >> 3);
    int scol = 16 * ((lane & 7) ^ (lane >> 3));
    const s8* Ag = A + (size_t)(row0 + srow) * K + scol;
    const s8* Bg = B + (size_t)(col0 + srow) * K + scol;

    for (int k0 = 0; k0 < K; k0 += 128) {
        #pragma unroll
        for (int i = 0; i < 4; ++i) {
            gload16(Ag + (size_t)i * 8 * K + k0, &As[w * 4096 + i * 1024]);
            gload16(Bg + (size_t)i * 8 * K + k0, &Bs[w * 4096 + i * 1024]);
        }
        __syncthreads();
        #pragma unroll
        for (int kh = 0; kh < 2; ++kh) {
            i32x4 af[4], bfr[4];
            #pragma unroll
            for (int mf = 0; mf < 4; ++mf)
                af[mf] = *reinterpret_cast<const i32x4*>(
                    &As[(wm * 64 + mf * 16 + lr) * 128 + 16 * (((kh << 2) + lg) ^ lr7)]);
            #pragma unroll
            for (int nf = 0; nf < 4; ++nf)
                bfr[nf] = *reinterpret_cast<const i32x4*>(
                    &Bs[(wn * 64 + nf * 16 + lr) * 128 + 16 * (((kh << 2) + lg) ^ lr7)]);
            #pragma unroll
            for (int mf = 0; mf < 4; ++mf)
                #pragma unroll
                for (int nf = 0; nf < 4; ++nf)
                    acc[mf][nf] = __builtin_amdgcn_mfma_i32_16x16x64_i8(af[mf], bfr[nf], acc[mf][nf], 0, 0, 0);
        }
        __syncthreads();
    }

    float alpha = alpha_from_partial(partial, 3);
    #pragma unroll
    for (int mf = 0; mf < 4; ++mf) {
        #pragma unroll
        for (int reg = 0; reg < 4; ++reg) {
            int row = row0 + wm * 64 + mf * 16 + lg * 4 + reg;
            float sc = gamma[row] * alpha;
            #pragma unroll
            for (int nf = 0; nf < 4; ++nf)
                C[(size_t)row * 1024 + col0 + wn * 64 + nf * 16 + lr] = (float)acc[mf][nf][reg] * sc;
        }
    }
}

// ---------------- causal flash attention, bf16 MFMA, paired q-tiles ----------------
// Proven structure (libm exp2f / plain division — amdgcn exp2/rcp intrinsics BROKEN here).
__global__ __launch_bounds__(256) void k_attn_mfma(const u16* __restrict__ Q,
                                                   const u16* __restrict__ K,
                                                   const u16* __restrict__ Vt,
                                                   u16* __restrict__ Y) {
    __shared__ __align__(16) u16 KVs[2][2][4096];   // [buf][K/V][64*64], swizzled
    __shared__ __align__(16) u16 Ps[4][1024];       // per-wave P strip [16 q][64 pos], swizzled
    int orig = blockIdx.x + ((blockIdx.y + (blockIdx.z << 4)) << 3);
    int wgid = ((orig & 7) << 7) + (orig >> 3);
    int qta = wgid & 7, qtb = 15 - qta;
    int h = (wgid >> 3) & 15, b = wgid >> 7;
    int kvh = h >> 2;
    int tid = threadIdx.x;
    int w = tid >> 6, lane = tid & 63;
    int lr = lane & 15, lg = lane >> 4;
    int lr7 = lr & 7;
    int q0a = qta * 64 + w * 16, q0b = qtb * 64 + w * 16;
    const u16* Qb = Q + (((size_t)b * 16 + h) * 1024) * 64;
    const u16* Kb = K + (((size_t)b * 4 + kvh) * 1024) * 64;
    const u16* Vb = Vt + (((size_t)b * 4 + kvh) * 64) * 1024;
    u16* Psw = Ps[w];
    unsigned* Pw32 = reinterpret_cast<unsigned*>(Psw);

    bf16x8 qa0 = *reinterpret_cast<const bf16x8*>(&Qb[(size_t)(q0a + lr) * 64 + 8 * lg]);
    bf16x8 qa1 = *reinterpret_cast<const bf16x8*>(&Qb[(size_t)(q0a + lr) * 64 + 32 + 8 * lg]);
    bf16x8 qb0 = *reinterpret_cast<const bf16x8*>(&Qb[(size_t)(q0b + lr) * 64 + 8 * lg]);
    bf16x8 qb1 = *reinterpret_cast<const bf16x8*>(&Qb[(size_t)(q0b + lr) * 64 + 32 + 8 * lg]);

    float mA[4], lpA[4], mB[4], lpB[4];
    f32x4 accA[4], accB[4];
    #pragma unroll
    for (int r = 0; r < 4; ++r) { mA[r] = -INFINITY; lpA[r] = 0.f; mB[r] = -INFINITY; lpB[r] = 0.f; }
    #pragma unroll
    for (int dt = 0; dt < 4; ++dt) { accA[dt] = (f32x4){0.f,0.f,0.f,0.f}; accB[dt] = (f32x4){0.f,0.f,0.f,0.f}; }

    int sub = lane >> 3, s7 = lane & 7;
    int scol16 = s7 ^ sub;
    int c0 = 2 * w, c1 = 2 * w + 1;

    #define STAGE(buf, t_) do { \
        int kk0 = (t_) * 64; \
        gload16(Kb + (size_t)(kk0 + 8 * c0 + sub) * 64 + scol16 * 8, &KVs[buf][0][c0 * 512]); \
        gload16(Kb + (size_t)(kk0 + 8 * c1 + sub) * 64 + scol16 * 8, &KVs[buf][0][c1 * 512]); \
        gload16(Vb + (size_t)(8 * c0 + sub) * 1024 + kk0 + scol16 * 8, &KVs[buf][1][c0 * 512]); \
        gload16(Vb + (size_t)(8 * c1 + sub) * 1024 + kk0 + scol16 * 8, &KVs[buf][1][c1 * 512]); \
    } while (0)

    STAGE(0, 0);
    asm volatile("s_waitcnt vmcnt(0)" ::: "memory");
    __syncthreads();
    int cur = 0;

    for (int t = 0; t <= qtb; ++t) {
        if (t < qtb) STAGE(cur ^ 1, t + 1);
        const int k0 = t * 64;
        const bool doA = (t <= qta);
        const u16* Kl = KVs[cur][0];
        const u16* Vl = KVs[cur][1];

        float svA[4][4], svB[4][4];
        __builtin_amdgcn_s_setprio(1);
        #pragma unroll
        for (int t4 = 0; t4 < 4; ++t4) {
            int r = t4 * 16 + lr;
            bf16x8 kf0 = *reinterpret_cast<const bf16x8*>(&Kl[r * 64 + ((lg ^ lr7) << 3)]);
            bf16x8 kf1 = *reinterpret_cast<const bf16x8*>(&Kl[r * 64 + (((4 | lg) ^ lr7) << 3)]);
            if (doA) {
                f32x4 z = (f32x4){0.f,0.f,0.f,0.f};
                z = __builtin_amdgcn_mfma_f32_16x16x32_bf16(qa0, kf0, z, 0, 0, 0);
                z = __builtin_amdgcn_mfma_f32_16x16x32_bf16(qa1, kf1, z, 0, 0, 0);
                #pragma unroll
                for (int rr = 0; rr < 4; ++rr) svA[t4][rr] = z[rr];
            }
            f32x4 z2 = (f32x4){0.f,0.f,0.f,0.f};
            z2 = __builtin_amdgcn_mfma_f32_16x16x32_bf16(qb0, kf0, z2, 0, 0, 0);
            z2 = __builtin_amdgcn_mfma_f32_16x16x32_bf16(qb1, kf1, z2, 0, 0, 0);
            #pragma unroll
            for (int rr = 0; rr < 4; ++rr) svB[t4][rr] = z2[rr];
        }
        __builtin_amdgcn_s_setprio(0);
        if (doA && t == qta) {
            #pragma unroll
            for (int t4 = 0; t4 < 4; ++t4) {
                int key = k0 + t4 * 16 + lr;
                #pragma unroll
                for (int rr = 0; rr < 4; ++rr)
                    if (key > q0a + lg * 4 + rr) svA[t4][rr] = -3.0e38f;
            }
        }
        if (t == qtb) {
            #pragma unroll
            for (int t4 = 0; t4 < 4; ++t4) {
                int key = k0 + t4 * 16 + lr;
                #pragma unroll
                for (int rr = 0; rr < 4; ++rr)
                    if (key > q0b + lg * 4 + rr) svB[t4][rr] = -3.0e38f;
            }
        }

        bf16x8 paA0, paA1, paB0, paB1;
        if (doA) {
            float vx[4]; int ok = 1;
            #pragma unroll
            for (int rr = 0; rr < 4; ++rr) {
                vx[rr] = fmaxf(fmaxf(svA[0][rr], svA[1][rr]), fmaxf(svA[2][rr], svA[3][rr]));
                ok &= (vx[rr] <= mA[rr] + 8.0f);
            }
            if (!__all(ok)) {
                #pragma unroll
                for (int rr = 0; rr < 4; ++rr) {
                    float mm = vx[rr];
                    #pragma unroll
                    for (int off = 8; off; off >>= 1) mm = fmaxf(mm, __shfl_xor(mm, off));
                    float mn = fmaxf(mA[rr], mm);
                    float corr = exp2f(mA[rr] - mn);
                    mA[rr] = mn;
                    lpA[rr] *= corr;
                    #pragma unroll
                    for (int dt = 0; dt < 4; ++dt) accA[dt][rr] *= corr;
                }
            }
            #pragma unroll
            for (int rr = 0; rr < 4; ++rr) {
                float p0 = exp2f(svA[0][rr] - mA[rr]);
                float p1 = exp2f(svA[1][rr] - mA[rr]);
                float p2 = exp2f(svA[2][rr] - mA[rr]);
                float p3 = exp2f(svA[3][rr] - mA[rr]);
                lpA[rr] += (p0 + p1) + (p2 + p3);
                unsigned pk01, pk23;
                asm("v_cvt_pk_bf16_f32 %0, %1, %2" : "=v"(pk01) : "v"(p0), "v"(p1));
                asm("v_cvt_pk_bf16_f32 %0, %1, %2" : "=v"(pk23) : "v"(p2), "v"(p3));
                int row = lg * 4 + rr, r7 = row & 7;
                Pw32[row * 32 + (((lr >> 2) ^ r7) << 2) + (lr & 3)] = pk01;
                Pw32[row * 32 + ((((lr >> 2) + 4) ^ r7) << 2) + (lr & 3)] = pk23;
            }
            paA0 = *reinterpret_cast<const bf16x8*>(&Psw[lr * 64 + ((lg ^ lr7) << 3)]);
            paA1 = *reinterpret_cast<const bf16x8*>(&Psw[lr * 64 + (((4 | lg) ^ lr7) << 3)]);
        }

        {
            float vx[4]; int ok = 1;
            #pragma unroll
            for (int rr = 0; rr < 4; ++rr) {
                vx[rr] = fmaxf(fmaxf(svB[0][rr], svB[1][rr]), fmaxf(svB[2][rr], svB[3][rr]));
                ok &= (vx[rr] <= mB[rr] + 8.0f);
            }
            if (!__all(ok)) {
                #pragma unroll
                for (int rr = 0; rr < 4; ++rr) {
                    float mm = vx[rr];
                    #pragma unroll
                    for (int off = 8; off; off >>= 1) mm = fmaxf(mm, __shfl_xor(mm, off));
                    float mn = fmaxf(mB[rr], mm);
                    float corr = exp2f(mB[rr] - mn);
                    mB[rr] = mn;
                    lpB[rr] *= corr;
                    #pragma unroll
                    for (int dt = 0; dt < 4; ++dt) accB[dt][rr] *= corr;
                }
            }
            #pragma unroll
            for (int rr = 0; rr < 4; ++rr) {
                float p0 = exp2f(svB[0][rr] - mB[rr]);
                float p1 = exp2f(svB[1][rr] - mB[rr]);
                float p2 = exp2f(svB[2][rr] - mB[rr]);
                float p3 = exp2f(svB[3][rr] - mB[rr]);
                lpB[rr] += (p0 + p1) + (p2 + p3);
                unsigned pk01, pk23;
                asm("v_cvt_pk_bf16_f32 %0, %1, %2" : "=v"(pk01) : "v"(p0), "v"(p1));
                asm("v_cvt_pk_bf16_f32 %0, %1, %2" : "=v"(pk23) : "v"(p2), "v"(p3));
                int row = lg * 4 + rr, r7 = row & 7;
                Pw32[row * 32 + (((lr >> 2) ^ r7) << 2) + (lr & 3)] = pk01;
                Pw32[row * 32 + ((((lr >> 2) + 4) ^ r7) << 2) + (lr & 3)] = pk23;
            }
            paB0 = *reinterpret_cast<const bf16x8*>(&Psw[lr * 64 + ((lg ^ lr7) << 3)]);
            paB1 = *reinterpret_cast<const bf16x8*>(&Psw[lr * 64 + (((4 | lg) ^ lr7) << 3)]);
        }

        __builtin_amdgcn_s_setprio(1);
        #pragma unroll
        for (int dt = 0; dt < 4; ++dt) {
            int r = dt * 16 + lr;
            bf16x8 vf0 = *reinterpret_cast<const bf16x8*>(&Vl[r * 64 + ((lg ^ lr7) << 3)]);
            bf16x8 vf1 = *reinterpret_cast<const bf16x8*>(&Vl[r * 64 + (((4 | lg) ^ lr7) << 3)]);
            if (doA) {
                accA[dt] = __builtin_amdgcn_mfma_f32_16x16x32_bf16(paA0, vf0, accA[dt], 0, 0, 0);
                accA[dt] = __builtin_amdgcn_mfma_f32_16x16x32_bf16(paA1, vf1, accA[dt], 0, 0, 0);
            }
            accB[dt] = __builtin_amdgcn_mfma_f32_16x16x32_bf16(paB0, vf0, accB[dt], 0, 0, 0);
            accB[dt] = __builtin_amdgcn_mfma_f32_16x16x32_bf16(paB1, vf1, accB[dt], 0, 0, 0);
        }
        __builtin_amdgcn_s_setprio(0);

        asm volatile("s_waitcnt vmcnt(0)" ::: "memory");
        __syncthreads();
        cur ^= 1;
    }
    #undef STAGE

    #pragma unroll
    for (int rr = 0; rr < 4; ++rr) {
        #pragma unroll
        for (int off = 8; off; off >>= 1) {
            lpA[rr] += __shfl_xor(lpA[rr], off);
            lpB[rr] += __shfl_xor(lpB[rr], off);
        }
    }

    #pragma unroll
    for (int rr = 0; rr < 4; ++rr) {
        float invA = 1.0f / lpA[rr];
        float invB = 1.0f / lpB[rr];
        size_t baseA = ((size_t)(b * 1024 + q0a + lg * 4 + rr)) * 1024 + h * 64;
        size_t baseB = ((size_t)(b * 1024 + q0b + lg * 4 + rr)) * 1024 + h * 64;
        #pragma unroll
        for (int dt = 0; dt < 4; ++dt) {
            Y[baseA + dt * 16 + lr] = f2bf(accA[dt][rr] * invA);
            Y[baseB + dt * 16 + lr] = f2bf(accB[dt][rr] * invB);
        }
    }
}

extern "C" void kernel_launch(void* const* d_in, const int* in_sizes, int n_in,
                              void* d_out, int out_size, void* d_ws, size_t ws_size,
                              hipStream_t stream) {
    (void)in_sizes; (void)n_in; (void)out_size; (void)ws_size;
    const float* x  = (const float*)d_in[0];
    const float* Wq = (const float*)d_in[1];
    const float* Wk = (const float*)d_in[2];
    const float* Wv = (const float*)d_in[3];
    const float* Wp = (const float*)d_in[4];
    const float* qg = (const float*)d_in[5];
    float* out = (float*)d_out;

    float* p = (float*)d_ws;
    float* partial = p; p += 256;
    s8* wtqkv = (s8*)p; p += 393216;     // 1536x1024 i8
    s8* wtp   = (s8*)p; p += 262144;     // 1024x1024 i8
    s8* xq    = (s8*)p; p += 2097152;    // 8192x1024 i8
    float* gam = p; p += 8192;
    u16* y16   = (u16*)p; p += 4194304;  // bf16 [8192][1024] attn output
    u16* qo = (u16*)p; p += 4194304;     // bf16 [b,16,1024,64]
    u16* ko = (u16*)p; p += 1048576;     // bf16 [b,4,1024,64]
    u16* vt = (u16*)p; p += 1048576;     // bf16 [b,4,64,pos]
    float* rc = p; p += 32768;
    float* rs = p; p += 32768;
    s8* yq = xq;   // reuse (xq dead after qkv gemm)

    // fused: weight abs-mean + x quantization + rope table (one dispatch)
    k_prep1<<<2432, 256, 0, stream>>>(Wq, Wk, Wv, Wp, partial, x, xq, gam, rc, rs);
    // ternarize (alpha derived inline from partial)
    k_tern_all<<<2560, 256, 0, stream>>>(Wq, Wk, Wv, Wp, partial, wtqkv, wtp);

    // fused i8 QKV projection (+norm/rope + V transpose)
    k_gemm_qkv<<<dim3(12, 64), 256, 0, stream>>>(xq, wtqkv, gam, partial, rc, rs, qg, qo, ko, vt);

    // attention (packed P via LDS, paired causal tiles, setprio, XCD-swizzled, bf16 out)
    k_attn_mfma<<<dim3(8, 16, 8), 256, 0, stream>>>(qo, ko, vt, y16);

    // output projection (i8)
    k_quant_bf16<<<2048, 256, 0, stream>>>(y16, yq, gam);
    k_gemm_out<<<dim3(8, 64), 256, 0, stream>>>(yq, wtp, gam, partial, out);
}

// Round 18
// 143.201 us; speedup vs baseline: 1.8644x; 1.0226x over previous
//
#include <hip/hip_runtime.h>
#include <cmath>

#define DIMM 1024
#define NHEADS 16
#define NKV 4
#define HD 64
#define SEQ 1024
#define BSZ 8
#define ROWS (BSZ * SEQ)   // 8192

typedef unsigned short u16;
typedef signed char s8;
typedef __attribute__((ext_vector_type(8))) short bf16x8;
typedef __attribute__((ext_vector_type(8))) unsigned short u16x8;
typedef __attribute__((ext_vector_type(4))) float f32x4;
typedef __attribute__((ext_vector_type(4))) int i32x4;
typedef __attribute__((ext_vector_type(4))) unsigned short u16x4;
typedef __attribute__((ext_vector_type(4))) unsigned int u32x4;

static __device__ __forceinline__ u16 f2bf(float f) {
    union { float f; unsigned u; } v; v.f = f;
    unsigned r = v.u + 0x7FFFu + ((v.u >> 16) & 1u);
    return (u16)(r >> 16);
}
static __device__ __forceinline__ float bf2f(u16 h) {
    union { unsigned u; float f; } v; v.u = ((unsigned)h) << 16;
    return v.f;
}

// async global->LDS, 16B per lane; dst must be wave-uniform base (HW adds lane*16)
static __device__ __forceinline__ void gload16(const void* g, void* l) {
    __builtin_amdgcn_global_load_lds(
        (const __attribute__((address_space(1))) unsigned int*)g,
        (__attribute__((address_space(3))) unsigned int*)l, 16, 0, 0);
}

static __device__ __forceinline__ unsigned packdiv4(float a, float b, float c, float d, float gamma) {
    int q0 = (int)rintf(fminf(fmaxf(a / gamma, -128.f), 127.f));
    int q1 = (int)rintf(fminf(fmaxf(b / gamma, -128.f), 127.f));
    int q2 = (int)rintf(fminf(fmaxf(c / gamma, -128.f), 127.f));
    int q3 = (int)rintf(fminf(fmaxf(d / gamma, -128.f), 127.f));
    return (q0 & 0xff) | ((q1 & 0xff) << 8) | ((q2 & 0xff) << 16) | ((q3 & 0xff) << 24);
}

// alpha_i = max(mean|W_i|, eps) from the 64 partial sums (same order as original reduce)
static __device__ __forceinline__ float alpha_from_partial(const float* partial, int wi) {
    const float* pp = partial + wi * 64;
    float su = 0.f;
    for (int j = 0; j < 64; ++j) su += pp[j];
    float n = (wi == 0 || wi == 3) ? 1048576.f : 262144.f;
    return fmaxf(su / n, 1e-8f);
}

// -------- fused: weight abs-mean (0..255) + x quant (256..2303) + rope table (2304..2431) --------
__global__ __launch_bounds__(256) void k_prep1(const float* __restrict__ Wq,
                                               const float* __restrict__ Wk,
                                               const float* __restrict__ Wv,
                                               const float* __restrict__ Wp,
                                               float* __restrict__ partial,
                                               const float* __restrict__ X,
                                               s8* __restrict__ Xq, float* __restrict__ g,
                                               float* __restrict__ rc, float* __restrict__ rs) {
    if (blockIdx.x < 256) {
        int wi = blockIdx.x >> 6, local = blockIdx.x & 63;
        const float* w = (wi == 0) ? Wq : (wi == 1) ? Wk : (wi == 2) ? Wv : Wp;
        int n = (wi == 0 || wi == 3) ? 1048576 : 262144;
        float s = 0.f;
        for (int i = local * 256 + threadIdx.x; i < n; i += 64 * 256) s += fabsf(w[i]);
        #pragma unroll
        for (int off = 32; off; off >>= 1) s += __shfl_xor(s, off);
        __shared__ float red[4];
        if ((threadIdx.x & 63) == 0) red[threadIdx.x >> 6] = s;
        __syncthreads();
        if (threadIdx.x == 0) partial[blockIdx.x] = red[0] + red[1] + red[2] + red[3];
    } else if (blockIdx.x < 2304) {
        int row = (blockIdx.x - 256) * 4 + (threadIdx.x >> 6);
        int lane = threadIdx.x & 63;
        const float* xr = X + (size_t)row * DIMM + lane * 16;
        float4 v0 = *reinterpret_cast<const float4*>(xr + 0);
        float4 v1 = *reinterpret_cast<const float4*>(xr + 4);
        float4 v2 = *reinterpret_cast<const float4*>(xr + 8);
        float4 v3 = *reinterpret_cast<const float4*>(xr + 12);
        float mv = fmaxf(fmaxf(fmaxf(fabsf(v0.x), fabsf(v0.y)), fmaxf(fabsf(v0.z), fabsf(v0.w))),
                         fmaxf(fmaxf(fabsf(v1.x), fabsf(v1.y)), fmaxf(fabsf(v1.z), fabsf(v1.w))));
        mv = fmaxf(mv, fmaxf(fmaxf(fabsf(v2.x), fabsf(v2.y)), fmaxf(fabsf(v2.z), fabsf(v2.w))));
        mv = fmaxf(mv, fmaxf(fmaxf(fabsf(v3.x), fabsf(v3.y)), fmaxf(fabsf(v3.z), fabsf(v3.w))));
        #pragma unroll
        for (int off = 32; off; off >>= 1) mv = fmaxf(mv, __shfl_xor(mv, off));
        float gamma = fmaxf(mv, 1e-8f) / 127.0f;
        u32x4 st;
        st.x = packdiv4(v0.x, v0.y, v0.z, v0.w, gamma);
        st.y = packdiv4(v1.x, v1.y, v1.z, v1.w, gamma);
        st.z = packdiv4(v2.x, v2.y, v2.z, v2.w, gamma);
        st.w = packdiv4(v3.x, v3.y, v3.z, v3.w, gamma);
        *reinterpret_cast<u32x4*>(Xq + (size_t)row * DIMM + lane * 16) = st;
        if (lane == 0) g[row] = gamma;
    } else {
        int idx = (blockIdx.x - 2304) * 256 + threadIdx.x;  // < 32768
        int t = idx >> 5, i = idx & 31;
        float inv = 1.0f / powf(10000.0f, (float)(2 * i) * (1.0f / 64.0f));
        float f = (float)t * inv;
        rc[idx] = cosf(f);
        rs[idx] = sinf(f);
    }
}

// ---------------- fused ternarize -> i8 {-1,0,1}, one dispatch (alpha inline) ----------------
__global__ __launch_bounds__(256) void k_tern_all(const float* __restrict__ Wq,
                                                  const float* __restrict__ Wk,
                                                  const float* __restrict__ Wv,
                                                  const float* __restrict__ Wp,
                                                  const float* __restrict__ partial,
                                                  s8* __restrict__ wtqkv,
                                                  s8* __restrict__ wtp) {
    int idx = blockIdx.x * 256 + threadIdx.x;   // < 655360 (weight boundaries block-aligned)
    const float* src; s8* dst; int wi;
    if (idx < 262144)      { src = Wq + (size_t)idx * 4;            dst = wtqkv + (size_t)idx * 4;                 wi = 0; }
    else if (idx < 327680) { src = Wk + (size_t)(idx - 262144) * 4; dst = wtqkv + 1048576 + (size_t)(idx - 262144) * 4; wi = 1; }
    else if (idx < 393216) { src = Wv + (size_t)(idx - 327680) * 4; dst = wtqkv + 1310720 + (size_t)(idx - 327680) * 4; wi = 2; }
    else                   { src = Wp + (size_t)(idx - 393216) * 4; dst = wtp + (size_t)(idx - 393216) * 4;        wi = 3; }
    float a = alpha_from_partial(partial, wi);
    float4 v = *reinterpret_cast<const float4*>(src);
    int q0 = (int)rintf(fminf(fmaxf(v.x / a, -1.f), 1.f));
    int q1 = (int)rintf(fminf(fmaxf(v.y / a, -1.f), 1.f));
    int q2 = (int)rintf(fminf(fmaxf(v.z / a, -1.f), 1.f));
    int q3 = (int)rintf(fminf(fmaxf(v.w / a, -1.f), 1.f));
    *reinterpret_cast<unsigned*>(dst) =
        (q0 & 0xff) | ((q1 & 0xff) << 8) | ((q2 & 0xff) << 16) | ((q3 & 0xff) << 24);
}

// ---------------- per-row activation quantization (bf16 input, wave-per-row) -> i8 ----------------
__global__ __launch_bounds__(256) void k_quant_bf16(const u16* __restrict__ X,
                                                    s8* __restrict__ Xq, float* __restrict__ g) {
    int row = blockIdx.x * 4 + (threadIdx.x >> 6);
    int lane = threadIdx.x & 63;
    const u16* xr = X + (size_t)row * DIMM + lane * 16;
    u16x8 h0 = *reinterpret_cast<const u16x8*>(xr);
    u16x8 h1 = *reinterpret_cast<const u16x8*>(xr + 8);
    float v[16];
    #pragma unroll
    for (int j = 0; j < 8; ++j) { v[j] = bf2f(h0[j]); v[8 + j] = bf2f(h1[j]); }
    float mv = 0.f;
    #pragma unroll
    for (int j = 0; j < 16; ++j) mv = fmaxf(mv, fabsf(v[j]));
    #pragma unroll
    for (int off = 32; off; off >>= 1) mv = fmaxf(mv, __shfl_xor(mv, off));
    float gamma = fmaxf(mv, 1e-8f) / 127.0f;
    u32x4 st;
    st.x = packdiv4(v[0], v[1], v[2], v[3], gamma);
    st.y = packdiv4(v[4], v[5], v[6], v[7], gamma);
    st.z = packdiv4(v[8], v[9], v[10], v[11], gamma);
    st.w = packdiv4(v[12], v[13], v[14], v[15], gamma);
    *reinterpret_cast<u32x4*>(Xq + (size_t)row * DIMM + lane * 16) = st;
    if (lane == 0) g[row] = gamma;
}

// ---------------- i8 QKV GEMM: fused rms_norm+rope epilogue + fused V transpose ----------------
__global__ __launch_bounds__(256) void k_gemm_qkv(const s8* __restrict__ A,
                                                  const s8* __restrict__ B,
                                                  const float* __restrict__ gamma,
                                                  const float* __restrict__ partial,
                                                  const float* __restrict__ rc,
                                                  const float* __restrict__ rs,
                                                  const float* __restrict__ gain,
                                                  u16* __restrict__ Qo,
                                                  u16* __restrict__ Ko,
                                                  u16* __restrict__ Vt) {
    __shared__ __align__(16) s8 SMEM[32768];
    s8* As = SMEM;
    s8* Bs = SMEM + 16384;
    const int K = DIMM;
    int tid = threadIdx.x;
    int w = tid >> 6, lane = tid & 63;
    int lr = lane & 15, lg = lane >> 4;
    int lr7 = lr & 7;
    int wm = w >> 1, wn = w & 1;
    int orig = blockIdx.x + 12 * blockIdx.y;
    int wgid = (orig & 7) * 96 + (orig >> 3);
    int bx = wgid % 12, by = wgid / 12;
    int row0 = by * 128, col0 = bx * 128;

    i32x4 acc[4][4];
    #pragma unroll
    for (int mf = 0; mf < 4; ++mf)
        #pragma unroll
        for (int nf = 0; nf < 4; ++nf) acc[mf][nf] = (i32x4){0, 0, 0, 0};

    int srow = w * 32 + (lane >> 3);
    int scol = 16 * ((lane & 7) ^ (lane >> 3));
    const s8* Ag = A + (size_t)(row0 + srow) * K + scol;
    const s8* Bg = B + (size_t)(col0 + srow) * K + scol;

    for (int k0 = 0; k0 < K; k0 += 128) {
        #pragma unroll
        for (int i = 0; i < 4; ++i) {
            gload16(Ag + (size_t)i * 8 * K + k0, &As[w * 4096 + i * 1024]);
            gload16(Bg + (size_t)i * 8 * K + k0, &Bs[w * 4096 + i * 1024]);
        }
        __syncthreads();
        #pragma unroll
        for (int kh = 0; kh < 2; ++kh) {
            i32x4 af[4], bfr[4];
            #pragma unroll
            for (int mf = 0; mf < 4; ++mf)
                af[mf] = *reinterpret_cast<const i32x4*>(
                    &As[(wm * 64 + mf * 16 + lr) * 128 + 16 * (((kh << 2) + lg) ^ lr7)]);
            #pragma unroll
            for (int nf = 0; nf < 4; ++nf)
                bfr[nf] = *reinterpret_cast<const i32x4*>(
                    &Bs[(wn * 64 + nf * 16 + lr) * 128 + 16 * (((kh << 2) + lg) ^ lr7)]);
            #pragma unroll
            for (int mf = 0; mf < 4; ++mf)
                #pragma unroll
                for (int nf = 0; nf < 4; ++nf)
                    acc[mf][nf] = __builtin_amdgcn_mfma_i32_16x16x64_i8(af[mf], bfr[nf], acc[mf][nf], 0, 0, 0);
        }
        __syncthreads();
    }

    int c0 = col0 + wn * 64;
    int hh = c0 >> 6;   // 0..15 Q heads, 16..19 K heads, 20..23 V heads
    float alpha = alpha_from_partial(partial, hh < 16 ? 0 : (hh < 20 ? 1 : 2));

    if (hh < 20) {
        float ga = (hh < 16) ? gain[hh] * (0.125f * 1.4426950408889634f) : 1.0f;
        #pragma unroll
        for (int mf = 0; mf < 4; ++mf) {
            #pragma unroll
            for (int reg = 0; reg < 4; ++reg) {
                int row = row0 + wm * 64 + mf * 16 + lg * 4 + reg;
                float sc = gamma[row] * alpha;
                float v0 = (float)acc[mf][0][reg] * sc;
                float v1 = (float)acc[mf][1][reg] * sc;
                float v2 = (float)acc[mf][2][reg] * sc;
                float v3 = (float)acc[mf][3][reg] * sc;
                int s = row & 1023, b = row >> 10;
                float ss = v0 * v0 + v1 * v1 + v2 * v2 + v3 * v3;
                #pragma unroll
                for (int off = 8; off; off >>= 1) ss += __shfl_xor(ss, off);
                float rn = 1.0f / sqrtf(ss * (1.0f / 64.0f) + 1.1920929e-07f);
                v0 *= rn; v1 *= rn; v2 *= rn; v3 *= rn;
                float cA = rc[s * 32 + lr],      sA = rs[s * 32 + lr];
                float cB = rc[s * 32 + 16 + lr], sB = rs[s * 32 + 16 + lr];
                float y0 = v0 * cA + v2 * sA, y2 = v2 * cA - v0 * sA;
                float y1 = v1 * cB + v3 * sB, y3 = v3 * cB - v1 * sB;
                u16* dst;
                if (hh < 16) {
                    y0 *= ga; y1 *= ga; y2 *= ga; y3 *= ga;
                    dst = Qo + ((size_t)((b * 16 + hh) * 1024 + s)) * 64;
                } else {
                    dst = Ko + ((size_t)((b * 4 + (hh - 16)) * 1024 + s)) * 64;
                }
                dst[lr] = f2bf(y0); dst[16 + lr] = f2bf(y1);
                dst[32 + lr] = f2bf(y2); dst[48 + lr] = f2bf(y3);
            }
        }
    } else {
        int kv = hh - 20;
        u16* T = reinterpret_cast<u16*>(SMEM) + w * 4096;
        #pragma unroll
        for (int mf = 0; mf < 4; ++mf) {
            int pb = (mf & 1) + 32 * (mf >> 1);
            #pragma unroll
            for (int reg = 0; reg < 4; ++reg) {
                int row = row0 + wm * 64 + mf * 16 + lg * 4 + reg;
                float sc = gamma[row] * alpha;
                int pos = 2 * (lg * 4 + reg) + pb;
                #pragma unroll
                for (int nf = 0; nf < 4; ++nf) {
                    int d = nf * 16 + lr;
                    T[d * 64 + (pos ^ (lr7 << 3))] = f2bf((float)acc[mf][nf][reg] * sc);
                }
            }
        }
        int b = row0 >> 10;
        int st = ((row0 & 1023) + wm * 64) >> 6;
        int d = lane, h3 = lane & 7;
        u16* dst = Vt + (((size_t)(b * 4 + kv) * 64) + d) * 1024 + st * 64;
        #pragma unroll
        for (int j = 0; j < 8; ++j) {
            u16x8 gv = *reinterpret_cast<const u16x8*>(&T[d * 64 + 8 * (j ^ h3)]);
            *reinterpret_cast<u16x8*>(&dst[8 * j]) = gv;
        }
    }
}

// ---------------- i8 GEMM for output projection (XCD-swizzled, alpha inline) ----------------
__global__ __launch_bounds__(256) void k_gemm_out(const s8* __restrict__ A,
                                                  const s8* __restrict__ B,
                                                  const float* __restrict__ gamma,
                                                  const float* __restrict__ partial,
                                                  float* __restrict__ C) {
    __shared__ s8 As[128 * 128];
    __shared__ s8 Bs[128 * 128];
    const int K = DIMM;
    int tid = threadIdx.x;
    int w = tid >> 6, lane = tid & 63;
    int lr = lane & 15, lg = lane >> 4;
    int lr7 = lr & 7;
    int wm = w >> 1, wn = w & 1;
    int orig = blockIdx.x + 8 * blockIdx.y;
    int wgid = ((orig & 7) << 6) + (orig >> 3);
    int row0 = (wgid >> 3) * 128, col0 = (wgid & 7) * 128;

    i32x4 acc[4][4];
    #pragma unroll
    for (int mf = 0; mf < 4; ++mf)
        #pragma unroll
        for (int nf = 0; nf < 4; ++nf) acc[mf][nf] = (i32x4){0, 0, 0, 0};

    int srow = w * 32 + (lane >> 3);
    int scol = 16 * ((lane & 7) ^ (lane >> 3));
    const s8* Ag = A + (size_t)(row0 + srow) * K + scol;
    const s8* Bg = B + (size_t)(col0 + srow) * K + scol;

    for (int k0 = 0; k0 < K; k0 += 128) {
        #pragma unroll
        for (int i = 0; i < 4; ++i) {
            gload16(Ag + (size_t)i * 8 * K + k0, &As[w * 4096 + i * 1024]);
            gload16(Bg + (size_t)i * 8 * K + k0, &Bs[w * 4096 + i * 1024]);
        }
        __syncthreads();
        #pragma unroll
        for (int kh = 0; kh < 2; ++kh) {
            i32x4 af[4], bfr[4];
            #pragma unroll
            for (int mf = 0; mf < 4; ++mf)
                af[mf] = *reinterpret_cast<const i32x4*>(
                    &As[(wm * 64 + mf * 16 + lr) * 128 + 16 * (((kh << 2) + lg) ^ lr7)]);
            #pragma unroll
            for (int nf = 0; nf < 4; ++nf)
                bfr[nf] = *reinterpret_cast<const i32x4*>(
                    &Bs[(wn * 64 + nf * 16 + lr) * 128 + 16 * (((kh << 2) + lg) ^ lr7)]);
            #pragma unroll
            for (int mf = 0; mf < 4; ++mf)
                #pragma unroll
                for (int nf = 0; nf < 4; ++nf)
                    acc[mf][nf] = __builtin_amdgcn_mfma_i32_16x16x64_i8(af[mf], bfr[nf], acc[mf][nf], 0, 0, 0);
        }
        __syncthreads();
    }

    float alpha = alpha_from_partial(partial, 3);
    #pragma unroll
    for (int mf = 0; mf < 4; ++mf) {
        #pragma unroll
        for (int reg = 0; reg < 4; ++reg) {
            int row = row0 + wm * 64 + mf * 16 + lg * 4 + reg;
            float sc = gamma[row] * alpha;
            #pragma unroll
            for (int nf = 0; nf < 4; ++nf)
                C[(size_t)row * 1024 + col0 + wn * 64 + nf * 16 + lr] = (float)acc[mf][nf][reg] * sc;
        }
    }
}

// ---------------- causal flash attention, bf16 MFMA, paired q-tiles ----------------
// 128-key staging / 64-key processing: one vmcnt+barrier per 128 keys (halved drains).
// Each 64-half keeps the proven [64][64] K and V^T layouts + swizzle byte-identically.
__global__ __launch_bounds__(256) void k_attn_mfma(const u16* __restrict__ Q,
                                                   const u16* __restrict__ K,
                                                   const u16* __restrict__ Vt,
                                                   u16* __restrict__ Y) {
    __shared__ __align__(16) u16 KVs[2][2][2][4096];  // [buf][half][K/V][64*64], swizzled
    __shared__ __align__(16) u16 Ps[4][1024];         // per-wave P strip [16 q][64 pos], swizzled
    int orig = blockIdx.x + ((blockIdx.y + (blockIdx.z << 4)) << 3);
    int wgid = ((orig & 7) << 7) + (orig >> 3);
    int qta = wgid & 7, qtb = 15 - qta;
    int h = (wgid >> 3) & 15, b = wgid >> 7;
    int kvh = h >> 2;
    int tid = threadIdx.x;
    int w = tid >> 6, lane = tid & 63;
    int lr = lane & 15, lg = lane >> 4;
    int lr7 = lr & 7;
    int q0a = qta * 64 + w * 16, q0b = qtb * 64 + w * 16;
    const u16* Qb = Q + (((size_t)b * 16 + h) * 1024) * 64;
    const u16* Kb = K + (((size_t)b * 4 + kvh) * 1024) * 64;
    const u16* Vb = Vt + (((size_t)b * 4 + kvh) * 64) * 1024;
    u16* Psw = Ps[w];
    unsigned* Pw32 = reinterpret_cast<unsigned*>(Psw);

    bf16x8 qa0 = *reinterpret_cast<const bf16x8*>(&Qb[(size_t)(q0a + lr) * 64 + 8 * lg]);
    bf16x8 qa1 = *reinterpret_cast<const bf16x8*>(&Qb[(size_t)(q0a + lr) * 64 + 32 + 8 * lg]);
    bf16x8 qb0 = *reinterpret_cast<const bf16x8*>(&Qb[(size_t)(q0b + lr) * 64 + 8 * lg]);
    bf16x8 qb1 = *reinterpret_cast<const bf16x8*>(&Qb[(size_t)(q0b + lr) * 64 + 32 + 8 * lg]);

    float mA[4], lpA[4], mB[4], lpB[4];
    f32x4 accA[4], accB[4];
    #pragma unroll
    for (int r = 0; r < 4; ++r) { mA[r] = -INFINITY; lpA[r] = 0.f; mB[r] = -INFINITY; lpB[r] = 0.f; }
    #pragma unroll
    for (int dt = 0; dt < 4; ++dt) { accA[dt] = (f32x4){0.f,0.f,0.f,0.f}; accB[dt] = (f32x4){0.f,0.f,0.f,0.f}; }

    int sub = lane >> 3, s7 = lane & 7;
    int scol16 = s7 ^ sub;
    int c0 = 2 * w, c1 = 2 * w + 1;

    // stage 64 keys (K + V^T) into KVs[buf][half]
    #define STAGE64(buf, half, t64) do { \
        int kk0 = (t64) * 64; \
        gload16(Kb + (size_t)(kk0 + 8 * c0 + sub) * 64 + scol16 * 8, &KVs[buf][half][0][c0 * 512]); \
        gload16(Kb + (size_t)(kk0 + 8 * c1 + sub) * 64 + scol16 * 8, &KVs[buf][half][0][c1 * 512]); \
        gload16(Vb + (size_t)(8 * c0 + sub) * 1024 + kk0 + scol16 * 8, &KVs[buf][half][1][c0 * 512]); \
        gload16(Vb + (size_t)(8 * c1 + sub) * 1024 + kk0 + scol16 * 8, &KVs[buf][half][1][c1 * 512]); \
    } while (0)

    STAGE64(0, 0, 0);
    STAGE64(0, 1, 1);
    asm volatile("s_waitcnt vmcnt(0)" ::: "memory");
    __syncthreads();
    int cur = 0;

    int npair = (qtb >> 1) + 1;
    for (int pair = 0; pair < npair; ++pair) {
        if (pair + 1 < npair) {
            STAGE64(cur ^ 1, 0, 2 * (pair + 1));
            STAGE64(cur ^ 1, 1, 2 * (pair + 1) + 1);
        }
        #pragma unroll
        for (int half = 0; half < 2; ++half) {
            int kc = 2 * pair + half;
            if (kc > qtb) break;
            const int k0 = kc * 64;
            const bool doA = (kc <= qta);
            const u16* Kl = KVs[cur][half][0];
            const u16* Vl = KVs[cur][half][1];

            float svA[4][4], svB[4][4];
            __builtin_amdgcn_s_setprio(1);
            #pragma unroll
            for (int t4 = 0; t4 < 4; ++t4) {
                int r = t4 * 16 + lr;
                bf16x8 kf0 = *reinterpret_cast<const bf16x8*>(&Kl[r * 64 + ((lg ^ lr7) << 3)]);
                bf16x8 kf1 = *reinterpret_cast<const bf16x8*>(&Kl[r * 64 + (((4 | lg) ^ lr7) << 3)]);
                if (doA) {
                    f32x4 z = (f32x4){0.f,0.f,0.f,0.f};
                    z = __builtin_amdgcn_mfma_f32_16x16x32_bf16(qa0, kf0, z, 0, 0, 0);
                    z = __builtin_amdgcn_mfma_f32_16x16x32_bf16(qa1, kf1, z, 0, 0, 0);
                    #pragma unroll
                    for (int rr = 0; rr < 4; ++rr) svA[t4][rr] = z[rr];
                }
                f32x4 z2 = (f32x4){0.f,0.f,0.f,0.f};
                z2 = __builtin_amdgcn_mfma_f32_16x16x32_bf16(qb0, kf0, z2, 0, 0, 0);
                z2 = __builtin_amdgcn_mfma_f32_16x16x32_bf16(qb1, kf1, z2, 0, 0, 0);
                #pragma unroll
                for (int rr = 0; rr < 4; ++rr) svB[t4][rr] = z2[rr];
            }
            __builtin_amdgcn_s_setprio(0);
            if (doA && kc == qta) {
                #pragma unroll
                for (int t4 = 0; t4 < 4; ++t4) {
                    int key = k0 + t4 * 16 + lr;
                    #pragma unroll
                    for (int rr = 0; rr < 4; ++rr)
                        if (key > q0a + lg * 4 + rr) svA[t4][rr] = -3.0e38f;
                }
            }
            if (kc == qtb) {
                #pragma unroll
                for (int t4 = 0; t4 < 4; ++t4) {
                    int key = k0 + t4 * 16 + lr;
                    #pragma unroll
                    for (int rr = 0; rr < 4; ++rr)
                        if (key > q0b + lg * 4 + rr) svB[t4][rr] = -3.0e38f;
                }
            }

            bf16x8 paA0, paA1, paB0, paB1;
            if (doA) {
                float vx[4]; int ok = 1;
                #pragma unroll
                for (int rr = 0; rr < 4; ++rr) {
                    vx[rr] = fmaxf(fmaxf(svA[0][rr], svA[1][rr]), fmaxf(svA[2][rr], svA[3][rr]));
                    ok &= (vx[rr] <= mA[rr] + 8.0f);
                }
                if (!__all(ok)) {
                    #pragma unroll
                    for (int rr = 0; rr < 4; ++rr) {
                        float mm = vx[rr];
                        #pragma unroll
                        for (int off = 8; off; off >>= 1) mm = fmaxf(mm, __shfl_xor(mm, off));
                        float mn = fmaxf(mA[rr], mm);
                        float corr = exp2f(mA[rr] - mn);
                        mA[rr] = mn;
                        lpA[rr] *= corr;
                        #pragma unroll
                        for (int dt = 0; dt < 4; ++dt) accA[dt][rr] *= corr;
                    }
                }
                #pragma unroll
                for (int rr = 0; rr < 4; ++rr) {
                    float p0 = exp2f(svA[0][rr] - mA[rr]);
                    float p1 = exp2f(svA[1][rr] - mA[rr]);
                    float p2 = exp2f(svA[2][rr] - mA[rr]);
                    float p3 = exp2f(svA[3][rr] - mA[rr]);
                    lpA[rr] += (p0 + p1) + (p2 + p3);
                    unsigned pk01, pk23;
                    asm("v_cvt_pk_bf16_f32 %0, %1, %2" : "=v"(pk01) : "v"(p0), "v"(p1));
                    asm("v_cvt_pk_bf16_f32 %0, %1, %2" : "=v"(pk23) : "v"(p2), "v"(p3));
                    int row = lg * 4 + rr, r7 = row & 7;
                    Pw32[row * 32 + (((lr >> 2) ^ r7) << 2) + (lr & 3)] = pk01;
                    Pw32[row * 32 + ((((lr >> 2) + 4) ^ r7) << 2) + (lr & 3)] = pk23;
                }
                paA0 = *reinterpret_cast<const bf16x8*>(&Psw[lr * 64 + ((lg ^ lr7) << 3)]);
                paA1 = *reinterpret_cast<const bf16x8*>(&Psw[lr * 64 + (((4 | lg) ^ lr7) << 3)]);
            }

            {
                float vx[4]; int ok = 1;
                #pragma unroll
                for (int rr = 0; rr < 4; ++rr) {
                    vx[rr] = fmaxf(fmaxf(svB[0][rr], svB[1][rr]), fmaxf(svB[2][rr], svB[3][rr]));
                    ok &= (vx[rr] <= mB[rr] + 8.0f);
                }
                if (!__all(ok)) {
                    #pragma unroll
                    for (int rr = 0; rr < 4; ++rr) {
                        float mm = vx[rr];
                        #pragma unroll
                        for (int off = 8; off; off >>= 1) mm = fmaxf(mm, __shfl_xor(mm, off));
                        float mn = fmaxf(mB[rr], mm);
                        float corr = exp2f(mB[rr] - mn);
                        mB[rr] = mn;
                        lpB[rr] *= corr;
                        #pragma unroll
                        for (int dt = 0; dt < 4; ++dt) accB[dt][rr] *= corr;
                    }
                }
                #pragma unroll
                for (int rr = 0; rr < 4; ++rr) {
                    float p0 = exp2f(svB[0][rr] - mB[rr]);
                    float p1 = exp2f(svB[1][rr] - mB[rr]);
                    float p2 = exp2f(svB[2][rr] - mB[rr]);
                    float p3 = exp2f(svB[3][rr] - mB[rr]);
                    lpB[rr] += (p0 + p1) + (p2 + p3);
                    unsigned pk01, pk23;
                    asm("v_cvt_pk_bf16_f32 %0, %1, %2" : "=v"(pk01) : "v"(p0), "v"(p1));
                    asm("v_cvt_pk_bf16_f32 %0, %1, %2" : "=v"(pk23) : "v"(p2), "v"(p3));
                    int row = lg * 4 + rr, r7 = row & 7;
                    Pw32[row * 32 + (((lr >> 2) ^ r7) << 2) + (lr & 3)] = pk01;
                    Pw32[row * 32 + ((((lr >> 2) + 4) ^ r7) << 2) + (lr & 3)] = pk23;
                }
                paB0 = *reinterpret_cast<const bf16x8*>(&Psw[lr * 64 + ((lg ^ lr7) << 3)]);
                paB1 = *reinterpret_cast<const bf16x8*>(&Psw[lr * 64 + (((4 | lg) ^ lr7) << 3)]);
            }

            __builtin_amdgcn_s_setprio(1);
            #pragma unroll
            for (int dt = 0; dt < 4; ++dt) {
                int r = dt * 16 + lr;
                bf16x8 vf0 = *reinterpret_cast<const bf16x8*>(&Vl[r * 64 + ((lg ^ lr7) << 3)]);
                bf16x8 vf1 = *reinterpret_cast<const bf16x8*>(&Vl[r * 64 + (((4 | lg) ^ lr7) << 3)]);
                if (doA) {
                    accA[dt] = __builtin_amdgcn_mfma_f32_16x16x32_bf16(paA0, vf0, accA[dt], 0, 0, 0);
                    accA[dt] = __builtin_amdgcn_mfma_f32_16x16x32_bf16(paA1, vf1, accA[dt], 0, 0, 0);
                }
                accB[dt] = __builtin_amdgcn_mfma_f32_16x16x32_bf16(paB0, vf0, accB[dt], 0, 0, 0);
                accB[dt] = __builtin_amdgcn_mfma_f32_16x16x32_bf16(paB1, vf1, accB[dt], 0, 0, 0);
            }
            __builtin_amdgcn_s_setprio(0);
        }

        asm volatile("s_waitcnt vmcnt(0)" ::: "memory");
        __syncthreads();
        cur ^= 1;
    }
    #undef STAGE64

    #pragma unroll
    for (int rr = 0; rr < 4; ++rr) {
        #pragma unroll
        for (int off = 8; off; off >>= 1) {
            lpA[rr] += __shfl_xor(lpA[rr], off);
            lpB[rr] += __shfl_xor(lpB[rr], off);
        }
    }

    #pragma unroll
    for (int rr = 0; rr < 4; ++rr) {
        float invA = 1.0f / lpA[rr];
        float invB = 1.0f / lpB[rr];
        size_t baseA = ((size_t)(b * 1024 + q0a + lg * 4 + rr)) * 1024 + h * 64;
        size_t baseB = ((size_t)(b * 1024 + q0b + lg * 4 + rr)) * 1024 + h * 64;
        #pragma unroll
        for (int dt = 0; dt < 4; ++dt) {
            Y[baseA + dt * 16 + lr] = f2bf(accA[dt][rr] * invA);
            Y[baseB + dt * 16 + lr] = f2bf(accB[dt][rr] * invB);
        }
    }
}

extern "C" void kernel_launch(void* const* d_in, const int* in_sizes, int n_in,
                              void* d_out, int out_size, void* d_ws, size_t ws_size,
                              hipStream_t stream) {
    (void)in_sizes; (void)n_in; (void)out_size; (void)ws_size;
    const float* x  = (const float*)d_in[0];
    const float* Wq = (const float*)d_in[1];
    const float* Wk = (const float*)d_in[2];
    const float* Wv = (const float*)d_in[3];
    const float* Wp = (const float*)d_in[4];
    const float* qg = (const float*)d_in[5];
    float* out = (float*)d_out;

    float* p = (float*)d_ws;
    float* partial = p; p += 256;
    s8* wtqkv = (s8*)p; p += 393216;     // 1536x1024 i8
    s8* wtp   = (s8*)p; p += 262144;     // 1024x1024 i8
    s8* xq    = (s8*)p; p += 2097152;    // 8192x1024 i8
    float* gam = p; p += 8192;
    u16* y16   = (u16*)p; p += 4194304;  // bf16 [8192][1024] attn output
    u16* qo = (u16*)p; p += 4194304;     // bf16 [b,16,1024,64]
    u16* ko = (u16*)p; p += 1048576;     // bf16 [b,4,1024,64]
    u16* vt = (u16*)p; p += 1048576;     // bf16 [b,4,64,pos]
    float* rc = p; p += 32768;
    float* rs = p; p += 32768;
    s8* yq = xq;   // reuse (xq dead after qkv gemm)

    // fused: weight abs-mean + x quantization + rope table (one dispatch)
    k_prep1<<<2432, 256, 0, stream>>>(Wq, Wk, Wv, Wp, partial, x, xq, gam, rc, rs);
    // ternarize (alpha derived inline from partial)
    k_tern_all<<<2560, 256, 0, stream>>>(Wq, Wk, Wv, Wp, partial, wtqkv, wtp);

    // fused i8 QKV projection (+norm/rope + V transpose)
    k_gemm_qkv<<<dim3(12, 64), 256, 0, stream>>>(xq, wtqkv, gam, partial, rc, rs, qg, qo, ko, vt);

    // attention (128-key staging / 64-key halves, packed P, XCD-swizzled, bf16 out)
    k_attn_mfma<<<dim3(8, 16, 8), 256, 0, stream>>>(qo, ko, vt, y16);

    // output projection (i8)
    k_quant_bf16<<<2048, 256, 0, stream>>>(y16, yq, gam);
    k_gemm_out<<<dim3(8, 64), 256, 0, stream>>>(yq, wtp, gam, partial, out);
}